// Round 1
// 469.067 us; speedup vs baseline: 1.0796x; 1.0796x over previous
//
#include <hip/hip_runtime.h>
#include <math.h>

// Problem constants (from reference): B=4, L=4096, D=1024
#define B_SZ 4
#define L_SZ 4096
#define D_SZ 1024
#define M_SZ (B_SZ * L_SZ)      // 16384 tokens
#define NBINS 513               // rfft bins for D=1024
#define CCH   (2 * NBINS)       // 1026 float channels per token (interleaved re,im)
#define TCH 32                  // cumsum chunks over L
#define TLEN (L_SZ / TCH)       // 128 timesteps per chunk

typedef short bf16x8 __attribute__((ext_vector_type(8)));
typedef float f32x4  __attribute__((ext_vector_type(4)));
typedef unsigned short us8 __attribute__((ext_vector_type(8)));

// round-to-nearest-even f32 -> bf16
__device__ inline unsigned short f2bf(float f) {
    unsigned int u = __float_as_uint(f);
    u += 0x7fffu + ((u >> 16) & 1u);
    return (unsigned short)(u >> 16);
}

// ---------------------------------------------------------------------------
// f32 -> bf16 cast, 8 elements/thread
// ---------------------------------------------------------------------------
__global__ __launch_bounds__(256) void cast_f32_bf16(
        const float* __restrict__ in, unsigned short* __restrict__ out, int n8) {
    int i = blockIdx.x * 256 + threadIdx.x;
    if (i >= n8) return;
    const float4* p = (const float4*)in + 2 * (size_t)i;
    float4 a = p[0], b = p[1];
    us8 o;
    o[0] = f2bf(a.x); o[1] = f2bf(a.y); o[2] = f2bf(a.z); o[3] = f2bf(a.w);
    o[4] = f2bf(b.x); o[5] = f2bf(b.y); o[6] = f2bf(b.z); o[7] = f2bf(b.w);
    *(us8*)(out + (size_t)i * 8) = o;
}

// ---------------------------------------------------------------------------
// bf16 MFMA GEMM, 128x128 tile, BK=32, XCD-swizzled 1D grid.
// A: M x K bf16.  W: (CN*128) x K bf16 (torch Linear layout).  K = 1024 here.
// Logical N axis split into halves of 1024: cols [0,1024) -> C0/bias0,
// cols [1024,2048) -> C1/bias1 (fused K+V projection). For CN=8 the second
// half is never reached (C1=C0).
//
// This round: (a) double-buffered LDS with prefetch — next K-tile's
// global_load_lds issued BEFORE the current tile's MFMAs, so the single
// end-of-iteration __syncthreads() drains loads whose latency was covered
// by compute (T3-minimum recipe); (b) LDS bank-conflict XOR swizzle applied
// both-sides (pre-swizzled global source column + swizzled ds_read slot,
// LDS destination stays linear as global_load_lds requires).
// ---------------------------------------------------------------------------
#define GBM 128
#define GBN 128
#define GBK 32
template<int CN>
__global__ __launch_bounds__(256) void gemm_mfma(
        const unsigned short* __restrict__ A, const unsigned short* __restrict__ W,
        const float* __restrict__ bias0, const float* __restrict__ bias1,
        const float* __restrict__ resid,
        float* __restrict__ C0, float* __restrict__ C1, int M, int K) {
    __shared__ unsigned short As[2][GBM * GBK];   // 2 x 8192 B
    __shared__ unsigned short Ws[2][GBN * GBK];   // 2 x 8192 B
    const int id   = blockIdx.x;
    const int bx   = (id >> 3) % CN;
    const int by   = (id & 7) + 8 * (id / (8 * CN));
    const int tid  = threadIdx.x;
    const int lane = tid & 63;
    const int wave = tid >> 6;                 // 0..3
    const int wm   = wave & 1;
    const int wn   = wave >> 1;
    const int bm   = by * GBM;
    const int bn   = bx * GBN;

    f32x4 acc[4][4] = {};

    // staging geometry: each lane loads 16B; row = ldr, col slot = lane&3.
    // Pre-swizzle the GLOBAL column slot so that LDS (linear dest) ends up
    // holding slot (s ^ ((row>>1)&3)) at slot s — spreads the ds_read_b128
    // column reads across all 32 banks.
    const int ldr  = lane >> 2;
    const int ldsw = ((lane & 3) ^ ((ldr >> 1) & 3)) * 8;   // shorts

    auto stage_tile = [&](int sel, int kk) {
        #pragma unroll
        for (int p = 0; p < 2; p++) {
            const int row = p * 64 + wave * 16 + ldr;
            const unsigned short* gsA = A + (size_t)(bm + row) * K + kk + ldsw;
            const unsigned short* gsW = W + (size_t)(bn + row) * K + kk + ldsw;
            __builtin_amdgcn_global_load_lds(
                (const __attribute__((address_space(1))) unsigned int*)gsA,
                (__attribute__((address_space(3))) unsigned int*)(As[sel] + (size_t)(p * 64 + wave * 16) * GBK),
                16, 0, 0);
            __builtin_amdgcn_global_load_lds(
                (const __attribute__((address_space(1))) unsigned int*)gsW,
                (__attribute__((address_space(3))) unsigned int*)(Ws[sel] + (size_t)(p * 64 + wave * 16) * GBK),
                16, 0, 0);
        }
    };

    const int fr  = lane & 15;
    const int swr = ((lane >> 4) ^ ((fr >> 1) & 3)) * 8;    // swizzled read slot (shorts)

    auto compute_tile = [&](int sel) {
        bf16x8 af[4], bfr[4];
        #pragma unroll
        for (int t = 0; t < 4; t++) {
            af[t]  = *(const bf16x8*)&As[sel][(wm * 64 + t * 16 + fr) * GBK + swr];
            bfr[t] = *(const bf16x8*)&Ws[sel][(wn * 64 + t * 16 + fr) * GBK + swr];
        }
        #pragma unroll
        for (int i = 0; i < 4; i++)
            #pragma unroll
            for (int j = 0; j < 4; j++)
                acc[i][j] = __builtin_amdgcn_mfma_f32_16x16x32_bf16(
                                af[i], bfr[j], acc[i][j], 0, 0, 0);
    };

    // prologue: stage first tile, full drain once
    stage_tile(0, 0);
    __syncthreads();

    int cur = 0;
    for (int k0 = 0; k0 < K - GBK; k0 += GBK) {
        stage_tile(cur ^ 1, k0 + GBK);     // prefetch next tile (async, in flight under MFMA)
        compute_tile(cur);
        __syncthreads();                   // drains vmcnt(0)+lgkmcnt(0): prefetch landed, reads done
        cur ^= 1;
    }
    compute_tile(cur);                     // last tile, no prefetch

    const int col0 = lane & 15;
    const int quad = lane >> 4;
    #pragma unroll
    for (int j = 0; j < 4; j++) {
        const int ng = bn + wn * 64 + j * 16 + col0;   // global col in [0, CN*128)
        const int half = ng >> 10;                     // 0 or 1 (wave-uniform per j)
        const int n = ng & 1023;
        float* __restrict__ Cp = half ? C1 : C0;
        const float bv = half ? bias1[n] : bias0[n];
        #pragma unroll
        for (int i = 0; i < 4; i++) {
            #pragma unroll
            for (int r = 0; r < 4; r++) {
                const int m = bm + wm * 64 + i * 16 + quad * 4 + r;
                float v = acc[i][j][r] + bv;
                size_t off = (size_t)m * 1024 + n;
                if (resid) v += resid[off];
                Cp[off] = v;
            }
        }
    }
}

// ---------------------------------------------------------------------------
// Stockham radix-4 1024-pt FFT. 256 threads, 4 complex/thread in registers,
// 5 stages, exchanges via two swizzled float2 LDS buffers (conflict-free).
// ---------------------------------------------------------------------------
#define SWZ(a) ((a) ^ (((a) >> 4) & 15))

struct cplx { float r, i; };
__device__ inline cplx cmul(cplx a, cplx b) {
    return {a.r * b.r - a.i * b.i, a.r * b.i + a.i * b.r};
}

__device__ inline void r4bfly(cplx v[4], float s) {
    cplx t0 {v[0].r + v[2].r, v[0].i + v[2].i};
    cplx t1 {v[0].r - v[2].r, v[0].i - v[2].i};
    cplx t2 {v[1].r + v[3].r, v[1].i + v[3].i};
    cplx t3 {v[1].r - v[3].r, v[1].i - v[3].i};
    cplx j3 {-s * t3.i, s * t3.r};     // s*i * t3
    v[0] = {t0.r + t2.r, t0.i + t2.i};
    v[2] = {t0.r - t2.r, t0.i - t2.i};
    v[1] = {t1.r + j3.r, t1.i + j3.i};
    v[3] = {t1.r - j3.r, t1.i - j3.i};
}

template<int SIGN>
__device__ inline void fft1024_r(float2* bA, float2* bB, cplx v[4], int tid) {
    const float s = (float)SIGN;
    r4bfly(v, s);
    {
        const int base = tid << 2;
        #pragma unroll
        for (int e = 0; e < 4; e++)
            bA[SWZ(base + e)] = make_float2(v[e].r, v[e].i);
    }
    __syncthreads();
    float2* cur = bA;
    float2* nxt = bB;
    #pragma unroll
    for (int q = 1; q <= 3; q++) {
        const int Ls = 1 << (2 * q);
        #pragma unroll
        for (int k = 0; k < 4; k++) {
            float2 t = cur[SWZ(tid + (k << 8))];
            v[k] = {t.x, t.y};
        }
        const int d = tid & (Ls - 1);
        const float ang = s * 1.57079632679489662f * (float)d / (float)Ls;
        float sn, cs; __sincosf(ang, &sn, &cs);
        cplx w1 {cs, sn};
        cplx w2 = cmul(w1, w1);
        cplx w3 = cmul(w2, w1);
        v[1] = cmul(v[1], w1);
        v[2] = cmul(v[2], w2);
        v[3] = cmul(v[3], w3);
        r4bfly(v, s);
        const int base = ((tid >> (2 * q)) << (2 * q + 2)) + d;
        #pragma unroll
        for (int e = 0; e < 4; e++)
            nxt[SWZ(base + (e << (2 * q)))] = make_float2(v[e].r, v[e].i);
        float2* tmp = cur; cur = nxt; nxt = tmp;
        __syncthreads();
    }
    #pragma unroll
    for (int k = 0; k < 4; k++) {
        float2 t = cur[SWZ(tid + (k << 8))];
        v[k] = {t.x, t.y};
    }
    {
        const float ang = s * 1.57079632679489662f * (float)tid / 256.0f;
        float sn, cs; __sincosf(ang, &sn, &cs);
        cplx w1 {cs, sn};
        cplx w2 = cmul(w1, w1);
        cplx w3 = cmul(w2, w1);
        v[1] = cmul(v[1], w1);
        v[2] = cmul(v[2], w2);
        v[3] = cmul(v[3], w3);
        r4bfly(v, s);
    }
}

// ---------------------------------------------------------------------------
// Bind: normalize keys, pack z = k_hat + i*v, one forward FFT, unpack the two
// real-signal spectra (Kf even part, Vf odd part), write P = Kf*Vf AND write
// Kf packed IN PLACE over the (now dead) Kraw row: float[0]=Kf[0].re,
// float[1]=Kf[512].re, float[2b],[2b+1]=Kf[b] for b=1..511 -> exactly 1024
// floats. Unbind then needs no forward FFT at all.
// ---------------------------------------------------------------------------
__global__ __launch_bounds__(256) void bind_fft_kernel(
        float* __restrict__ KIO, const float* __restrict__ V,
        float* __restrict__ P) {
    __shared__ float2 bA[1024], bB[1024];
    __shared__ float red[256];
    const int token = blockIdx.x;
    const int tid = threadIdx.x;

    float* krow = KIO + (size_t)token * D_SZ;
    const float* vrow = V + (size_t)token * D_SZ;
    float kv[4], vv[4];
    float ss = 0.0f;
    #pragma unroll
    for (int k = 0; k < 4; k++) {
        kv[k] = krow[tid + (k << 8)];
        vv[k] = vrow[tid + (k << 8)];
        ss += kv[k] * kv[k];
    }
    red[tid] = ss;
    __syncthreads();
    for (int sft = 128; sft > 0; sft >>= 1) {
        if (tid < sft) red[tid] += red[tid + sft];
        __syncthreads();
    }
    const float scale = 1.0f / fmaxf(sqrtf(red[0]), 1e-12f);

    cplx z[4];
    #pragma unroll
    for (int k = 0; k < 4; k++) z[k] = {kv[k] * scale, vv[k]};

    __syncthreads();
    fft1024_r<-1>(bA, bB, z, tid);

    #pragma unroll
    for (int e = 0; e < 4; e++)
        bA[SWZ(tid + (e << 8))] = make_float2(z[e].r, z[e].i);
    __syncthreads();

    float2* Po = (float2*)(P + (size_t)token * CCH);
    for (int bin = tid; bin < NBINS; bin += 256) {
        float2 Zb = bA[SWZ(bin)];
        float2 Zm = bA[SWZ((1024 - bin) & 1023)];
        float ar = 0.5f * (Zb.x + Zm.x);
        float ai = 0.5f * (Zb.y - Zm.y);
        float br = 0.5f * (Zb.y + Zm.y);
        float bi = 0.5f * (Zm.x - Zb.x);
        Po[bin] = make_float2(ar * br - ai * bi, ar * bi + ai * br);
        // packed Kf write (in place over Kraw; all krow reads happened above)
        if (bin == 0)        krow[0] = ar;
        else if (bin == 512) krow[1] = ar;
        else { krow[2 * bin] = ar; krow[2 * bin + 1] = ai; }
    }
}

// ---------------------------------------------------------------------------
// Cumsum pass 1: in-place local cumsum within each t-chunk + chunk totals.
// ---------------------------------------------------------------------------
__global__ __launch_bounds__(256) void cumsum_local(
        float* __restrict__ S, float* __restrict__ totals) {
    const int c = blockIdx.x * 256 + threadIdx.x;
    if (c >= CCH) return;
    const int chunk = blockIdx.y;
    const int b = blockIdx.z;
    size_t p = ((size_t)b * L_SZ + (size_t)chunk * TLEN) * CCH + c;
    float acc = 0.0f;
    #pragma unroll 4
    for (int t = 0; t < TLEN; t++) {
        acc += S[p];
        S[p] = acc;
        p += CCH;
    }
    totals[((size_t)b * TCH + chunk) * CCH + c] = acc;
}

// Pass 2: turn chunk totals into EXCLUSIVE prefix offsets (in place).
__global__ __launch_bounds__(256) void scan_totals(float* __restrict__ totals) {
    const int c = blockIdx.x * 256 + threadIdx.x;
    if (c >= CCH) return;
    const int b = blockIdx.y;
    float acc = 0.0f;
    for (int ch = 0; ch < TCH; ch++) {
        size_t idx = ((size_t)b * TCH + ch) * CCH + c;
        float v = totals[idx];
        totals[idx] = acc;
        acc += v;
    }
}

// ---------------------------------------------------------------------------
// Unbind: read packed Kf (stored by bind), Rf = (S_local+off)*conj(Kf),
// Hermitian extend, inverse FFT, /sqrt(t+1), LayerNorm -> bf16 RLN.
// (No forward FFT, no key re-normalization — bind already did both.)
// ---------------------------------------------------------------------------
__global__ __launch_bounds__(256) void unbind_ln_kernel(
        const float* __restrict__ P, const float* __restrict__ totals,
        const float* __restrict__ KF,
        const float* __restrict__ ln_g, const float* __restrict__ ln_b,
        unsigned short* __restrict__ RLNb) {
    __shared__ float2 bA[1024], bB[1024];
    __shared__ float red1[256], red2[256];
    const int token = blockIdx.x;
    const int tid = threadIdx.x;
    const int b = token >> 12;
    const int t = token & (L_SZ - 1);
    const int chunk = t >> 7;

    const float* kfrow   = KF + (size_t)token * D_SZ;
    const float2* Srow   = (const float2*)(P + (size_t)token * CCH);
    const float2* offrow = (const float2*)(totals + ((size_t)b * TCH + chunk) * CCH);
    #pragma unroll
    for (int e = 0; e < 3; e++) {
        const int bin = tid + (e << 8);
        if (bin < NBINS) {
            float kr, ki;
            if (bin == 0)        { kr = kfrow[0]; ki = 0.0f; }
            else if (bin == 512) { kr = kfrow[1]; ki = 0.0f; }
            else { float2 kf2 = *(const float2*)(kfrow + 2 * bin); kr = kf2.x; ki = kf2.y; }
            float2 s2 = Srow[bin];
            float2 o2 = offrow[bin];
            float sr = s2.x + o2.x, si = s2.y + o2.y;
            bA[SWZ(bin)] = make_float2(sr * kr + si * ki, si * kr - sr * ki);
        }
    }
    __syncthreads();
    for (int n = 513 + tid; n < 1024; n += 256) {
        float2 c = bA[SWZ(1024 - n)];
        bA[SWZ(n)] = make_float2(c.x, -c.y);
    }
    __syncthreads();

    cplx rz[4];
    #pragma unroll
    for (int k = 0; k < 4; k++) {
        float2 c = bA[SWZ(tid + (k << 8))];
        rz[k] = {c.x, c.y};
    }
    __syncthreads();
    fft1024_r<1>(bA, bB, rz, tid);      // rz[e].r = r[tid + 256e] * 1024

    const float posscale = (1.0f / 1024.0f) * rsqrtf((float)(t + 1));
    float rv[4];
    float sum = 0.0f, sumsq = 0.0f;
    #pragma unroll
    for (int e = 0; e < 4; e++) {
        float v = rz[e].r * posscale;
        rv[e] = v;
        sum += v;
        sumsq += v * v;
    }
    red1[tid] = sum; red2[tid] = sumsq;
    __syncthreads();
    for (int sft = 128; sft > 0; sft >>= 1) {
        if (tid < sft) { red1[tid] += red1[tid + sft]; red2[tid] += red2[tid + sft]; }
        __syncthreads();
    }
    const float mu = red1[0] * (1.0f / 1024.0f);
    const float var = red2[0] * (1.0f / 1024.0f) - mu * mu;
    const float rstd = rsqrtf(var + 1e-5f);

    unsigned short* outp = RLNb + (size_t)token * D_SZ;
    #pragma unroll
    for (int e = 0; e < 4; e++) {
        const int d = tid + (e << 8);
        outp[d] = f2bf((rv[e] - mu) * rstd * ln_g[d] + ln_b[d]);
    }
}

// ---------------------------------------------------------------------------
// Workspace (bytes):
//   Kraw   fp32 M*D    = 64.0 MB  (keys; bind overwrites in place with packed Kf)
//   V      fp32 M*D    = 64.0 MB  (dead after bind; reused as bf16 RLN)
//   P      fp32 M*CCH  = 67.2 MB  (local cumsum in place)
//   totals fp32        =  0.5 MB
//   xb     bf16 M*D    = 32.0 MB
//   WB     bf16 2048*D =  4.0 MB  (Wk ++ Wv, concatenated)
//   Wob    bf16 D*D    =  2.0 MB
//   total ~= 234 MB
// ---------------------------------------------------------------------------
extern "C" void kernel_launch(void* const* d_in, const int* in_sizes, int n_in,
                              void* d_out, int out_size, void* d_ws, size_t ws_size,
                              hipStream_t stream) {
    (void)in_sizes; (void)n_in; (void)out_size; (void)ws_size;
    const float* x    = (const float*)d_in[0];
    const float* Wk   = (const float*)d_in[1];
    const float* bk   = (const float*)d_in[2];
    const float* Wv   = (const float*)d_in[3];
    const float* bv   = (const float*)d_in[4];
    const float* ln_g = (const float*)d_in[5];
    const float* ln_b = (const float*)d_in[6];
    const float* Wo   = (const float*)d_in[7];
    const float* bo   = (const float*)d_in[8];
    float* out = (float*)d_out;

    char* w = (char*)d_ws;
    float* Kraw   = (float*)w;  w += (size_t)M_SZ * D_SZ * 4;
    float* V      = (float*)w;  w += (size_t)M_SZ * D_SZ * 4;
    float* P      = (float*)w;  w += (size_t)M_SZ * CCH * 4;
    float* totals = (float*)w;  w += (size_t)B_SZ * TCH * CCH * 4;
    unsigned short* xb  = (unsigned short*)w;  w += (size_t)M_SZ * D_SZ * 2;
    unsigned short* WB  = (unsigned short*)w;  w += (size_t)2 * D_SZ * D_SZ * 2;
    unsigned short* Wob = (unsigned short*)w;  w += (size_t)D_SZ * D_SZ * 2;
    unsigned short* RLNb = (unsigned short*)V;  // overlays dead V

    const int n8x = M_SZ * D_SZ / 8;
    const int n8w = D_SZ * D_SZ / 8;
    cast_f32_bf16<<<n8x / 256, 256, 0, stream>>>(x,  xb,  n8x);
    cast_f32_bf16<<<n8w / 256, 256, 0, stream>>>(Wk, WB,                  n8w);
    cast_f32_bf16<<<n8w / 256, 256, 0, stream>>>(Wv, WB + D_SZ * D_SZ,    n8w);
    cast_f32_bf16<<<n8w / 256, 256, 0, stream>>>(Wo, Wob, n8w);

    // fused K/V projection: N=2048 (first half -> Kraw, second -> V)
    gemm_mfma<16><<<(M_SZ / GBM) * 16, 256, 0, stream>>>(
        xb, WB, bk, bv, nullptr, Kraw, V, M_SZ, D_SZ);

    bind_fft_kernel<<<M_SZ, 256, 0, stream>>>(Kraw, V, P);

    dim3 cgrid((CCH + 255) / 256, TCH, B_SZ);
    cumsum_local<<<cgrid, 256, 0, stream>>>(P, totals);
    dim3 sgrid((CCH + 255) / 256, B_SZ);
    scan_totals<<<sgrid, 256, 0, stream>>>(totals);

    unbind_ln_kernel<<<M_SZ, 256, 0, stream>>>(P, totals, Kraw, ln_g, ln_b, RLNb);

    // output GEMM with fp32 residual
    gemm_mfma<8><<<(M_SZ / GBM) * 8, 256, 0, stream>>>(
        RLNb, Wob, bo, bo, x, out, out, M_SZ, D_SZ);
}

// Round 2
// 459.663 us; speedup vs baseline: 1.1016x; 1.0205x over previous
//
#include <hip/hip_runtime.h>
#include <math.h>

// Problem constants (from reference): B=4, L=4096, D=1024
#define B_SZ 4
#define L_SZ 4096
#define D_SZ 1024
#define M_SZ (B_SZ * L_SZ)      // 16384 tokens
#define NBINS 513               // rfft bins for D=1024
#define CCH   (2 * NBINS)       // 1026 float channels per token (interleaved re,im)
#define TCH 32                  // cumsum chunks over L
#define TLEN (L_SZ / TCH)       // 128 timesteps per chunk

typedef short bf16x8 __attribute__((ext_vector_type(8)));
typedef float f32x4  __attribute__((ext_vector_type(4)));
typedef unsigned short us8 __attribute__((ext_vector_type(8)));

// round-to-nearest-even f32 -> bf16
__device__ inline unsigned short f2bf(float f) {
    unsigned int u = __float_as_uint(f);
    u += 0x7fffu + ((u >> 16) & 1u);
    return (unsigned short)(u >> 16);
}

// ---------------------------------------------------------------------------
// f32 -> bf16 cast, 8 elements/thread
// ---------------------------------------------------------------------------
__global__ __launch_bounds__(256) void cast_f32_bf16(
        const float* __restrict__ in, unsigned short* __restrict__ out, int n8) {
    int i = blockIdx.x * 256 + threadIdx.x;
    if (i >= n8) return;
    const float4* p = (const float4*)in + 2 * (size_t)i;
    float4 a = p[0], b = p[1];
    us8 o;
    o[0] = f2bf(a.x); o[1] = f2bf(a.y); o[2] = f2bf(a.z); o[3] = f2bf(a.w);
    o[4] = f2bf(b.x); o[5] = f2bf(b.y); o[6] = f2bf(b.z); o[7] = f2bf(b.w);
    *(us8*)(out + (size_t)i * 8) = o;
}

// ---------------------------------------------------------------------------
// bf16 MFMA GEMM, 128x128 tile, BK=32, XCD-swizzled 1D grid.
// A: M x K bf16.  W: (CN*128) x K bf16 (torch Linear layout).  K = 1024 here.
// Logical N axis split into halves of 1024: cols [0,1024) -> C0/bias0,
// cols [1024,2048) -> C1/bias1 (fused K+V projection). For CN=8 the second
// half is never reached (C1=C0).
//
// Round 2: depth-2 counted-vmcnt pipeline (T4). 3 LDS buffers; raw
// s_barrier (no implicit vmcnt(0) drain); inline-asm s_waitcnt vmcnt(4)
// waits only for the tile about to be computed — the next tile's 4
// global_load_lds stay in flight ACROSS the barrier. Per-iteration order:
//   wait vmcnt(4) -> s_barrier -> stage(i+2) -> compute(i)
// Memory-clobber asm on both sides of the barrier pins ds_reads/stages.
// Buffer safety: stage(i+2) writes buf[(i+2)%3], last read by compute(i-1),
// which all waves completed before passing iteration i's barrier (their
// ds_reads are drained by the compiler's lgkmcnt before the consuming MFMAs).
// LDS bank-conflict XOR swizzle (both-sides) kept from round 1.
// ---------------------------------------------------------------------------
#define GBM 128
#define GBN 128
#define GBK 32
template<int CN>
__global__ __launch_bounds__(256) void gemm_mfma(
        const unsigned short* __restrict__ A, const unsigned short* __restrict__ W,
        const float* __restrict__ bias0, const float* __restrict__ bias1,
        const float* __restrict__ resid,
        float* __restrict__ C0, float* __restrict__ C1, int M, int K) {
    __shared__ unsigned short As[3][GBM * GBK];   // 3 x 8192 B
    __shared__ unsigned short Ws[3][GBN * GBK];   // 3 x 8192 B
    const int id   = blockIdx.x;
    const int bx   = (id >> 3) % CN;
    const int by   = (id & 7) + 8 * (id / (8 * CN));
    const int tid  = threadIdx.x;
    const int lane = tid & 63;
    const int wave = tid >> 6;                 // 0..3
    const int wm   = wave & 1;
    const int wn   = wave >> 1;
    const int bm   = by * GBM;
    const int bn   = bx * GBN;

    f32x4 acc[4][4] = {};

    // staging geometry: each lane loads 16B; row = ldr, col slot = lane&3.
    // Pre-swizzle the GLOBAL column slot so that LDS (linear dest) ends up
    // holding slot (s ^ ((row>>1)&3)) at slot s — spreads the ds_read_b128
    // column reads across all 32 banks.
    const int ldr  = lane >> 2;
    const int ldsw = ((lane & 3) ^ ((ldr >> 1) & 3)) * 8;   // shorts

    auto stage_tile = [&](int sel, int kk) {
        #pragma unroll
        for (int p = 0; p < 2; p++) {
            const int row = p * 64 + wave * 16 + ldr;
            const unsigned short* gsA = A + (size_t)(bm + row) * K + kk + ldsw;
            const unsigned short* gsW = W + (size_t)(bn + row) * K + kk + ldsw;
            __builtin_amdgcn_global_load_lds(
                (const __attribute__((address_space(1))) unsigned int*)gsA,
                (__attribute__((address_space(3))) unsigned int*)(As[sel] + (size_t)(p * 64 + wave * 16) * GBK),
                16, 0, 0);
            __builtin_amdgcn_global_load_lds(
                (const __attribute__((address_space(1))) unsigned int*)gsW,
                (__attribute__((address_space(3))) unsigned int*)(Ws[sel] + (size_t)(p * 64 + wave * 16) * GBK),
                16, 0, 0);
        }
    };

    const int fr  = lane & 15;
    const int swr = ((lane >> 4) ^ ((fr >> 1) & 3)) * 8;    // swizzled read slot (shorts)

    auto compute_tile = [&](int sel) {
        bf16x8 af[4], bfr[4];
        #pragma unroll
        for (int t = 0; t < 4; t++) {
            af[t]  = *(const bf16x8*)&As[sel][(wm * 64 + t * 16 + fr) * GBK + swr];
            bfr[t] = *(const bf16x8*)&Ws[sel][(wn * 64 + t * 16 + fr) * GBK + swr];
        }
        #pragma unroll
        for (int i = 0; i < 4; i++)
            #pragma unroll
            for (int j = 0; j < 4; j++)
                acc[i][j] = __builtin_amdgcn_mfma_f32_16x16x32_bf16(
                                af[i], bfr[j], acc[i][j], 0, 0, 0);
    };

    const int nt = K / GBK;                // 32 K-tiles
    // prologue: two tiles in flight (8 loads/thread)
    stage_tile(0, 0);
    stage_tile(1, GBK);

    int sel = 0;
    for (int i = 0; i < nt - 1; ++i) {
        // wait for tile i's 4 loads; tile i+1's 4 stay in flight
        asm volatile("s_waitcnt vmcnt(4)" ::: "memory");
        __builtin_amdgcn_s_barrier();
        asm volatile("" ::: "memory");
        if (i + 2 < nt) {
            int s2 = sel + 2; if (s2 >= 3) s2 -= 3;
            stage_tile(s2, (i + 2) * GBK);
        }
        compute_tile(sel);
        sel += 1; if (sel >= 3) sel -= 3;
    }
    // last tile: full drain
    asm volatile("s_waitcnt vmcnt(0)" ::: "memory");
    __builtin_amdgcn_s_barrier();
    asm volatile("" ::: "memory");
    compute_tile(sel);

    const int col0 = lane & 15;
    const int quad = lane >> 4;
    #pragma unroll
    for (int j = 0; j < 4; j++) {
        const int ng = bn + wn * 64 + j * 16 + col0;   // global col in [0, CN*128)
        const int half = ng >> 10;                     // 0 or 1 (wave-uniform per j)
        const int n = ng & 1023;
        float* __restrict__ Cp = half ? C1 : C0;
        const float bv = half ? bias1[n] : bias0[n];
        #pragma unroll
        for (int i = 0; i < 4; i++) {
            #pragma unroll
            for (int r = 0; r < 4; r++) {
                const int m = bm + wm * 64 + i * 16 + quad * 4 + r;
                float v = acc[i][j][r] + bv;
                size_t off = (size_t)m * 1024 + n;
                if (resid) v += resid[off];
                Cp[off] = v;
            }
        }
    }
}

// ---------------------------------------------------------------------------
// Stockham radix-4 1024-pt FFT. 256 threads, 4 complex/thread in registers,
// 5 stages, exchanges via two swizzled float2 LDS buffers (conflict-free).
// ---------------------------------------------------------------------------
#define SWZ(a) ((a) ^ (((a) >> 4) & 15))

struct cplx { float r, i; };
__device__ inline cplx cmul(cplx a, cplx b) {
    return {a.r * b.r - a.i * b.i, a.r * b.i + a.i * b.r};
}

__device__ inline void r4bfly(cplx v[4], float s) {
    cplx t0 {v[0].r + v[2].r, v[0].i + v[2].i};
    cplx t1 {v[0].r - v[2].r, v[0].i - v[2].i};
    cplx t2 {v[1].r + v[3].r, v[1].i + v[3].i};
    cplx t3 {v[1].r - v[3].r, v[1].i - v[3].i};
    cplx j3 {-s * t3.i, s * t3.r};     // s*i * t3
    v[0] = {t0.r + t2.r, t0.i + t2.i};
    v[2] = {t0.r - t2.r, t0.i - t2.i};
    v[1] = {t1.r + j3.r, t1.i + j3.i};
    v[3] = {t1.r - j3.r, t1.i - j3.i};
}

template<int SIGN>
__device__ inline void fft1024_r(float2* bA, float2* bB, cplx v[4], int tid) {
    const float s = (float)SIGN;
    r4bfly(v, s);
    {
        const int base = tid << 2;
        #pragma unroll
        for (int e = 0; e < 4; e++)
            bA[SWZ(base + e)] = make_float2(v[e].r, v[e].i);
    }
    __syncthreads();
    float2* cur = bA;
    float2* nxt = bB;
    #pragma unroll
    for (int q = 1; q <= 3; q++) {
        const int Ls = 1 << (2 * q);
        #pragma unroll
        for (int k = 0; k < 4; k++) {
            float2 t = cur[SWZ(tid + (k << 8))];
            v[k] = {t.x, t.y};
        }
        const int d = tid & (Ls - 1);
        const float ang = s * 1.57079632679489662f * (float)d / (float)Ls;
        float sn, cs; __sincosf(ang, &sn, &cs);
        cplx w1 {cs, sn};
        cplx w2 = cmul(w1, w1);
        cplx w3 = cmul(w2, w1);
        v[1] = cmul(v[1], w1);
        v[2] = cmul(v[2], w2);
        v[3] = cmul(v[3], w3);
        r4bfly(v, s);
        const int base = ((tid >> (2 * q)) << (2 * q + 2)) + d;
        #pragma unroll
        for (int e = 0; e < 4; e++)
            nxt[SWZ(base + (e << (2 * q)))] = make_float2(v[e].r, v[e].i);
        float2* tmp = cur; cur = nxt; nxt = tmp;
        __syncthreads();
    }
    #pragma unroll
    for (int k = 0; k < 4; k++) {
        float2 t = cur[SWZ(tid + (k << 8))];
        v[k] = {t.x, t.y};
    }
    {
        const float ang = s * 1.57079632679489662f * (float)tid / 256.0f;
        float sn, cs; __sincosf(ang, &sn, &cs);
        cplx w1 {cs, sn};
        cplx w2 = cmul(w1, w1);
        cplx w3 = cmul(w2, w1);
        v[1] = cmul(v[1], w1);
        v[2] = cmul(v[2], w2);
        v[3] = cmul(v[3], w3);
        r4bfly(v, s);
    }
}

// ---------------------------------------------------------------------------
// Bind: normalize keys, pack z = k_hat + i*v, one forward FFT, unpack the two
// real-signal spectra (Kf even part, Vf odd part), write P = Kf*Vf AND write
// Kf packed IN PLACE over the (now dead) Kraw row: float[0]=Kf[0].re,
// float[1]=Kf[512].re, float[2b],[2b+1]=Kf[b] for b=1..511 -> exactly 1024
// floats. Unbind then needs no forward FFT at all.
// ---------------------------------------------------------------------------
__global__ __launch_bounds__(256) void bind_fft_kernel(
        float* __restrict__ KIO, const float* __restrict__ V,
        float* __restrict__ P) {
    __shared__ float2 bA[1024], bB[1024];
    __shared__ float red[256];
    const int token = blockIdx.x;
    const int tid = threadIdx.x;

    float* krow = KIO + (size_t)token * D_SZ;
    const float* vrow = V + (size_t)token * D_SZ;
    float kv[4], vv[4];
    float ss = 0.0f;
    #pragma unroll
    for (int k = 0; k < 4; k++) {
        kv[k] = krow[tid + (k << 8)];
        vv[k] = vrow[tid + (k << 8)];
        ss += kv[k] * kv[k];
    }
    red[tid] = ss;
    __syncthreads();
    for (int sft = 128; sft > 0; sft >>= 1) {
        if (tid < sft) red[tid] += red[tid + sft];
        __syncthreads();
    }
    const float scale = 1.0f / fmaxf(sqrtf(red[0]), 1e-12f);

    cplx z[4];
    #pragma unroll
    for (int k = 0; k < 4; k++) z[k] = {kv[k] * scale, vv[k]};

    __syncthreads();
    fft1024_r<-1>(bA, bB, z, tid);

    #pragma unroll
    for (int e = 0; e < 4; e++)
        bA[SWZ(tid + (e << 8))] = make_float2(z[e].r, z[e].i);
    __syncthreads();

    float2* Po = (float2*)(P + (size_t)token * CCH);
    for (int bin = tid; bin < NBINS; bin += 256) {
        float2 Zb = bA[SWZ(bin)];
        float2 Zm = bA[SWZ((1024 - bin) & 1023)];
        float ar = 0.5f * (Zb.x + Zm.x);
        float ai = 0.5f * (Zb.y - Zm.y);
        float br = 0.5f * (Zb.y + Zm.y);
        float bi = 0.5f * (Zm.x - Zb.x);
        Po[bin] = make_float2(ar * br - ai * bi, ar * bi + ai * br);
        // packed Kf write (in place over Kraw; all krow reads happened above)
        if (bin == 0)        krow[0] = ar;
        else if (bin == 512) krow[1] = ar;
        else { krow[2 * bin] = ar; krow[2 * bin + 1] = ai; }
    }
}

// ---------------------------------------------------------------------------
// Cumsum pass 1: in-place local cumsum within each t-chunk + chunk totals.
// ---------------------------------------------------------------------------
__global__ __launch_bounds__(256) void cumsum_local(
        float* __restrict__ S, float* __restrict__ totals) {
    const int c = blockIdx.x * 256 + threadIdx.x;
    if (c >= CCH) return;
    const int chunk = blockIdx.y;
    const int b = blockIdx.z;
    size_t p = ((size_t)b * L_SZ + (size_t)chunk * TLEN) * CCH + c;
    float acc = 0.0f;
    #pragma unroll 4
    for (int t = 0; t < TLEN; t++) {
        acc += S[p];
        S[p] = acc;
        p += CCH;
    }
    totals[((size_t)b * TCH + chunk) * CCH + c] = acc;
}

// Pass 2: turn chunk totals into EXCLUSIVE prefix offsets (in place).
__global__ __launch_bounds__(256) void scan_totals(float* __restrict__ totals) {
    const int c = blockIdx.x * 256 + threadIdx.x;
    if (c >= CCH) return;
    const int b = blockIdx.y;
    float acc = 0.0f;
    for (int ch = 0; ch < TCH; ch++) {
        size_t idx = ((size_t)b * TCH + ch) * CCH + c;
        float v = totals[idx];
        totals[idx] = acc;
        acc += v;
    }
}

// ---------------------------------------------------------------------------
// Unbind: read packed Kf (stored by bind), Rf = (S_local+off)*conj(Kf),
// Hermitian extend, inverse FFT, /sqrt(t+1), LayerNorm -> bf16 RLN.
// (No forward FFT, no key re-normalization — bind already did both.)
// ---------------------------------------------------------------------------
__global__ __launch_bounds__(256) void unbind_ln_kernel(
        const float* __restrict__ P, const float* __restrict__ totals,
        const float* __restrict__ KF,
        const float* __restrict__ ln_g, const float* __restrict__ ln_b,
        unsigned short* __restrict__ RLNb) {
    __shared__ float2 bA[1024], bB[1024];
    __shared__ float red1[256], red2[256];
    const int token = blockIdx.x;
    const int tid = threadIdx.x;
    const int b = token >> 12;
    const int t = token & (L_SZ - 1);
    const int chunk = t >> 7;

    const float* kfrow   = KF + (size_t)token * D_SZ;
    const float2* Srow   = (const float2*)(P + (size_t)token * CCH);
    const float2* offrow = (const float2*)(totals + ((size_t)b * TCH + chunk) * CCH);
    #pragma unroll
    for (int e = 0; e < 3; e++) {
        const int bin = tid + (e << 8);
        if (bin < NBINS) {
            float kr, ki;
            if (bin == 0)        { kr = kfrow[0]; ki = 0.0f; }
            else if (bin == 512) { kr = kfrow[1]; ki = 0.0f; }
            else { float2 kf2 = *(const float2*)(kfrow + 2 * bin); kr = kf2.x; ki = kf2.y; }
            float2 s2 = Srow[bin];
            float2 o2 = offrow[bin];
            float sr = s2.x + o2.x, si = s2.y + o2.y;
            bA[SWZ(bin)] = make_float2(sr * kr + si * ki, si * kr - sr * ki);
        }
    }
    __syncthreads();
    for (int n = 513 + tid; n < 1024; n += 256) {
        float2 c = bA[SWZ(1024 - n)];
        bA[SWZ(n)] = make_float2(c.x, -c.y);
    }
    __syncthreads();

    cplx rz[4];
    #pragma unroll
    for (int k = 0; k < 4; k++) {
        float2 c = bA[SWZ(tid + (k << 8))];
        rz[k] = {c.x, c.y};
    }
    __syncthreads();
    fft1024_r<1>(bA, bB, rz, tid);      // rz[e].r = r[tid + 256e] * 1024

    const float posscale = (1.0f / 1024.0f) * rsqrtf((float)(t + 1));
    float rv[4];
    float sum = 0.0f, sumsq = 0.0f;
    #pragma unroll
    for (int e = 0; e < 4; e++) {
        float v = rz[e].r * posscale;
        rv[e] = v;
        sum += v;
        sumsq += v * v;
    }
    red1[tid] = sum; red2[tid] = sumsq;
    __syncthreads();
    for (int sft = 128; sft > 0; sft >>= 1) {
        if (tid < sft) { red1[tid] += red1[tid + sft]; red2[tid] += red2[tid + sft]; }
        __syncthreads();
    }
    const float mu = red1[0] * (1.0f / 1024.0f);
    const float var = red2[0] * (1.0f / 1024.0f) - mu * mu;
    const float rstd = rsqrtf(var + 1e-5f);

    unsigned short* outp = RLNb + (size_t)token * D_SZ;
    #pragma unroll
    for (int e = 0; e < 4; e++) {
        const int d = tid + (e << 8);
        outp[d] = f2bf((rv[e] - mu) * rstd * ln_g[d] + ln_b[d]);
    }
}

// ---------------------------------------------------------------------------
// Workspace (bytes):
//   Kraw   fp32 M*D    = 64.0 MB  (keys; bind overwrites in place with packed Kf)
//   V      fp32 M*D    = 64.0 MB  (dead after bind; reused as bf16 RLN)
//   P      fp32 M*CCH  = 67.2 MB  (local cumsum in place)
//   totals fp32        =  0.5 MB
//   xb     bf16 M*D    = 32.0 MB
//   WB     bf16 2048*D =  4.0 MB  (Wk ++ Wv, concatenated)
//   Wob    bf16 D*D    =  2.0 MB
//   total ~= 234 MB
// ---------------------------------------------------------------------------
extern "C" void kernel_launch(void* const* d_in, const int* in_sizes, int n_in,
                              void* d_out, int out_size, void* d_ws, size_t ws_size,
                              hipStream_t stream) {
    (void)in_sizes; (void)n_in; (void)out_size; (void)ws_size;
    const float* x    = (const float*)d_in[0];
    const float* Wk   = (const float*)d_in[1];
    const float* bk   = (const float*)d_in[2];
    const float* Wv   = (const float*)d_in[3];
    const float* bv   = (const float*)d_in[4];
    const float* ln_g = (const float*)d_in[5];
    const float* ln_b = (const float*)d_in[6];
    const float* Wo   = (const float*)d_in[7];
    const float* bo   = (const float*)d_in[8];
    float* out = (float*)d_out;

    char* w = (char*)d_ws;
    float* Kraw   = (float*)w;  w += (size_t)M_SZ * D_SZ * 4;
    float* V      = (float*)w;  w += (size_t)M_SZ * D_SZ * 4;
    float* P      = (float*)w;  w += (size_t)M_SZ * CCH * 4;
    float* totals = (float*)w;  w += (size_t)B_SZ * TCH * CCH * 4;
    unsigned short* xb  = (unsigned short*)w;  w += (size_t)M_SZ * D_SZ * 2;
    unsigned short* WB  = (unsigned short*)w;  w += (size_t)2 * D_SZ * D_SZ * 2;
    unsigned short* Wob = (unsigned short*)w;  w += (size_t)D_SZ * D_SZ * 2;
    unsigned short* RLNb = (unsigned short*)V;  // overlays dead V

    const int n8x = M_SZ * D_SZ / 8;
    const int n8w = D_SZ * D_SZ / 8;
    cast_f32_bf16<<<n8x / 256, 256, 0, stream>>>(x,  xb,  n8x);
    cast_f32_bf16<<<n8w / 256, 256, 0, stream>>>(Wk, WB,                  n8w);
    cast_f32_bf16<<<n8w / 256, 256, 0, stream>>>(Wv, WB + D_SZ * D_SZ,    n8w);
    cast_f32_bf16<<<n8w / 256, 256, 0, stream>>>(Wo, Wob, n8w);

    // fused K/V projection: N=2048 (first half -> Kraw, second -> V)
    gemm_mfma<16><<<(M_SZ / GBM) * 16, 256, 0, stream>>>(
        xb, WB, bk, bv, nullptr, Kraw, V, M_SZ, D_SZ);

    bind_fft_kernel<<<M_SZ, 256, 0, stream>>>(Kraw, V, P);

    dim3 cgrid((CCH + 255) / 256, TCH, B_SZ);
    cumsum_local<<<cgrid, 256, 0, stream>>>(P, totals);
    dim3 sgrid((CCH + 255) / 256, B_SZ);
    scan_totals<<<sgrid, 256, 0, stream>>>(totals);

    unbind_ln_kernel<<<M_SZ, 256, 0, stream>>>(P, totals, Kraw, ln_g, ln_b, RLNb);

    // output GEMM with fp32 residual
    gemm_mfma<8><<<(M_SZ / GBM) * 8, 256, 0, stream>>>(
        RLNb, Wob, bo, bo, x, out, out, M_SZ, D_SZ);
}

// Round 3
// 439.808 us; speedup vs baseline: 1.1514x; 1.0451x over previous
//
#include <hip/hip_runtime.h>
#include <math.h>

// Problem constants (from reference): B=4, L=4096, D=1024
#define B_SZ 4
#define L_SZ 4096
#define D_SZ 1024
#define M_SZ (B_SZ * L_SZ)      // 16384 tokens
#define NBINS 513               // rfft bins for D=1024
#define CCH   (2 * NBINS)       // 1026 float channels per token (interleaved re,im)
#define TCH 32                  // cumsum chunks over L
#define TLEN (L_SZ / TCH)       // 128 timesteps per chunk

typedef short bf16x8 __attribute__((ext_vector_type(8)));
typedef float f32x4  __attribute__((ext_vector_type(4)));
typedef unsigned short us8 __attribute__((ext_vector_type(8)));

#define AS1 __attribute__((address_space(1)))
#define AS3 __attribute__((address_space(3)))

// round-to-nearest-even f32 -> bf16
__device__ inline unsigned short f2bf(float f) {
    unsigned int u = __float_as_uint(f);
    u += 0x7fffu + ((u >> 16) & 1u);
    return (unsigned short)(u >> 16);
}

// ---------------------------------------------------------------------------
// f32 -> bf16 cast, 8 elements/thread
// ---------------------------------------------------------------------------
__global__ __launch_bounds__(256) void cast_f32_bf16(
        const float* __restrict__ in, unsigned short* __restrict__ out, int n8) {
    int i = blockIdx.x * 256 + threadIdx.x;
    if (i >= n8) return;
    const float4* p = (const float4*)in + 2 * (size_t)i;
    float4 a = p[0], b = p[1];
    us8 o;
    o[0] = f2bf(a.x); o[1] = f2bf(a.y); o[2] = f2bf(a.z); o[3] = f2bf(a.w);
    o[4] = f2bf(b.x); o[5] = f2bf(b.y); o[6] = f2bf(b.z); o[7] = f2bf(b.w);
    *(us8*)(out + (size_t)i * 8) = o;
}

// ---------------------------------------------------------------------------
// 256x256 8-phase bf16 MFMA GEMM (m201-style template), BK=64, 512 threads
// (8 waves = 2Mx4N), 128 KiB LDS (2 K-tile slots), counted vmcnt(6).
//
// A: M x K bf16.  W: (CNT*256) x K bf16 (torch Linear layout). K = 1024.
// Logical N split into halves of 1024: cols [0,1024)->C0/bias0, else C1/bias1.
//
// Per K-tile (BK=64): 4 phases = C-quadrants (mh,nh) of the per-wave 128x64
// output; each phase: {ds_read reg subtile | stage 1 half-tile | barrier |
// lgkmcnt(0) | setprio(1) 16 MFMA setprio(0) | barrier}.
// Stage placement (one phase after each LDS region's last read):
//   r0: (cur+1) A-hi  (slot^1)     r1: (cur+2) A-lo (slot)
//   r2: (cur+2) B-lo  (slot)       r3: (cur+2) B-hi (slot)
// vmcnt(6) at r3 end: allows exactly the 3 halves staged at r1/r2/r3
// outstanding -> forces all 4 halves of tile cur+1 resident.
// LDS swizzle: linear dest (global_load_lds requirement), pre-swizzled
// global source slot (lane&7)^((row)&7), ds_read applies the same XOR.
// ---------------------------------------------------------------------------
template<int CNT>   // number of 256-wide column tiles; total N = CNT*256
__global__ __launch_bounds__(512, 2) void gemm_mfma256(
        const unsigned short* __restrict__ A, const unsigned short* __restrict__ W,
        const float* __restrict__ bias0, const float* __restrict__ bias1,
        const float* __restrict__ resid,
        float* __restrict__ C0, float* __restrict__ C1, int M, int K) {
    __shared__ unsigned short Abuf[2][256 * 64];   // 2 x 32 KiB
    __shared__ unsigned short Bbuf[2][256 * 64];   // 2 x 32 KiB
    const int id   = blockIdx.x;
    const int bx   = (id >> 3) % CNT;
    const int by   = (id & 7) + 8 * (id / (8 * CNT));
    const int tid  = threadIdx.x;
    const int lane = tid & 63;
    const int wid  = tid >> 6;        // 0..7
    const int wr   = wid >> 2;        // 0..1  (M direction, 128 rows each)
    const int wc   = wid & 3;         // 0..3  (N direction, 64 cols each)
    const int bm   = by * 256;
    const int bn   = bx * 256;

    const int fr   = lane & 15;
    const int kq   = lane >> 4;               // 0..3
    const int xorv = (fr & 7) << 4;           // byte XOR for swizzled ds_read

    // staging geometry: 512 threads x 16B = 8 KiB = 64 rows per chunk;
    // thread covers (row = row0 + tid>>3, slot = tid&7); source slot
    // pre-swizzled so linear LDS holds slot s at position s^(row&7).
    const int strow = tid >> 3;
    const int sslot = (tid & 7) ^ ((tid >> 3) & 7);

    auto stageA = [&](int slot, int row0, int kk) {
        const int row = row0 + strow;
        const unsigned short* src = A + (size_t)(bm + row) * K + kk + sslot * 8;
        __builtin_amdgcn_global_load_lds((const AS1 unsigned int*)src,
            (AS3 unsigned int*)(&Abuf[slot][row * 64 + (tid & 7) * 8]), 16, 0, 0);
    };
    auto stageB = [&](int slot, int row0, int kk) {
        const int row = row0 + strow;
        const unsigned short* src = W + (size_t)(bn + row) * K + kk + sslot * 8;
        __builtin_amdgcn_global_load_lds((const AS1 unsigned int*)src,
            (AS3 unsigned int*)(&Bbuf[slot][row * 64 + (tid & 7) * 8]), 16, 0, 0);
    };
    // half-tiles (16 KiB each, 2 chunks): A-lo = rows {0-63,128-191} (read at
    // phase mh0 by waves wr=0/1), A-hi = {64-127,192-255} (phase mh1);
    // B-lo = rows 0-127, B-hi = rows 128-255.
    auto H_Alo = [&](int slot, int kk){ stageA(slot,   0, kk); stageA(slot, 128, kk); };
    auto H_Ahi = [&](int slot, int kk){ stageA(slot,  64, kk); stageA(slot, 192, kk); };
    auto H_Blo = [&](int slot, int kk){ stageB(slot,   0, kk); stageB(slot,  64, kk); };
    auto H_Bhi = [&](int slot, int kk){ stageB(slot, 128, kk); stageB(slot, 192, kk); };

    bf16x8 a[4][2];         // current mh half: 4 m-frags x 2 k-subs
    bf16x8 b[2][2][2];      // [nh][nf][ks], both nh halves live
    f32x4 acc[8][4] = {};   // [mi][ni]

    auto loadA = [&](int slot, int mh) {
        #pragma unroll
        for (int mf = 0; mf < 4; mf++) {
            const int row = wr * 128 + mh * 64 + mf * 16 + fr;
            #pragma unroll
            for (int ks = 0; ks < 2; ks++) {
                const int off = row * 128 + ((((ks << 2) + kq) << 4) ^ xorv);
                a[mf][ks] = *(const bf16x8*)((const char*)&Abuf[slot][0] + off);
            }
        }
    };
    auto loadB = [&](int slot, int nh) {
        #pragma unroll
        for (int nf = 0; nf < 2; nf++) {
            const int row = wc * 64 + nh * 32 + nf * 16 + fr;
            #pragma unroll
            for (int ks = 0; ks < 2; ks++) {
                const int off = row * 128 + ((((ks << 2) + kq) << 4) ^ xorv);
                b[nh][nf][ks] = *(const bf16x8*)((const char*)&Bbuf[slot][0] + off);
            }
        }
    };
    auto mmaq = [&](int mh, int nh) {
        __builtin_amdgcn_s_setprio(1);
        #pragma unroll
        for (int mf = 0; mf < 4; mf++)
            #pragma unroll
            for (int nf = 0; nf < 2; nf++)
                #pragma unroll
                for (int ks = 0; ks < 2; ks++)
                    acc[mh * 4 + mf][nh * 2 + nf] =
                        __builtin_amdgcn_mfma_f32_16x16x32_bf16(
                            a[mf][ks], b[nh][nf][ks],
                            acc[mh * 4 + mf][nh * 2 + nf], 0, 0, 0);
        __builtin_amdgcn_s_setprio(0);
    };

#define BARX  do { asm volatile("" ::: "memory"); __builtin_amdgcn_s_barrier(); \
                   asm volatile("" ::: "memory"); } while (0)
#define LGKM0 asm volatile("s_waitcnt lgkmcnt(0)" ::: "memory")

    const int nt = K >> 6;   // K-tiles of 64
    // prologue: tile0 full + tile1 {A-lo, B-lo, B-hi}; last 6 loads may fly
    H_Alo(0, 0); H_Blo(0, 0); H_Bhi(0, 0); H_Ahi(0, 0);
    H_Alo(1, 64); H_Blo(1, 64); H_Bhi(1, 64);
    asm volatile("s_waitcnt vmcnt(6)" ::: "memory");
    BARX;

    for (int cur = 0; cur < nt; ++cur) {
        const int slot = cur & 1;
        const int kk1 = (cur + 1) << 6;
        const int kk2 = (cur + 2) << 6;
        // ---- r0: quadrant (mh0, nh0)
        loadA(slot, 0); loadB(slot, 0);
        if (cur + 1 < nt) H_Ahi(slot ^ 1, kk1);
        BARX; LGKM0;
        mmaq(0, 0);
        BARX;
        // ---- r1: quadrant (mh0, nh1)
        loadB(slot, 1);
        if (cur + 2 < nt) H_Alo(slot, kk2);
        BARX; LGKM0;
        mmaq(0, 1);
        BARX;
        // ---- r2: quadrant (mh1, nh0)
        loadA(slot, 1);
        if (cur + 2 < nt) H_Blo(slot, kk2);
        BARX; LGKM0;
        mmaq(1, 0);
        BARX;
        // ---- r3: quadrant (mh1, nh1)
        if (cur + 2 < nt) H_Bhi(slot, kk2);
        BARX; LGKM0;
        mmaq(1, 1);
        if (cur + 2 < nt) { asm volatile("s_waitcnt vmcnt(6)" ::: "memory"); }
        else              { asm volatile("s_waitcnt vmcnt(0)" ::: "memory"); }
        BARX;
    }
#undef BARX
#undef LGKM0

    const int col0 = lane & 15;
    const int quad = lane >> 4;
    #pragma unroll
    for (int ni = 0; ni < 4; ni++) {
        const int ng = bn + wc * 64 + ni * 16 + col0;   // global col in [0, CNT*256)
        const int half = ng >> 10;                      // wave-uniform per ni
        const int n = ng & 1023;
        float* __restrict__ Cp = half ? C1 : C0;
        const float bv = half ? bias1[n] : bias0[n];
        #pragma unroll
        for (int mi = 0; mi < 8; mi++) {
            #pragma unroll
            for (int r = 0; r < 4; r++) {
                const int m = bm + wr * 128 + mi * 16 + quad * 4 + r;
                float v = acc[mi][ni][r] + bv;
                size_t off = (size_t)m * 1024 + n;
                if (resid) v += resid[off];
                Cp[off] = v;
            }
        }
    }
}

// ---------------------------------------------------------------------------
// Stockham radix-4 1024-pt FFT. 256 threads, 4 complex/thread in registers,
// 5 stages, exchanges via two swizzled float2 LDS buffers (conflict-free).
// ---------------------------------------------------------------------------
#define SWZ(a) ((a) ^ (((a) >> 4) & 15))

struct cplx { float r, i; };
__device__ inline cplx cmul(cplx a, cplx b) {
    return {a.r * b.r - a.i * b.i, a.r * b.i + a.i * b.r};
}

__device__ inline void r4bfly(cplx v[4], float s) {
    cplx t0 {v[0].r + v[2].r, v[0].i + v[2].i};
    cplx t1 {v[0].r - v[2].r, v[0].i - v[2].i};
    cplx t2 {v[1].r + v[3].r, v[1].i + v[3].i};
    cplx t3 {v[1].r - v[3].r, v[1].i - v[3].i};
    cplx j3 {-s * t3.i, s * t3.r};     // s*i * t3
    v[0] = {t0.r + t2.r, t0.i + t2.i};
    v[2] = {t0.r - t2.r, t0.i - t2.i};
    v[1] = {t1.r + j3.r, t1.i + j3.i};
    v[3] = {t1.r - j3.r, t1.i - j3.i};
}

template<int SIGN>
__device__ inline void fft1024_r(float2* bA, float2* bB, cplx v[4], int tid) {
    const float s = (float)SIGN;
    r4bfly(v, s);
    {
        const int base = tid << 2;
        #pragma unroll
        for (int e = 0; e < 4; e++)
            bA[SWZ(base + e)] = make_float2(v[e].r, v[e].i);
    }
    __syncthreads();
    float2* cur = bA;
    float2* nxt = bB;
    #pragma unroll
    for (int q = 1; q <= 3; q++) {
        const int Ls = 1 << (2 * q);
        #pragma unroll
        for (int k = 0; k < 4; k++) {
            float2 t = cur[SWZ(tid + (k << 8))];
            v[k] = {t.x, t.y};
        }
        const int d = tid & (Ls - 1);
        const float ang = s * 1.57079632679489662f * (float)d / (float)Ls;
        float sn, cs; __sincosf(ang, &sn, &cs);
        cplx w1 {cs, sn};
        cplx w2 = cmul(w1, w1);
        cplx w3 = cmul(w2, w1);
        v[1] = cmul(v[1], w1);
        v[2] = cmul(v[2], w2);
        v[3] = cmul(v[3], w3);
        r4bfly(v, s);
        const int base = ((tid >> (2 * q)) << (2 * q + 2)) + d;
        #pragma unroll
        for (int e = 0; e < 4; e++)
            nxt[SWZ(base + (e << (2 * q)))] = make_float2(v[e].r, v[e].i);
        float2* tmp = cur; cur = nxt; nxt = tmp;
        __syncthreads();
    }
    #pragma unroll
    for (int k = 0; k < 4; k++) {
        float2 t = cur[SWZ(tid + (k << 8))];
        v[k] = {t.x, t.y};
    }
    {
        const float ang = s * 1.57079632679489662f * (float)tid / 256.0f;
        float sn, cs; __sincosf(ang, &sn, &cs);
        cplx w1 {cs, sn};
        cplx w2 = cmul(w1, w1);
        cplx w3 = cmul(w2, w1);
        v[1] = cmul(v[1], w1);
        v[2] = cmul(v[2], w2);
        v[3] = cmul(v[3], w3);
        r4bfly(v, s);
    }
}

// ---------------------------------------------------------------------------
// Bind: normalize keys, pack z = k_hat + i*v, one forward FFT, unpack the two
// real-signal spectra (Kf even part, Vf odd part), write P = Kf*Vf AND write
// Kf packed IN PLACE over the (now dead) Kraw row: float[0]=Kf[0].re,
// float[1]=Kf[512].re, float[2b],[2b+1]=Kf[b] for b=1..511 -> exactly 1024
// floats. Unbind then needs no forward FFT at all.
// ---------------------------------------------------------------------------
__global__ __launch_bounds__(256) void bind_fft_kernel(
        float* __restrict__ KIO, const float* __restrict__ V,
        float* __restrict__ P) {
    __shared__ float2 bA[1024], bB[1024];
    __shared__ float red[256];
    const int token = blockIdx.x;
    const int tid = threadIdx.x;

    float* krow = KIO + (size_t)token * D_SZ;
    const float* vrow = V + (size_t)token * D_SZ;
    float kv[4], vv[4];
    float ss = 0.0f;
    #pragma unroll
    for (int k = 0; k < 4; k++) {
        kv[k] = krow[tid + (k << 8)];
        vv[k] = vrow[tid + (k << 8)];
        ss += kv[k] * kv[k];
    }
    red[tid] = ss;
    __syncthreads();
    for (int sft = 128; sft > 0; sft >>= 1) {
        if (tid < sft) red[tid] += red[tid + sft];
        __syncthreads();
    }
    const float scale = 1.0f / fmaxf(sqrtf(red[0]), 1e-12f);

    cplx z[4];
    #pragma unroll
    for (int k = 0; k < 4; k++) z[k] = {kv[k] * scale, vv[k]};

    __syncthreads();
    fft1024_r<-1>(bA, bB, z, tid);

    #pragma unroll
    for (int e = 0; e < 4; e++)
        bA[SWZ(tid + (e << 8))] = make_float2(z[e].r, z[e].i);
    __syncthreads();

    float2* Po = (float2*)(P + (size_t)token * CCH);
    for (int bin = tid; bin < NBINS; bin += 256) {
        float2 Zb = bA[SWZ(bin)];
        float2 Zm = bA[SWZ((1024 - bin) & 1023)];
        float ar = 0.5f * (Zb.x + Zm.x);
        float ai = 0.5f * (Zb.y - Zm.y);
        float br = 0.5f * (Zb.y + Zm.y);
        float bi = 0.5f * (Zm.x - Zb.x);
        Po[bin] = make_float2(ar * br - ai * bi, ar * bi + ai * br);
        // packed Kf write (in place over Kraw; all krow reads happened above)
        if (bin == 0)        krow[0] = ar;
        else if (bin == 512) krow[1] = ar;
        else { krow[2 * bin] = ar; krow[2 * bin + 1] = ai; }
    }
}

// ---------------------------------------------------------------------------
// Cumsum pass 1: in-place local cumsum within each t-chunk + chunk totals.
// ---------------------------------------------------------------------------
__global__ __launch_bounds__(256) void cumsum_local(
        float* __restrict__ S, float* __restrict__ totals) {
    const int c = blockIdx.x * 256 + threadIdx.x;
    if (c >= CCH) return;
    const int chunk = blockIdx.y;
    const int b = blockIdx.z;
    size_t p = ((size_t)b * L_SZ + (size_t)chunk * TLEN) * CCH + c;
    float acc = 0.0f;
    #pragma unroll 4
    for (int t = 0; t < TLEN; t++) {
        acc += S[p];
        S[p] = acc;
        p += CCH;
    }
    totals[((size_t)b * TCH + chunk) * CCH + c] = acc;
}

// Pass 2: turn chunk totals into EXCLUSIVE prefix offsets (in place).
__global__ __launch_bounds__(256) void scan_totals(float* __restrict__ totals) {
    const int c = blockIdx.x * 256 + threadIdx.x;
    if (c >= CCH) return;
    const int b = blockIdx.y;
    float acc = 0.0f;
    for (int ch = 0; ch < TCH; ch++) {
        size_t idx = ((size_t)b * TCH + ch) * CCH + c;
        float v = totals[idx];
        totals[idx] = acc;
        acc += v;
    }
}

// ---------------------------------------------------------------------------
// Unbind: read packed Kf (stored by bind), Rf = (S_local+off)*conj(Kf),
// Hermitian extend, inverse FFT, /sqrt(t+1), LayerNorm -> bf16 RLN.
// (No forward FFT, no key re-normalization — bind already did both.)
// ---------------------------------------------------------------------------
__global__ __launch_bounds__(256) void unbind_ln_kernel(
        const float* __restrict__ P, const float* __restrict__ totals,
        const float* __restrict__ KF,
        const float* __restrict__ ln_g, const float* __restrict__ ln_b,
        unsigned short* __restrict__ RLNb) {
    __shared__ float2 bA[1024], bB[1024];
    __shared__ float red1[256], red2[256];
    const int token = blockIdx.x;
    const int tid = threadIdx.x;
    const int b = token >> 12;
    const int t = token & (L_SZ - 1);
    const int chunk = t >> 7;

    const float* kfrow   = KF + (size_t)token * D_SZ;
    const float2* Srow   = (const float2*)(P + (size_t)token * CCH);
    const float2* offrow = (const float2*)(totals + ((size_t)b * TCH + chunk) * CCH);
    #pragma unroll
    for (int e = 0; e < 3; e++) {
        const int bin = tid + (e << 8);
        if (bin < NBINS) {
            float kr, ki;
            if (bin == 0)        { kr = kfrow[0]; ki = 0.0f; }
            else if (bin == 512) { kr = kfrow[1]; ki = 0.0f; }
            else { float2 kf2 = *(const float2*)(kfrow + 2 * bin); kr = kf2.x; ki = kf2.y; }
            float2 s2 = Srow[bin];
            float2 o2 = offrow[bin];
            float sr = s2.x + o2.x, si = s2.y + o2.y;
            bA[SWZ(bin)] = make_float2(sr * kr + si * ki, si * kr - sr * ki);
        }
    }
    __syncthreads();
    for (int n = 513 + tid; n < 1024; n += 256) {
        float2 c = bA[SWZ(1024 - n)];
        bA[SWZ(n)] = make_float2(c.x, -c.y);
    }
    __syncthreads();

    cplx rz[4];
    #pragma unroll
    for (int k = 0; k < 4; k++) {
        float2 c = bA[SWZ(tid + (k << 8))];
        rz[k] = {c.x, c.y};
    }
    __syncthreads();
    fft1024_r<1>(bA, bB, rz, tid);      // rz[e].r = r[tid + 256e] * 1024

    const float posscale = (1.0f / 1024.0f) * rsqrtf((float)(t + 1));
    float rv[4];
    float sum = 0.0f, sumsq = 0.0f;
    #pragma unroll
    for (int e = 0; e < 4; e++) {
        float v = rz[e].r * posscale;
        rv[e] = v;
        sum += v;
        sumsq += v * v;
    }
    red1[tid] = sum; red2[tid] = sumsq;
    __syncthreads();
    for (int sft = 128; sft > 0; sft >>= 1) {
        if (tid < sft) { red1[tid] += red1[tid + sft]; red2[tid] += red2[tid + sft]; }
        __syncthreads();
    }
    const float mu = red1[0] * (1.0f / 1024.0f);
    const float var = red2[0] * (1.0f / 1024.0f) - mu * mu;
    const float rstd = rsqrtf(var + 1e-5f);

    unsigned short* outp = RLNb + (size_t)token * D_SZ;
    #pragma unroll
    for (int e = 0; e < 4; e++) {
        const int d = tid + (e << 8);
        outp[d] = f2bf((rv[e] - mu) * rstd * ln_g[d] + ln_b[d]);
    }
}

// ---------------------------------------------------------------------------
// Workspace (bytes):
//   Kraw   fp32 M*D    = 64.0 MB  (keys; bind overwrites in place with packed Kf)
//   V      fp32 M*D    = 64.0 MB  (dead after bind; reused as bf16 RLN)
//   P      fp32 M*CCH  = 67.2 MB  (local cumsum in place)
//   totals fp32        =  0.5 MB
//   xb     bf16 M*D    = 32.0 MB
//   WB     bf16 2048*D =  4.0 MB  (Wk ++ Wv, concatenated)
//   Wob    bf16 D*D    =  2.0 MB
//   total ~= 234 MB
// ---------------------------------------------------------------------------
extern "C" void kernel_launch(void* const* d_in, const int* in_sizes, int n_in,
                              void* d_out, int out_size, void* d_ws, size_t ws_size,
                              hipStream_t stream) {
    (void)in_sizes; (void)n_in; (void)out_size; (void)ws_size;
    const float* x    = (const float*)d_in[0];
    const float* Wk   = (const float*)d_in[1];
    const float* bk   = (const float*)d_in[2];
    const float* Wv   = (const float*)d_in[3];
    const float* bv   = (const float*)d_in[4];
    const float* ln_g = (const float*)d_in[5];
    const float* ln_b = (const float*)d_in[6];
    const float* Wo   = (const float*)d_in[7];
    const float* bo   = (const float*)d_in[8];
    float* out = (float*)d_out;

    char* w = (char*)d_ws;
    float* Kraw   = (float*)w;  w += (size_t)M_SZ * D_SZ * 4;
    float* V      = (float*)w;  w += (size_t)M_SZ * D_SZ * 4;
    float* P      = (float*)w;  w += (size_t)M_SZ * CCH * 4;
    float* totals = (float*)w;  w += (size_t)B_SZ * TCH * CCH * 4;
    unsigned short* xb  = (unsigned short*)w;  w += (size_t)M_SZ * D_SZ * 2;
    unsigned short* WB  = (unsigned short*)w;  w += (size_t)2 * D_SZ * D_SZ * 2;
    unsigned short* Wob = (unsigned short*)w;  w += (size_t)D_SZ * D_SZ * 2;
    unsigned short* RLNb = (unsigned short*)V;  // overlays dead V

    const int n8x = M_SZ * D_SZ / 8;
    const int n8w = D_SZ * D_SZ / 8;
    cast_f32_bf16<<<n8x / 256, 256, 0, stream>>>(x,  xb,  n8x);
    cast_f32_bf16<<<n8w / 256, 256, 0, stream>>>(Wk, WB,                  n8w);
    cast_f32_bf16<<<n8w / 256, 256, 0, stream>>>(Wv, WB + D_SZ * D_SZ,    n8w);
    cast_f32_bf16<<<n8w / 256, 256, 0, stream>>>(Wo, Wob, n8w);

    // fused K/V projection: N=2048 (first half -> Kraw, second -> V)
    gemm_mfma256<8><<<(M_SZ / 256) * 8, 512, 0, stream>>>(
        xb, WB, bk, bv, nullptr, Kraw, V, M_SZ, D_SZ);

    bind_fft_kernel<<<M_SZ, 256, 0, stream>>>(Kraw, V, P);

    dim3 cgrid((CCH + 255) / 256, TCH, B_SZ);
    cumsum_local<<<cgrid, 256, 0, stream>>>(P, totals);
    dim3 sgrid((CCH + 255) / 256, B_SZ);
    scan_totals<<<sgrid, 256, 0, stream>>>(totals);

    unbind_ln_kernel<<<M_SZ, 256, 0, stream>>>(P, totals, Kraw, ln_g, ln_b, RLNb);

    // output GEMM with fp32 residual
    gemm_mfma256<4><<<(M_SZ / 256) * 4, 512, 0, stream>>>(
        RLNb, Wob, bo, bo, x, out, out, M_SZ, D_SZ);
}

// Round 4
// 426.894 us; speedup vs baseline: 1.1862x; 1.0303x over previous
//
#include <hip/hip_runtime.h>
#include <math.h>

// Problem constants (from reference): B=4, L=4096, D=1024
#define B_SZ 4
#define L_SZ 4096
#define D_SZ 1024
#define M_SZ (B_SZ * L_SZ)      // 16384 tokens
#define NBINS 513               // rfft bins for D=1024
#define CCH   (2 * NBINS)       // 1026 float channels per token (interleaved re,im)
#define TCH 32                  // cumsum chunks over L
#define TLEN (L_SZ / TCH)       // 128 timesteps per chunk

typedef short bf16x8 __attribute__((ext_vector_type(8)));
typedef float f32x4  __attribute__((ext_vector_type(4)));
typedef unsigned short us8 __attribute__((ext_vector_type(8)));

#define AS1 __attribute__((address_space(1)))
#define AS3 __attribute__((address_space(3)))

// round-to-nearest-even f32 -> bf16
__device__ inline unsigned short f2bf(float f) {
    unsigned int u = __float_as_uint(f);
    u += 0x7fffu + ((u >> 16) & 1u);
    return (unsigned short)(u >> 16);
}

// ---------------------------------------------------------------------------
// f32 -> bf16 cast, 8 elements/thread
// ---------------------------------------------------------------------------
__global__ __launch_bounds__(256) void cast_f32_bf16(
        const float* __restrict__ in, unsigned short* __restrict__ out, int n8) {
    int i = blockIdx.x * 256 + threadIdx.x;
    if (i >= n8) return;
    const float4* p = (const float4*)in + 2 * (size_t)i;
    float4 a = p[0], b = p[1];
    us8 o;
    o[0] = f2bf(a.x); o[1] = f2bf(a.y); o[2] = f2bf(a.z); o[3] = f2bf(a.w);
    o[4] = f2bf(b.x); o[5] = f2bf(b.y); o[6] = f2bf(b.z); o[7] = f2bf(b.w);
    *(us8*)(out + (size_t)i * 8) = o;
}

// merged weight casts: blockIdx.y selects {Wk->WB, Wv->WB+1M, Wo->Wob}
__global__ __launch_bounds__(256) void cast_w3(
        const float* __restrict__ Wk, const float* __restrict__ Wv,
        const float* __restrict__ Wo,
        unsigned short* __restrict__ WB, unsigned short* __restrict__ Wob, int n8) {
    int i = blockIdx.x * 256 + threadIdx.x;
    if (i >= n8) return;
    const int which = blockIdx.y;
    const float* src = (which == 0) ? Wk : (which == 1) ? Wv : Wo;
    unsigned short* dst = (which == 0) ? WB : (which == 1) ? (WB + D_SZ * D_SZ) : Wob;
    const float4* p = (const float4*)src + 2 * (size_t)i;
    float4 a = p[0], b = p[1];
    us8 o;
    o[0] = f2bf(a.x); o[1] = f2bf(a.y); o[2] = f2bf(a.z); o[3] = f2bf(a.w);
    o[4] = f2bf(b.x); o[5] = f2bf(b.y); o[6] = f2bf(b.z); o[7] = f2bf(b.w);
    *(us8*)(dst + (size_t)i * 8) = o;
}

// ---------------------------------------------------------------------------
// bf16 MFMA GEMM, 256x128 tile, BK=32, 3 LDS slots (72 KiB -> 2 blocks/CU),
// 512 threads = 8 waves (2M x 4N), per-wave 128x32 output.
//
// Round 4 rationale: rounds 1-3 showed the inner-loop structure is NOT the
// limiter (112-132us across 3 structures, MfmaUtil ~11%, everything idle);
// the shared trait was 1 block/CU lockstep. This version targets block-level
// TLP: 2 co-resident blocks/CU cover each other's vmcnt/barrier/epilogue
// stalls. One barrier + one counted vmcnt(3) per K-tile; tile cur stages ALL
// 3 chunks (A-lo, A-hi, B) of tile cur+2 into slot (cur+2)%3 — that slot's
// tile-(cur-1) reads drained before the previous barrier, so no races.
//
// LDS layout (both-sides swizzle, rule 21): each 128-B line holds TWO rows
// (2l, 2l+1) of 32 k-shorts; 16-B slot s of line l stores logical slot
// s^(l&7) where logical slot q = (row&1)*4 + k8. Global source pre-applies
// the same XOR so the linear global_load_lds dest ends up correct. ds_read
// banks: 16 lanes spread over all 8 slot-groups twice -> 2-way (free).
// Read addressing collapses to lane-constant base + mf*1024 immediates.
//
// A: M x K bf16. W: (CNT*128) x K bf16 (torch Linear layout). K=1024.
// Logical N split into halves of 1024: [0,1024)->C0/bias0, else C1/bias1.
// ---------------------------------------------------------------------------
template<int CNT>   // N = CNT*128
__global__ __launch_bounds__(512, 4) void gemm_mfma(
        const unsigned short* __restrict__ A, const unsigned short* __restrict__ W,
        const float* __restrict__ bias0, const float* __restrict__ bias1,
        const float* __restrict__ resid,
        float* __restrict__ C0, float* __restrict__ C1, int M, int K) {
    __shared__ unsigned short Abuf[3][256 * 32];   // 3 x 16 KiB
    __shared__ unsigned short Bbuf[3][128 * 32];   // 3 x  8 KiB
    const int id   = blockIdx.x;
    const int bx   = (id >> 3) % CNT;
    const int by   = (id & 7) + 8 * (id / (8 * CNT));
    const int tid  = threadIdx.x;
    const int lane = tid & 63;
    const int wid  = tid >> 6;        // 0..7
    const int wr   = wid >> 2;        // 0..1 (M, 128 rows)
    const int wc   = wid & 3;         // 0..3 (N, 32 cols)
    const int bm   = by * 256;
    const int bn   = bx * 128;

    // ---- staging geometry (one 8-KiB chunk = 128 rows x 32k per gll/thread)
    const int sl = tid >> 3;              // line 0..63 (2 rows each)
    const int sq = (tid & 7) ^ (sl & 7);  // logical slot at this dest position
    const int srow = 2 * sl + (sq >> 2);  // row within chunk
    const int skof = (sq & 3) * 8;        // k offset (shorts)
    const unsigned short* Abase = A + (size_t)(bm + srow) * K + skof;
    const unsigned short* Wbase = W + (size_t)(bn + srow) * K + skof;
    const int dstoff = tid * 16;          // linear dest bytes within chunk

    auto stage3 = [&](int slot, int kk) {
        __builtin_amdgcn_global_load_lds((const AS1 unsigned int*)(Abase + kk),
            (AS3 unsigned int*)((char*)&Abuf[slot][0] + dstoff), 16, 0, 0);
        __builtin_amdgcn_global_load_lds((const AS1 unsigned int*)(Abase + (size_t)128 * K + kk),
            (AS3 unsigned int*)((char*)&Abuf[slot][128 * 32] + dstoff), 16, 0, 0);
        __builtin_amdgcn_global_load_lds((const AS1 unsigned int*)(Wbase + kk),
            (AS3 unsigned int*)((char*)&Bbuf[slot][0] + dstoff), 16, 0, 0);
    };

    // ---- fragment read addressing (lane constants + mf/nf*1024 immediates)
    const int fr = lane & 15;
    const int kq = lane >> 4;
    const int rslot = (((((fr & 1) << 2) + kq) ^ ((fr >> 1) & 7)) << 4); // bytes
    const int aoff0 = wr * 8192 + (fr >> 1) * 128 + rslot;
    const int boff0 = wc * 2048 + (fr >> 1) * 128 + rslot;

    f32x4 acc[8][2] = {};

    const int nt = K >> 5;    // 32 K-tiles
    stage3(0, 0);
    stage3(1, 32);
    asm volatile("s_waitcnt vmcnt(3)" ::: "memory");
    __builtin_amdgcn_s_barrier();
    asm volatile("" ::: "memory");

    int slot = 0, slot2 = 2;
    for (int cur = 0; cur < nt; ++cur) {
        bf16x8 a[8], b[2];
        const char* Ab = (const char*)&Abuf[slot][0];
        const char* Bb = (const char*)&Bbuf[slot][0];
        #pragma unroll
        for (int nf = 0; nf < 2; nf++)
            b[nf] = *(const bf16x8*)(Bb + boff0 + nf * 1024);
        #pragma unroll
        for (int mf = 0; mf < 8; mf++)
            a[mf] = *(const bf16x8*)(Ab + aoff0 + mf * 1024);
        if (cur + 2 < nt) stage3(slot2, (cur + 2) << 5);
        __builtin_amdgcn_s_setprio(1);
        #pragma unroll
        for (int mf = 0; mf < 8; mf++)
            #pragma unroll
            for (int nf = 0; nf < 2; nf++)
                acc[mf][nf] = __builtin_amdgcn_mfma_f32_16x16x32_bf16(
                                  a[mf], b[nf], acc[mf][nf], 0, 0, 0);
        __builtin_amdgcn_s_setprio(0);
        // counted drain: allow only tile cur+2's 3 chunks outstanding ->
        // forces tile cur+1 fully resident before any wave reads it.
        if (cur + 2 < nt) { asm volatile("s_waitcnt vmcnt(3)" ::: "memory"); }
        else              { asm volatile("s_waitcnt vmcnt(0)" ::: "memory"); }
        __builtin_amdgcn_s_barrier();
        asm volatile("" ::: "memory");
        slot  = (slot  == 2) ? 0 : slot  + 1;
        slot2 = (slot2 == 2) ? 0 : slot2 + 1;
    }

    // ---- epilogue: bias (+resid) add, fp32 store
    const int col0 = lane & 15;
    const int quad = lane >> 4;
    #pragma unroll
    for (int nf = 0; nf < 2; nf++) {
        const int ng = bn + wc * 32 + nf * 16 + col0;   // global col in [0, CNT*128)
        const int half = ng >> 10;                      // wave-uniform per nf
        const int n = ng & 1023;
        float* __restrict__ Cp = half ? C1 : C0;
        const float bv = half ? bias1[n] : bias0[n];
        #pragma unroll
        for (int mf = 0; mf < 8; mf++) {
            #pragma unroll
            for (int r = 0; r < 4; r++) {
                const int m = bm + wr * 128 + mf * 16 + quad * 4 + r;
                float v = acc[mf][nf][r] + bv;
                size_t off = (size_t)m * 1024 + n;
                if (resid) v += resid[off];
                Cp[off] = v;
            }
        }
    }
}

// ---------------------------------------------------------------------------
// Stockham radix-4 1024-pt FFT. 256 threads, 4 complex/thread in registers,
// 5 stages, exchanges via two swizzled float2 LDS buffers (conflict-free).
// ---------------------------------------------------------------------------
#define SWZ(a) ((a) ^ (((a) >> 4) & 15))

struct cplx { float r, i; };
__device__ inline cplx cmul(cplx a, cplx b) {
    return {a.r * b.r - a.i * b.i, a.r * b.i + a.i * b.r};
}

__device__ inline void r4bfly(cplx v[4], float s) {
    cplx t0 {v[0].r + v[2].r, v[0].i + v[2].i};
    cplx t1 {v[0].r - v[2].r, v[0].i - v[2].i};
    cplx t2 {v[1].r + v[3].r, v[1].i + v[3].i};
    cplx t3 {v[1].r - v[3].r, v[1].i - v[3].i};
    cplx j3 {-s * t3.i, s * t3.r};     // s*i * t3
    v[0] = {t0.r + t2.r, t0.i + t2.i};
    v[2] = {t0.r - t2.r, t0.i - t2.i};
    v[1] = {t1.r + j3.r, t1.i + j3.i};
    v[3] = {t1.r - j3.r, t1.i - j3.i};
}

template<int SIGN>
__device__ inline void fft1024_r(float2* bA, float2* bB, cplx v[4], int tid) {
    const float s = (float)SIGN;
    r4bfly(v, s);
    {
        const int base = tid << 2;
        #pragma unroll
        for (int e = 0; e < 4; e++)
            bA[SWZ(base + e)] = make_float2(v[e].r, v[e].i);
    }
    __syncthreads();
    float2* cur = bA;
    float2* nxt = bB;
    #pragma unroll
    for (int q = 1; q <= 3; q++) {
        const int Ls = 1 << (2 * q);
        #pragma unroll
        for (int k = 0; k < 4; k++) {
            float2 t = cur[SWZ(tid + (k << 8))];
            v[k] = {t.x, t.y};
        }
        const int d = tid & (Ls - 1);
        const float ang = s * 1.57079632679489662f * (float)d / (float)Ls;
        float sn, cs; __sincosf(ang, &sn, &cs);
        cplx w1 {cs, sn};
        cplx w2 = cmul(w1, w1);
        cplx w3 = cmul(w2, w1);
        v[1] = cmul(v[1], w1);
        v[2] = cmul(v[2], w2);
        v[3] = cmul(v[3], w3);
        r4bfly(v, s);
        const int base = ((tid >> (2 * q)) << (2 * q + 2)) + d;
        #pragma unroll
        for (int e = 0; e < 4; e++)
            nxt[SWZ(base + (e << (2 * q)))] = make_float2(v[e].r, v[e].i);
        float2* tmp = cur; cur = nxt; nxt = tmp;
        __syncthreads();
    }
    #pragma unroll
    for (int k = 0; k < 4; k++) {
        float2 t = cur[SWZ(tid + (k << 8))];
        v[k] = {t.x, t.y};
    }
    {
        const float ang = s * 1.57079632679489662f * (float)tid / 256.0f;
        float sn, cs; __sincosf(ang, &sn, &cs);
        cplx w1 {cs, sn};
        cplx w2 = cmul(w1, w1);
        cplx w3 = cmul(w2, w1);
        v[1] = cmul(v[1], w1);
        v[2] = cmul(v[2], w2);
        v[3] = cmul(v[3], w3);
        r4bfly(v, s);
    }
}

// ---------------------------------------------------------------------------
// Bind: normalize keys, pack z = k_hat + i*v, one forward FFT, unpack the two
// real-signal spectra (Kf even part, Vf odd part), write P = Kf*Vf AND write
// Kf packed IN PLACE over the (now dead) Kraw row: float[0]=Kf[0].re,
// float[1]=Kf[512].re, float[2b],[2b+1]=Kf[b] for b=1..511 -> exactly 1024
// floats. Unbind then needs no forward FFT at all.
// ---------------------------------------------------------------------------
__global__ __launch_bounds__(256) void bind_fft_kernel(
        float* __restrict__ KIO, const float* __restrict__ V,
        float* __restrict__ P) {
    __shared__ float2 bA[1024], bB[1024];
    __shared__ float red[256];
    const int token = blockIdx.x;
    const int tid = threadIdx.x;

    float* krow = KIO + (size_t)token * D_SZ;
    const float* vrow = V + (size_t)token * D_SZ;
    float kv[4], vv[4];
    float ss = 0.0f;
    #pragma unroll
    for (int k = 0; k < 4; k++) {
        kv[k] = krow[tid + (k << 8)];
        vv[k] = vrow[tid + (k << 8)];
        ss += kv[k] * kv[k];
    }
    red[tid] = ss;
    __syncthreads();
    for (int sft = 128; sft > 0; sft >>= 1) {
        if (tid < sft) red[tid] += red[tid + sft];
        __syncthreads();
    }
    const float scale = 1.0f / fmaxf(sqrtf(red[0]), 1e-12f);

    cplx z[4];
    #pragma unroll
    for (int k = 0; k < 4; k++) z[k] = {kv[k] * scale, vv[k]};

    __syncthreads();
    fft1024_r<-1>(bA, bB, z, tid);

    #pragma unroll
    for (int e = 0; e < 4; e++)
        bA[SWZ(tid + (e << 8))] = make_float2(z[e].r, z[e].i);
    __syncthreads();

    float2* Po = (float2*)(P + (size_t)token * CCH);
    for (int bin = tid; bin < NBINS; bin += 256) {
        float2 Zb = bA[SWZ(bin)];
        float2 Zm = bA[SWZ((1024 - bin) & 1023)];
        float ar = 0.5f * (Zb.x + Zm.x);
        float ai = 0.5f * (Zb.y - Zm.y);
        float br = 0.5f * (Zb.y + Zm.y);
        float bi = 0.5f * (Zm.x - Zb.x);
        Po[bin] = make_float2(ar * br - ai * bi, ar * bi + ai * br);
        // packed Kf write (in place over Kraw; all krow reads happened above)
        if (bin == 0)        krow[0] = ar;
        else if (bin == 512) krow[1] = ar;
        else { krow[2 * bin] = ar; krow[2 * bin + 1] = ai; }
    }
}

// ---------------------------------------------------------------------------
// Cumsum pass 1: in-place local cumsum within each t-chunk + chunk totals.
// ---------------------------------------------------------------------------
__global__ __launch_bounds__(256) void cumsum_local(
        float* __restrict__ S, float* __restrict__ totals) {
    const int c = blockIdx.x * 256 + threadIdx.x;
    if (c >= CCH) return;
    const int chunk = blockIdx.y;
    const int b = blockIdx.z;
    size_t p = ((size_t)b * L_SZ + (size_t)chunk * TLEN) * CCH + c;
    float acc = 0.0f;
    #pragma unroll 4
    for (int t = 0; t < TLEN; t++) {
        acc += S[p];
        S[p] = acc;
        p += CCH;
    }
    totals[((size_t)b * TCH + chunk) * CCH + c] = acc;
}

// Pass 2: turn chunk totals into EXCLUSIVE prefix offsets (in place).
__global__ __launch_bounds__(256) void scan_totals(float* __restrict__ totals) {
    const int c = blockIdx.x * 256 + threadIdx.x;
    if (c >= CCH) return;
    const int b = blockIdx.y;
    float acc = 0.0f;
    for (int ch = 0; ch < TCH; ch++) {
        size_t idx = ((size_t)b * TCH + ch) * CCH + c;
        float v = totals[idx];
        totals[idx] = acc;
        acc += v;
    }
}

// ---------------------------------------------------------------------------
// Unbind: read packed Kf (stored by bind), Rf = (S_local+off)*conj(Kf),
// Hermitian extend, inverse FFT, /sqrt(t+1), LayerNorm -> bf16 RLN.
// (No forward FFT, no key re-normalization — bind already did both.)
// ---------------------------------------------------------------------------
__global__ __launch_bounds__(256) void unbind_ln_kernel(
        const float* __restrict__ P, const float* __restrict__ totals,
        const float* __restrict__ KF,
        const float* __restrict__ ln_g, const float* __restrict__ ln_b,
        unsigned short* __restrict__ RLNb) {
    __shared__ float2 bA[1024], bB[1024];
    __shared__ float red1[256], red2[256];
    const int token = blockIdx.x;
    const int tid = threadIdx.x;
    const int b = token >> 12;
    const int t = token & (L_SZ - 1);
    const int chunk = t >> 7;

    const float* kfrow   = KF + (size_t)token * D_SZ;
    const float2* Srow   = (const float2*)(P + (size_t)token * CCH);
    const float2* offrow = (const float2*)(totals + ((size_t)b * TCH + chunk) * CCH);
    #pragma unroll
    for (int e = 0; e < 3; e++) {
        const int bin = tid + (e << 8);
        if (bin < NBINS) {
            float kr, ki;
            if (bin == 0)        { kr = kfrow[0]; ki = 0.0f; }
            else if (bin == 512) { kr = kfrow[1]; ki = 0.0f; }
            else { float2 kf2 = *(const float2*)(kfrow + 2 * bin); kr = kf2.x; ki = kf2.y; }
            float2 s2 = Srow[bin];
            float2 o2 = offrow[bin];
            float sr = s2.x + o2.x, si = s2.y + o2.y;
            bA[SWZ(bin)] = make_float2(sr * kr + si * ki, si * kr - sr * ki);
        }
    }
    __syncthreads();
    for (int n = 513 + tid; n < 1024; n += 256) {
        float2 c = bA[SWZ(1024 - n)];
        bA[SWZ(n)] = make_float2(c.x, -c.y);
    }
    __syncthreads();

    cplx rz[4];
    #pragma unroll
    for (int k = 0; k < 4; k++) {
        float2 c = bA[SWZ(tid + (k << 8))];
        rz[k] = {c.x, c.y};
    }
    __syncthreads();
    fft1024_r<1>(bA, bB, rz, tid);      // rz[e].r = r[tid + 256e] * 1024

    const float posscale = (1.0f / 1024.0f) * rsqrtf((float)(t + 1));
    float rv[4];
    float sum = 0.0f, sumsq = 0.0f;
    #pragma unroll
    for (int e = 0; e < 4; e++) {
        float v = rz[e].r * posscale;
        rv[e] = v;
        sum += v;
        sumsq += v * v;
    }
    red1[tid] = sum; red2[tid] = sumsq;
    __syncthreads();
    for (int sft = 128; sft > 0; sft >>= 1) {
        if (tid < sft) { red1[tid] += red1[tid + sft]; red2[tid] += red2[tid + sft]; }
        __syncthreads();
    }
    const float mu = red1[0] * (1.0f / 1024.0f);
    const float var = red2[0] * (1.0f / 1024.0f) - mu * mu;
    const float rstd = rsqrtf(var + 1e-5f);

    unsigned short* outp = RLNb + (size_t)token * D_SZ;
    #pragma unroll
    for (int e = 0; e < 4; e++) {
        const int d = tid + (e << 8);
        outp[d] = f2bf((rv[e] - mu) * rstd * ln_g[d] + ln_b[d]);
    }
}

// ---------------------------------------------------------------------------
// Workspace (bytes):
//   Kraw   fp32 M*D    = 64.0 MB  (keys; bind overwrites in place with packed Kf)
//   V      fp32 M*D    = 64.0 MB  (dead after bind; reused as bf16 RLN)
//   P      fp32 M*CCH  = 67.2 MB  (local cumsum in place)
//   totals fp32        =  0.5 MB
//   xb     bf16 M*D    = 32.0 MB
//   WB     bf16 2048*D =  4.0 MB  (Wk ++ Wv, concatenated)
//   Wob    bf16 D*D    =  2.0 MB
//   total ~= 234 MB
// ---------------------------------------------------------------------------
extern "C" void kernel_launch(void* const* d_in, const int* in_sizes, int n_in,
                              void* d_out, int out_size, void* d_ws, size_t ws_size,
                              hipStream_t stream) {
    (void)in_sizes; (void)n_in; (void)out_size; (void)ws_size;
    const float* x    = (const float*)d_in[0];
    const float* Wk   = (const float*)d_in[1];
    const float* bk   = (const float*)d_in[2];
    const float* Wv   = (const float*)d_in[3];
    const float* bv   = (const float*)d_in[4];
    const float* ln_g = (const float*)d_in[5];
    const float* ln_b = (const float*)d_in[6];
    const float* Wo   = (const float*)d_in[7];
    const float* bo   = (const float*)d_in[8];
    float* out = (float*)d_out;

    char* w = (char*)d_ws;
    float* Kraw   = (float*)w;  w += (size_t)M_SZ * D_SZ * 4;
    float* V      = (float*)w;  w += (size_t)M_SZ * D_SZ * 4;
    float* P      = (float*)w;  w += (size_t)M_SZ * CCH * 4;
    float* totals = (float*)w;  w += (size_t)B_SZ * TCH * CCH * 4;
    unsigned short* xb  = (unsigned short*)w;  w += (size_t)M_SZ * D_SZ * 2;
    unsigned short* WB  = (unsigned short*)w;  w += (size_t)2 * D_SZ * D_SZ * 2;
    unsigned short* Wob = (unsigned short*)w;  w += (size_t)D_SZ * D_SZ * 2;
    unsigned short* RLNb = (unsigned short*)V;  // overlays dead V

    const int n8x = M_SZ * D_SZ / 8;
    const int n8w = D_SZ * D_SZ / 8;
    cast_f32_bf16<<<n8x / 256, 256, 0, stream>>>(x, xb, n8x);
    dim3 wgrid(n8w / 256, 3);
    cast_w3<<<wgrid, 256, 0, stream>>>(Wk, Wv, Wo, WB, Wob, n8w);

    // fused K/V projection: N=2048 (first half -> Kraw, second -> V)
    gemm_mfma<16><<<(M_SZ / 256) * 16, 512, 0, stream>>>(
        xb, WB, bk, bv, nullptr, Kraw, V, M_SZ, D_SZ);

    bind_fft_kernel<<<M_SZ, 256, 0, stream>>>(Kraw, V, P);

    dim3 cgrid((CCH + 255) / 256, TCH, B_SZ);
    cumsum_local<<<cgrid, 256, 0, stream>>>(P, totals);
    dim3 sgrid((CCH + 255) / 256, B_SZ);
    scan_totals<<<sgrid, 256, 0, stream>>>(totals);

    unbind_ln_kernel<<<M_SZ, 256, 0, stream>>>(P, totals, Kraw, ln_g, ln_b, RLNb);

    // output GEMM with fp32 residual
    gemm_mfma<8><<<(M_SZ / 256) * 8, 512, 0, stream>>>(
        RLNb, Wob, bo, bo, x, out, out, M_SZ, D_SZ);
}

// Round 5
// 417.398 us; speedup vs baseline: 1.2132x; 1.0227x over previous
//
#include <hip/hip_runtime.h>
#include <math.h>

// Problem constants (from reference): B=4, L=4096, D=1024
#define B_SZ 4
#define L_SZ 4096
#define D_SZ 1024
#define M_SZ (B_SZ * L_SZ)      // 16384 tokens
#define NBINS 513               // rfft bins for D=1024
#define CCH   (2 * NBINS)       // 1026 float channels per token (interleaved re,im)
#define TLEN 16                 // tokens per cumsum chunk (= per bind block)
#define NCH  (L_SZ / TLEN)      // 256 chunks per batch
#define NG   16                 // chunk groups (16 chunks each) for 2-level scan

typedef short bf16x8 __attribute__((ext_vector_type(8)));
typedef float f32x4  __attribute__((ext_vector_type(4)));
typedef unsigned short us8 __attribute__((ext_vector_type(8)));

#define AS1 __attribute__((address_space(1)))
#define AS3 __attribute__((address_space(3)))

// round-to-nearest-even f32 -> bf16
__device__ inline unsigned short f2bf(float f) {
    unsigned int u = __float_as_uint(f);
    u += 0x7fffu + ((u >> 16) & 1u);
    return (unsigned short)(u >> 16);
}

// ---------------------------------------------------------------------------
// f32 -> bf16 cast, 8 elements/thread
// ---------------------------------------------------------------------------
__global__ __launch_bounds__(256) void cast_f32_bf16(
        const float* __restrict__ in, unsigned short* __restrict__ out, int n8) {
    int i = blockIdx.x * 256 + threadIdx.x;
    if (i >= n8) return;
    const float4* p = (const float4*)in + 2 * (size_t)i;
    float4 a = p[0], b = p[1];
    us8 o;
    o[0] = f2bf(a.x); o[1] = f2bf(a.y); o[2] = f2bf(a.z); o[3] = f2bf(a.w);
    o[4] = f2bf(b.x); o[5] = f2bf(b.y); o[6] = f2bf(b.z); o[7] = f2bf(b.w);
    *(us8*)(out + (size_t)i * 8) = o;
}

// merged weight casts: blockIdx.y selects {Wk->WB, Wv->WB+1M, Wo->Wob}
__global__ __launch_bounds__(256) void cast_w3(
        const float* __restrict__ Wk, const float* __restrict__ Wv,
        const float* __restrict__ Wo,
        unsigned short* __restrict__ WB, unsigned short* __restrict__ Wob, int n8) {
    int i = blockIdx.x * 256 + threadIdx.x;
    if (i >= n8) return;
    const int which = blockIdx.y;
    const float* src = (which == 0) ? Wk : (which == 1) ? Wv : Wo;
    unsigned short* dst = (which == 0) ? WB : (which == 1) ? (WB + D_SZ * D_SZ) : Wob;
    const float4* p = (const float4*)src + 2 * (size_t)i;
    float4 a = p[0], b = p[1];
    us8 o;
    o[0] = f2bf(a.x); o[1] = f2bf(a.y); o[2] = f2bf(a.z); o[3] = f2bf(a.w);
    o[4] = f2bf(b.x); o[5] = f2bf(b.y); o[6] = f2bf(b.z); o[7] = f2bf(b.w);
    *(us8*)(dst + (size_t)i * 8) = o;
}

// ---------------------------------------------------------------------------
// bf16 MFMA GEMM, 256x128 tile, BK=32, 3 LDS slots (72 KiB -> 2 blocks/CU),
// 512 threads = 8 waves (2M x 4N), per-wave 128x32 output. (R4, known-good.)
// ---------------------------------------------------------------------------
template<int CNT>   // N = CNT*128
__global__ __launch_bounds__(512, 4) void gemm_mfma(
        const unsigned short* __restrict__ A, const unsigned short* __restrict__ W,
        const float* __restrict__ bias0, const float* __restrict__ bias1,
        const float* __restrict__ resid,
        float* __restrict__ C0, float* __restrict__ C1, int M, int K) {
    __shared__ unsigned short Abuf[3][256 * 32];   // 3 x 16 KiB
    __shared__ unsigned short Bbuf[3][128 * 32];   // 3 x  8 KiB
    const int id   = blockIdx.x;
    const int bx   = (id >> 3) % CNT;
    const int by   = (id & 7) + 8 * (id / (8 * CNT));
    const int tid  = threadIdx.x;
    const int lane = tid & 63;
    const int wid  = tid >> 6;        // 0..7
    const int wr   = wid >> 2;        // 0..1 (M, 128 rows)
    const int wc   = wid & 3;         // 0..3 (N, 32 cols)
    const int bm   = by * 256;
    const int bn   = bx * 128;

    const int sl = tid >> 3;              // line 0..63 (2 rows each)
    const int sq = (tid & 7) ^ (sl & 7);  // logical slot at this dest position
    const int srow = 2 * sl + (sq >> 2);  // row within chunk
    const int skof = (sq & 3) * 8;        // k offset (shorts)
    const unsigned short* Abase = A + (size_t)(bm + srow) * K + skof;
    const unsigned short* Wbase = W + (size_t)(bn + srow) * K + skof;
    const int dstoff = tid * 16;          // linear dest bytes within chunk

    auto stage3 = [&](int slot, int kk) {
        __builtin_amdgcn_global_load_lds((const AS1 unsigned int*)(Abase + kk),
            (AS3 unsigned int*)((char*)&Abuf[slot][0] + dstoff), 16, 0, 0);
        __builtin_amdgcn_global_load_lds((const AS1 unsigned int*)(Abase + (size_t)128 * K + kk),
            (AS3 unsigned int*)((char*)&Abuf[slot][128 * 32] + dstoff), 16, 0, 0);
        __builtin_amdgcn_global_load_lds((const AS1 unsigned int*)(Wbase + kk),
            (AS3 unsigned int*)((char*)&Bbuf[slot][0] + dstoff), 16, 0, 0);
    };

    const int fr = lane & 15;
    const int kq = lane >> 4;
    const int rslot = (((((fr & 1) << 2) + kq) ^ ((fr >> 1) & 7)) << 4); // bytes
    const int aoff0 = wr * 8192 + (fr >> 1) * 128 + rslot;
    const int boff0 = wc * 2048 + (fr >> 1) * 128 + rslot;

    f32x4 acc[8][2] = {};

    const int nt = K >> 5;    // 32 K-tiles
    stage3(0, 0);
    stage3(1, 32);
    asm volatile("s_waitcnt vmcnt(3)" ::: "memory");
    __builtin_amdgcn_s_barrier();
    asm volatile("" ::: "memory");

    int slot = 0, slot2 = 2;
    for (int cur = 0; cur < nt; ++cur) {
        bf16x8 a[8], b[2];
        const char* Ab = (const char*)&Abuf[slot][0];
        const char* Bb = (const char*)&Bbuf[slot][0];
        #pragma unroll
        for (int nf = 0; nf < 2; nf++)
            b[nf] = *(const bf16x8*)(Bb + boff0 + nf * 1024);
        #pragma unroll
        for (int mf = 0; mf < 8; mf++)
            a[mf] = *(const bf16x8*)(Ab + aoff0 + mf * 1024);
        if (cur + 2 < nt) stage3(slot2, (cur + 2) << 5);
        __builtin_amdgcn_s_setprio(1);
        #pragma unroll
        for (int mf = 0; mf < 8; mf++)
            #pragma unroll
            for (int nf = 0; nf < 2; nf++)
                acc[mf][nf] = __builtin_amdgcn_mfma_f32_16x16x32_bf16(
                                  a[mf], b[nf], acc[mf][nf], 0, 0, 0);
        __builtin_amdgcn_s_setprio(0);
        if (cur + 2 < nt) { asm volatile("s_waitcnt vmcnt(3)" ::: "memory"); }
        else              { asm volatile("s_waitcnt vmcnt(0)" ::: "memory"); }
        __builtin_amdgcn_s_barrier();
        asm volatile("" ::: "memory");
        slot  = (slot  == 2) ? 0 : slot  + 1;
        slot2 = (slot2 == 2) ? 0 : slot2 + 1;
    }

    const int col0 = lane & 15;
    const int quad = lane >> 4;
    #pragma unroll
    for (int nf = 0; nf < 2; nf++) {
        const int ng = bn + wc * 32 + nf * 16 + col0;   // global col in [0, CNT*128)
        const int half = ng >> 10;                      // wave-uniform per nf
        const int n = ng & 1023;
        float* __restrict__ Cp = half ? C1 : C0;
        const float bv = half ? bias1[n] : bias0[n];
        #pragma unroll
        for (int mf = 0; mf < 8; mf++) {
            #pragma unroll
            for (int r = 0; r < 4; r++) {
                const int m = bm + wr * 128 + mf * 16 + quad * 4 + r;
                float v = acc[mf][nf][r] + bv;
                size_t off = (size_t)m * 1024 + n;
                if (resid) v += resid[off];
                Cp[off] = v;
            }
        }
    }
}

// ---------------------------------------------------------------------------
// Stockham radix-4 1024-pt FFT. 256 threads, 4 complex/thread in registers,
// 5 stages, exchanges via two swizzled float2 LDS buffers (conflict-free).
// ---------------------------------------------------------------------------
#define SWZ(a) ((a) ^ (((a) >> 4) & 15))

struct cplx { float r, i; };
__device__ inline cplx cmul(cplx a, cplx b) {
    return {a.r * b.r - a.i * b.i, a.r * b.i + a.i * b.r};
}

__device__ inline void r4bfly(cplx v[4], float s) {
    cplx t0 {v[0].r + v[2].r, v[0].i + v[2].i};
    cplx t1 {v[0].r - v[2].r, v[0].i - v[2].i};
    cplx t2 {v[1].r + v[3].r, v[1].i + v[3].i};
    cplx t3 {v[1].r - v[3].r, v[1].i - v[3].i};
    cplx j3 {-s * t3.i, s * t3.r};     // s*i * t3
    v[0] = {t0.r + t2.r, t0.i + t2.i};
    v[2] = {t0.r - t2.r, t0.i - t2.i};
    v[1] = {t1.r + j3.r, t1.i + j3.i};
    v[3] = {t1.r - j3.r, t1.i - j3.i};
}

template<int SIGN>
__device__ inline void fft1024_r(float2* bA, float2* bB, cplx v[4], int tid) {
    const float s = (float)SIGN;
    r4bfly(v, s);
    {
        const int base = tid << 2;
        #pragma unroll
        for (int e = 0; e < 4; e++)
            bA[SWZ(base + e)] = make_float2(v[e].r, v[e].i);
    }
    __syncthreads();
    float2* cur = bA;
    float2* nxt = bB;
    #pragma unroll
    for (int q = 1; q <= 3; q++) {
        const int Ls = 1 << (2 * q);
        #pragma unroll
        for (int k = 0; k < 4; k++) {
            float2 t = cur[SWZ(tid + (k << 8))];
            v[k] = {t.x, t.y};
        }
        const int d = tid & (Ls - 1);
        const float ang = s * 1.57079632679489662f * (float)d / (float)Ls;
        float sn, cs; __sincosf(ang, &sn, &cs);
        cplx w1 {cs, sn};
        cplx w2 = cmul(w1, w1);
        cplx w3 = cmul(w2, w1);
        v[1] = cmul(v[1], w1);
        v[2] = cmul(v[2], w2);
        v[3] = cmul(v[3], w3);
        r4bfly(v, s);
        const int base = ((tid >> (2 * q)) << (2 * q + 2)) + d;
        #pragma unroll
        for (int e = 0; e < 4; e++)
            nxt[SWZ(base + (e << (2 * q)))] = make_float2(v[e].r, v[e].i);
        float2* tmp = cur; cur = nxt; nxt = tmp;
        __syncthreads();
    }
    #pragma unroll
    for (int k = 0; k < 4; k++) {
        float2 t = cur[SWZ(tid + (k << 8))];
        v[k] = {t.x, t.y};
    }
    {
        const float ang = s * 1.57079632679489662f * (float)tid / 256.0f;
        float sn, cs; __sincosf(ang, &sn, &cs);
        cplx w1 {cs, sn};
        cplx w2 = cmul(w1, w1);
        cplx w3 = cmul(w2, w1);
        v[1] = cmul(v[1], w1);
        v[2] = cmul(v[2], w2);
        v[3] = cmul(v[3], w3);
        r4bfly(v, s);
    }
}

// ---------------------------------------------------------------------------
// Bind + fused in-chunk cumsum. One block = one 16-token chunk, tokens
// processed sequentially; running P-cumsum held in registers (6 floats/thr).
// Per token: normalize key (shuffle reduce), z = khat + i*v, one fwd FFT,
// unpack Kf/Vf, P[token] = running += Kf*Vf, pack Kf in place over Kraw row.
// After the loop: write the chunk's inclusive totals row.
// Next token's K/V rows are prefetched under the current token's FFT.
// ---------------------------------------------------------------------------
__global__ __launch_bounds__(256) void bind_cum_kernel(
        float* __restrict__ KIO, const float* __restrict__ V,
        float* __restrict__ P, float* __restrict__ totals) {
    __shared__ float2 bA[1024], bB[1024];
    __shared__ float red[4];
    const int blk = blockIdx.x;           // = b*NCH + chunk
    const int tid = threadIdx.x;
    const int wv  = tid >> 6;
    const int ln  = tid & 63;
    const size_t tok0 = (size_t)blk * TLEN;

    float r0r = 0.f, r0i = 0.f, r1r = 0.f, r1i = 0.f, r2r = 0.f, r2i = 0.f;

    float kvC[4], vvC[4];
    {
        const float* krow = KIO + tok0 * D_SZ;
        const float* vrow = V   + tok0 * D_SZ;
        #pragma unroll
        for (int k = 0; k < 4; k++) {
            kvC[k] = krow[tid + (k << 8)];
            vvC[k] = vrow[tid + (k << 8)];
        }
    }

    for (int tk = 0; tk < TLEN; ++tk) {
        const size_t token = tok0 + tk;
        float* krow = KIO + token * D_SZ;

        float ss = 0.f;
        #pragma unroll
        for (int k = 0; k < 4; k++) ss += kvC[k] * kvC[k];
        #pragma unroll
        for (int m = 1; m < 64; m <<= 1) ss += __shfl_xor(ss, m, 64);
        if (ln == 0) red[wv] = ss;
        __syncthreads();     // red ready; also protects bA reuse across tokens
        const float scale = 1.0f /
            fmaxf(sqrtf(red[0] + red[1] + red[2] + red[3]), 1e-12f);

        cplx z[4];
        #pragma unroll
        for (int k = 0; k < 4; k++) z[k] = {kvC[k] * scale, vvC[k]};

        // prefetch next token's rows (latency hidden under the FFT)
        if (tk + 1 < TLEN) {
            const float* krowN = KIO + (token + 1) * D_SZ;
            const float* vrowN = V   + (token + 1) * D_SZ;
            #pragma unroll
            for (int k = 0; k < 4; k++) {
                kvC[k] = krowN[tid + (k << 8)];
                vvC[k] = vrowN[tid + (k << 8)];
            }
        }

        fft1024_r<-1>(bA, bB, z, tid);

        #pragma unroll
        for (int e = 0; e < 4; e++)
            bA[SWZ(tid + (e << 8))] = make_float2(z[e].r, z[e].i);
        __syncthreads();

        float2* Po = (float2*)(P + token * CCH);
        auto procbin = [&](int bin, float& rr, float& ri) {
            float2 Zb = bA[SWZ(bin)];
            float2 Zm = bA[SWZ((1024 - bin) & 1023)];
            float ar = 0.5f * (Zb.x + Zm.x);
            float ai = 0.5f * (Zb.y - Zm.y);
            float br = 0.5f * (Zb.y + Zm.y);
            float bi = 0.5f * (Zm.x - Zb.x);
            rr += ar * br - ai * bi;
            ri += ar * bi + ai * br;
            Po[bin] = make_float2(rr, ri);
            if (bin == 0)        krow[0] = ar;
            else if (bin == 512) krow[1] = ar;
            else { krow[2 * bin] = ar; krow[2 * bin + 1] = ai; }
        };
        procbin(tid,       r0r, r0i);
        procbin(tid + 256, r1r, r1i);
        if (tid == 0) procbin(512, r2r, r2i);
        // no trailing barrier needed: next iteration's barrier covers bA reuse
    }

    float* trow = totals + (size_t)blk * CCH;
    trow[2 * tid]             = r0r;  trow[2 * tid + 1]         = r0i;
    trow[2 * (tid + 256)]     = r1r;  trow[2 * (tid + 256) + 1] = r1i;
    if (tid == 0) { trow[1024] = r2r; trow[1025] = r2i; }
}

// ---------------------------------------------------------------------------
// 2-level scan of chunk totals -> exclusive offsets.
// S1: within each group of 16 chunks: exclusive scan in place + group total.
// S2: exclusive scan of the 16 group totals per batch.
// unbind adds totals[chunk] + gt[chunk>>4].
// ---------------------------------------------------------------------------
__global__ __launch_bounds__(256) void scan_s1(
        float* __restrict__ totals, float* __restrict__ gt) {
    const int c = blockIdx.x * 256 + threadIdx.x;
    if (c >= CCH) return;
    const int g = blockIdx.y;
    const int b = blockIdx.z;
    float run = 0.f;
    #pragma unroll
    for (int i = 0; i < 16; i++) {
        size_t idx = ((size_t)(b * NCH + g * 16 + i)) * CCH + c;
        float v = totals[idx];
        totals[idx] = run;
        run += v;
    }
    gt[((size_t)(b * NG + g)) * CCH + c] = run;
}

__global__ __launch_bounds__(256) void scan_s2(float* __restrict__ gt) {
    const int c = blockIdx.x * 256 + threadIdx.x;
    if (c >= CCH) return;
    const int b = blockIdx.y;
    float run = 0.f;
    #pragma unroll
    for (int g = 0; g < NG; g++) {
        size_t idx = ((size_t)(b * NG + g)) * CCH + c;
        float v = gt[idx];
        gt[idx] = run;
        run += v;
    }
}

// ---------------------------------------------------------------------------
// Unbind, TWO tokens per block via packed real iFFT: Y = Ra_ext + i*Rb_ext,
// one 1024-pt inverse FFT -> ra = Re(z), rb = Im(z). Tokens (2i, 2i+1)
// always share (batch, chunk) so one offset-row pair serves both.
// Then /sqrt(t+1), LayerNorm (shuffle reduce) -> bf16 RLN rows.
// ---------------------------------------------------------------------------
__global__ __launch_bounds__(256) void unbind2_ln_kernel(
        const float* __restrict__ P, const float* __restrict__ totals,
        const float* __restrict__ gt, const float* __restrict__ KF,
        const float* __restrict__ ln_g, const float* __restrict__ ln_b,
        unsigned short* __restrict__ RLNb) {
    __shared__ float2 bA[1024], bB[1024];
    __shared__ float red[16];
    const int pair = blockIdx.x;
    const int tid  = threadIdx.x;
    const int wv   = tid >> 6;
    const int ln   = tid & 63;
    const size_t ta = (size_t)pair * 2, tb = ta + 1;
    const int bidx = (int)(ta >> 12);
    const int t_a  = (int)(ta & (L_SZ - 1));
    const int chunk = t_a >> 4;                 // TLEN=16

    const float2* Sa2  = (const float2*)(P + ta * CCH);
    const float2* Sb2  = (const float2*)(P + tb * CCH);
    const float*  Ka   = KF + ta * D_SZ;
    const float*  Kb   = KF + tb * D_SZ;
    const float2* off2 = (const float2*)(totals + (size_t)(bidx * NCH + chunk) * CCH);
    const float2* gof2 = (const float2*)(gt + (size_t)(bidx * NG + (chunk >> 4)) * CCH);

    auto zc = [&](int bin, const float2* S2, const float* kf, float2 og) {
        float kr, ki;
        if (bin == 0)        { kr = kf[0]; ki = 0.f; }
        else if (bin == 512) { kr = kf[1]; ki = 0.f; }
        else { float2 k2 = *(const float2*)(kf + 2 * bin); kr = k2.x; ki = k2.y; }
        float2 s2 = S2[bin];
        float sr = s2.x + og.x, si = s2.y + og.y;
        return make_float2(sr * kr + si * ki, si * kr - sr * ki);
    };
    auto fill = [&](int bin) {
        float2 o = off2[bin], g = gof2[bin];
        float2 og = make_float2(o.x + g.x, o.y + g.y);
        float2 Za = zc(bin, Sa2, Ka, og);
        float2 Zb = zc(bin, Sb2, Kb, og);
        bA[SWZ(bin)] = make_float2(Za.x - Zb.y, Za.y + Zb.x);
        if (bin != 0 && bin != 512)
            bA[SWZ(1024 - bin)] = make_float2(Za.x + Zb.y, Zb.x - Za.y);
    };
    fill(tid);
    fill(tid + 256);
    if (tid == 0) fill(512);
    __syncthreads();

    cplx z[4];
    #pragma unroll
    for (int k = 0; k < 4; k++) {
        float2 c = bA[SWZ(tid + (k << 8))];
        z[k] = {c.x, c.y};
    }
    __syncthreads();
    fft1024_r<1>(bA, bB, z, tid);   // z = 1024 * (ra + i*rb)

    const float sa = (1.0f / 1024.0f) * rsqrtf((float)(t_a + 1));
    const float sb = (1.0f / 1024.0f) * rsqrtf((float)(t_a + 2));
    float ra[4], rb[4];
    float s1a = 0.f, s2a = 0.f, s1b = 0.f, s2b = 0.f;
    #pragma unroll
    for (int e = 0; e < 4; e++) {
        ra[e] = z[e].r * sa;
        rb[e] = z[e].i * sb;
        s1a += ra[e]; s2a += ra[e] * ra[e];
        s1b += rb[e]; s2b += rb[e] * rb[e];
    }
    #pragma unroll
    for (int m = 1; m < 64; m <<= 1) {
        s1a += __shfl_xor(s1a, m, 64);
        s2a += __shfl_xor(s2a, m, 64);
        s1b += __shfl_xor(s1b, m, 64);
        s2b += __shfl_xor(s2b, m, 64);
    }
    if (ln == 0) {
        red[wv] = s1a; red[4 + wv] = s2a; red[8 + wv] = s1b; red[12 + wv] = s2b;
    }
    __syncthreads();
    const float S1a = red[0] + red[1] + red[2] + red[3];
    const float S2a = red[4] + red[5] + red[6] + red[7];
    const float S1b = red[8] + red[9] + red[10] + red[11];
    const float S2b = red[12] + red[13] + red[14] + red[15];
    const float mua = S1a * (1.0f / 1024.0f);
    const float vara = S2a * (1.0f / 1024.0f) - mua * mua;
    const float rsa = rsqrtf(vara + 1e-5f);
    const float mub = S1b * (1.0f / 1024.0f);
    const float varb = S2b * (1.0f / 1024.0f) - mub * mub;
    const float rsb = rsqrtf(varb + 1e-5f);

    unsigned short* outA = RLNb + ta * D_SZ;
    unsigned short* outB = RLNb + tb * D_SZ;
    #pragma unroll
    for (int e = 0; e < 4; e++) {
        const int d = tid + (e << 8);
        const float g = ln_g[d], be = ln_b[d];
        outA[d] = f2bf((ra[e] - mua) * rsa * g + be);
        outB[d] = f2bf((rb[e] - mub) * rsb * g + be);
    }
}

// ---------------------------------------------------------------------------
// Workspace (bytes):
//   Kraw   fp32 M*D        = 64.0 MB  (keys; bind overwrites with packed Kf)
//   V      fp32 M*D        = 64.0 MB  (dead after bind; reused as bf16 RLN)
//   P      fp32 M*CCH      = 64.1 MB  (bind writes inclusive-in-chunk cumsum)
//   totals fp32 B*NCH*CCH  =  4.2 MB  (chunk totals -> exclusive via scan)
//   gt     fp32 B*NG*CCH   =  0.3 MB
//   xb     bf16 M*D        = 32.0 MB
//   WB     bf16 2048*D     =  4.0 MB  (Wk ++ Wv)
//   Wob    bf16 D*D        =  2.0 MB
//   total ~= 235 MB
// ---------------------------------------------------------------------------
extern "C" void kernel_launch(void* const* d_in, const int* in_sizes, int n_in,
                              void* d_out, int out_size, void* d_ws, size_t ws_size,
                              hipStream_t stream) {
    (void)in_sizes; (void)n_in; (void)out_size; (void)ws_size;
    const float* x    = (const float*)d_in[0];
    const float* Wk   = (const float*)d_in[1];
    const float* bk   = (const float*)d_in[2];
    const float* Wv   = (const float*)d_in[3];
    const float* bv   = (const float*)d_in[4];
    const float* ln_g = (const float*)d_in[5];
    const float* ln_b = (const float*)d_in[6];
    const float* Wo   = (const float*)d_in[7];
    const float* bo   = (const float*)d_in[8];
    float* out = (float*)d_out;

    char* w = (char*)d_ws;
    float* Kraw   = (float*)w;  w += (size_t)M_SZ * D_SZ * 4;
    float* V      = (float*)w;  w += (size_t)M_SZ * D_SZ * 4;
    float* P      = (float*)w;  w += (size_t)M_SZ * CCH * 4;
    float* totals = (float*)w;  w += (size_t)B_SZ * NCH * CCH * 4;
    float* gt     = (float*)w;  w += (size_t)B_SZ * NG * CCH * 4;
    unsigned short* xb  = (unsigned short*)w;  w += (size_t)M_SZ * D_SZ * 2;
    unsigned short* WB  = (unsigned short*)w;  w += (size_t)2 * D_SZ * D_SZ * 2;
    unsigned short* Wob = (unsigned short*)w;  w += (size_t)D_SZ * D_SZ * 2;
    unsigned short* RLNb = (unsigned short*)V;  // overlays dead V

    const int n8x = M_SZ * D_SZ / 8;
    const int n8w = D_SZ * D_SZ / 8;
    cast_f32_bf16<<<n8x / 256, 256, 0, stream>>>(x, xb, n8x);
    dim3 wgrid(n8w / 256, 3);
    cast_w3<<<wgrid, 256, 0, stream>>>(Wk, Wv, Wo, WB, Wob, n8w);

    // fused K/V projection: N=2048 (first half -> Kraw, second -> V)
    gemm_mfma<16><<<(M_SZ / 256) * 16, 512, 0, stream>>>(
        xb, WB, bk, bv, nullptr, Kraw, V, M_SZ, D_SZ);

    // bind + in-chunk cumsum (one block per 16-token chunk)
    bind_cum_kernel<<<M_SZ / TLEN, 256, 0, stream>>>(Kraw, V, P, totals);

    // 2-level exclusive scan of chunk totals
    dim3 g1((CCH + 255) / 256, NG, B_SZ);
    scan_s1<<<g1, 256, 0, stream>>>(totals, gt);
    dim3 g2((CCH + 255) / 256, B_SZ);
    scan_s2<<<g2, 256, 0, stream>>>(gt);

    // unbind: 2 tokens per block via packed real iFFT
    unbind2_ln_kernel<<<M_SZ / 2, 256, 0, stream>>>(
        P, totals, gt, Kraw, ln_g, ln_b, RLNb);

    // output GEMM with fp32 residual
    gemm_mfma<8><<<(M_SZ / 256) * 8, 512, 0, stream>>>(
        RLNb, Wob, bo, bo, x, out, out, M_SZ, D_SZ);
}

// Round 8
// 391.226 us; speedup vs baseline: 1.2943x; 1.0669x over previous
//
#include <hip/hip_runtime.h>
#include <math.h>

// Problem constants (from reference): B=4, L=4096, D=1024
#define B_SZ 4
#define L_SZ 4096
#define D_SZ 1024
#define M_SZ (B_SZ * L_SZ)      // 16384 tokens
#define NBINS 513               // rfft bins for D=1024
#define CCH   (2 * NBINS)       // 1026 float channels per token (interleaved re,im)
#define TLEN 8                  // tokens per cumsum chunk (= per bind block)
#define NCH  (L_SZ / TLEN)      // 512 chunks per batch
#define NG   32                 // chunk groups (16 chunks each) for 2-level scan

typedef short bf16x8 __attribute__((ext_vector_type(8)));
typedef float f32x4  __attribute__((ext_vector_type(4)));
typedef unsigned short us8 __attribute__((ext_vector_type(8)));

#define AS1 __attribute__((address_space(1)))
#define AS3 __attribute__((address_space(3)))

// round-to-nearest-even f32 -> bf16
__device__ inline unsigned short f2bf(float f) {
    unsigned int u = __float_as_uint(f);
    u += 0x7fffu + ((u >> 16) & 1u);
    return (unsigned short)(u >> 16);
}

// ---------------------------------------------------------------------------
// f32 -> bf16 cast, 8 elements/thread
// ---------------------------------------------------------------------------
__global__ __launch_bounds__(256) void cast_f32_bf16(
        const float* __restrict__ in, unsigned short* __restrict__ out, int n8) {
    int i = blockIdx.x * 256 + threadIdx.x;
    if (i >= n8) return;
    const float4* p = (const float4*)in + 2 * (size_t)i;
    float4 a = p[0], b = p[1];
    us8 o;
    o[0] = f2bf(a.x); o[1] = f2bf(a.y); o[2] = f2bf(a.z); o[3] = f2bf(a.w);
    o[4] = f2bf(b.x); o[5] = f2bf(b.y); o[6] = f2bf(b.z); o[7] = f2bf(b.w);
    *(us8*)(out + (size_t)i * 8) = o;
}

// merged weight casts: blockIdx.y selects {Wk->WB, Wv->WB+1M, Wo->Wob}
__global__ __launch_bounds__(256) void cast_w3(
        const float* __restrict__ Wk, const float* __restrict__ Wv,
        const float* __restrict__ Wo,
        unsigned short* __restrict__ WB, unsigned short* __restrict__ Wob, int n8) {
    int i = blockIdx.x * 256 + threadIdx.x;
    if (i >= n8) return;
    const int which = blockIdx.y;
    const float* src = (which == 0) ? Wk : (which == 1) ? Wv : Wo;
    unsigned short* dst = (which == 0) ? WB : (which == 1) ? (WB + D_SZ * D_SZ) : Wob;
    const float4* p = (const float4*)src + 2 * (size_t)i;
    float4 a = p[0], b = p[1];
    us8 o;
    o[0] = f2bf(a.x); o[1] = f2bf(a.y); o[2] = f2bf(a.z); o[3] = f2bf(a.w);
    o[4] = f2bf(b.x); o[5] = f2bf(b.y); o[6] = f2bf(b.z); o[7] = f2bf(b.w);
    *(us8*)(dst + (size_t)i * 8) = o;
}

// ---------------------------------------------------------------------------
// bf16 MFMA GEMM, 256x128 tile, BK=32, 3 LDS slots (72 KiB -> 2 blocks/CU),
// 512 threads = 8 waves (2M x 4N), per-wave 128x32 output. (R4, known-good.)
// ---------------------------------------------------------------------------
template<int CNT>   // N = CNT*128
__global__ __launch_bounds__(512, 4) void gemm_mfma(
        const unsigned short* __restrict__ A, const unsigned short* __restrict__ W,
        const float* __restrict__ bias0, const float* __restrict__ bias1,
        const float* __restrict__ resid,
        float* __restrict__ C0, float* __restrict__ C1, int M, int K) {
    __shared__ unsigned short Abuf[3][256 * 32];   // 3 x 16 KiB
    __shared__ unsigned short Bbuf[3][128 * 32];   // 3 x  8 KiB
    const int id   = blockIdx.x;
    const int bx   = (id >> 3) % CNT;
    const int by   = (id & 7) + 8 * (id / (8 * CNT));
    const int tid  = threadIdx.x;
    const int lane = tid & 63;
    const int wid  = tid >> 6;        // 0..7
    const int wr   = wid >> 2;        // 0..1 (M, 128 rows)
    const int wc   = wid & 3;         // 0..3 (N, 32 cols)
    const int bm   = by * 256;
    const int bn   = bx * 128;

    const int sl = tid >> 3;              // line 0..63 (2 rows each)
    const int sq = (tid & 7) ^ (sl & 7);  // logical slot at this dest position
    const int srow = 2 * sl + (sq >> 2);  // row within chunk
    const int skof = (sq & 3) * 8;        // k offset (shorts)
    const unsigned short* Abase = A + (size_t)(bm + srow) * K + skof;
    const unsigned short* Wbase = W + (size_t)(bn + srow) * K + skof;
    const int dstoff = tid * 16;          // linear dest bytes within chunk

    auto stage3 = [&](int slot, int kk) {
        __builtin_amdgcn_global_load_lds((const AS1 unsigned int*)(Abase + kk),
            (AS3 unsigned int*)((char*)&Abuf[slot][0] + dstoff), 16, 0, 0);
        __builtin_amdgcn_global_load_lds((const AS1 unsigned int*)(Abase + (size_t)128 * K + kk),
            (AS3 unsigned int*)((char*)&Abuf[slot][128 * 32] + dstoff), 16, 0, 0);
        __builtin_amdgcn_global_load_lds((const AS1 unsigned int*)(Wbase + kk),
            (AS3 unsigned int*)((char*)&Bbuf[slot][0] + dstoff), 16, 0, 0);
    };

    const int fr = lane & 15;
    const int kq = lane >> 4;
    const int rslot = (((((fr & 1) << 2) + kq) ^ ((fr >> 1) & 7)) << 4); // bytes
    const int aoff0 = wr * 8192 + (fr >> 1) * 128 + rslot;
    const int boff0 = wc * 2048 + (fr >> 1) * 128 + rslot;

    f32x4 acc[8][2] = {};

    const int nt = K >> 5;    // 32 K-tiles
    stage3(0, 0);
    stage3(1, 32);
    asm volatile("s_waitcnt vmcnt(3)" ::: "memory");
    __builtin_amdgcn_s_barrier();
    asm volatile("" ::: "memory");

    int slot = 0, slot2 = 2;
    for (int cur = 0; cur < nt; ++cur) {
        bf16x8 a[8], b[2];
        const char* Ab = (const char*)&Abuf[slot][0];
        const char* Bb = (const char*)&Bbuf[slot][0];
        #pragma unroll
        for (int nf = 0; nf < 2; nf++)
            b[nf] = *(const bf16x8*)(Bb + boff0 + nf * 1024);
        #pragma unroll
        for (int mf = 0; mf < 8; mf++)
            a[mf] = *(const bf16x8*)(Ab + aoff0 + mf * 1024);
        if (cur + 2 < nt) stage3(slot2, (cur + 2) << 5);
        __builtin_amdgcn_s_setprio(1);
        #pragma unroll
        for (int mf = 0; mf < 8; mf++)
            #pragma unroll
            for (int nf = 0; nf < 2; nf++)
                acc[mf][nf] = __builtin_amdgcn_mfma_f32_16x16x32_bf16(
                                  a[mf], b[nf], acc[mf][nf], 0, 0, 0);
        __builtin_amdgcn_s_setprio(0);
        if (cur + 2 < nt) { asm volatile("s_waitcnt vmcnt(3)" ::: "memory"); }
        else              { asm volatile("s_waitcnt vmcnt(0)" ::: "memory"); }
        __builtin_amdgcn_s_barrier();
        asm volatile("" ::: "memory");
        slot  = (slot  == 2) ? 0 : slot  + 1;
        slot2 = (slot2 == 2) ? 0 : slot2 + 1;
    }

    const int col0 = lane & 15;
    const int quad = lane >> 4;
    #pragma unroll
    for (int nf = 0; nf < 2; nf++) {
        const int ng = bn + wc * 32 + nf * 16 + col0;   // global col in [0, CNT*128)
        const int half = ng >> 10;                      // wave-uniform per nf
        const int n = ng & 1023;
        float* __restrict__ Cp = half ? C1 : C0;
        const float bv = half ? bias1[n] : bias0[n];
        #pragma unroll
        for (int mf = 0; mf < 8; mf++) {
            #pragma unroll
            for (int r = 0; r < 4; r++) {
                const int m = bm + wr * 128 + mf * 16 + quad * 4 + r;
                float v = acc[mf][nf][r] + bv;
                size_t off = (size_t)m * 1024 + n;
                if (resid) v += resid[off];
                Cp[off] = v;
            }
        }
    }
}

// ---------------------------------------------------------------------------
// Stockham radix-4 1024-pt FFT, twiddles precomputed per thread (w1 per
// stage, 8 VGPRs, reused across many FFTs in a block). 256 threads, 4
// complex/thread, exchanges via two swizzled float2 LDS buffers.
// ---------------------------------------------------------------------------
#define SWZ(a) ((a) ^ (((a) >> 4) & 15))

struct cplx { float r, i; };
__device__ inline cplx cmul(cplx a, cplx b) {
    return {a.r * b.r - a.i * b.i, a.r * b.i + a.i * b.r};
}

__device__ inline void r4bfly(cplx v[4], float s) {
    cplx t0 {v[0].r + v[2].r, v[0].i + v[2].i};
    cplx t1 {v[0].r - v[2].r, v[0].i - v[2].i};
    cplx t2 {v[1].r + v[3].r, v[1].i + v[3].i};
    cplx t3 {v[1].r - v[3].r, v[1].i - v[3].i};
    cplx j3 {-s * t3.i, s * t3.r};     // s*i * t3
    v[0] = {t0.r + t2.r, t0.i + t2.i};
    v[2] = {t0.r - t2.r, t0.i - t2.i};
    v[1] = {t1.r + j3.r, t1.i + j3.i};
    v[3] = {t1.r - j3.r, t1.i - j3.i};
}

template<int SIGN>
__device__ inline void make_w1(cplx w1s[4], int tid) {
    const float s = (float)SIGN;
    #pragma unroll
    for (int q = 1; q <= 3; q++) {
        const int Ls = 1 << (2 * q);
        const float ang = s * 1.57079632679489662f * (float)(tid & (Ls - 1)) / (float)Ls;
        float sn, cs; __sincosf(ang, &sn, &cs);
        w1s[q - 1] = {cs, sn};
    }
    float sn, cs;
    __sincosf(s * 1.57079632679489662f * (float)tid / 256.0f, &sn, &cs);
    w1s[3] = {cs, sn};
}

template<int SIGN>
__device__ inline void fft1024_tw(float2* bA, float2* bB, cplx v[4], int tid,
                                  const cplx w1s[4]) {
    const float s = (float)SIGN;
    r4bfly(v, s);
    {
        const int base = tid << 2;
        #pragma unroll
        for (int e = 0; e < 4; e++)
            bA[SWZ(base + e)] = make_float2(v[e].r, v[e].i);
    }
    __syncthreads();
    float2* cur = bA;
    float2* nxt = bB;
    #pragma unroll
    for (int q = 1; q <= 3; q++) {
        const int Ls = 1 << (2 * q);
        #pragma unroll
        for (int k = 0; k < 4; k++) {
            float2 t = cur[SWZ(tid + (k << 8))];
            v[k] = {t.x, t.y};
        }
        const int d = tid & (Ls - 1);
        cplx w1 = w1s[q - 1];
        cplx w2 = cmul(w1, w1);
        cplx w3 = cmul(w2, w1);
        v[1] = cmul(v[1], w1);
        v[2] = cmul(v[2], w2);
        v[3] = cmul(v[3], w3);
        r4bfly(v, s);
        const int base = ((tid >> (2 * q)) << (2 * q + 2)) + d;
        #pragma unroll
        for (int e = 0; e < 4; e++)
            nxt[SWZ(base + (e << (2 * q)))] = make_float2(v[e].r, v[e].i);
        float2* tmp = cur; cur = nxt; nxt = tmp;
        __syncthreads();
    }
    #pragma unroll
    for (int k = 0; k < 4; k++) {
        float2 t = cur[SWZ(tid + (k << 8))];
        v[k] = {t.x, t.y};
    }
    {
        cplx w1 = w1s[3];
        cplx w2 = cmul(w1, w1);
        cplx w3 = cmul(w2, w1);
        v[1] = cmul(v[1], w1);
        v[2] = cmul(v[2], w2);
        v[3] = cmul(v[3], w3);
        r4bfly(v, s);
    }
}

// ---------------------------------------------------------------------------
// Bind + fused in-chunk cumsum. One block = one 8-token chunk (2048 blocks),
// tokens sequential; running P-cumsum in registers (6 floats/thread).
// Twiddles hoisted out of the token loop. Per token: normalize key (shuffle
// reduce), z = khat + i*v, one fwd FFT, unpack Kf/Vf, P[token] = running +=
// Kf*Vf, pack Kf in place over the dead Kraw row. Finally: chunk totals row.
// ---------------------------------------------------------------------------
__global__ __launch_bounds__(256) void bind_cum_kernel(
        float* __restrict__ KIO, const float* __restrict__ V,
        float* __restrict__ P, float* __restrict__ totals) {
    __shared__ float2 bA[1024], bB[1024];
    __shared__ float red[4];
    const int blk = blockIdx.x;           // = b*NCH + chunk
    const int tid = threadIdx.x;
    const int wv  = tid >> 6;
    const int ln  = tid & 63;
    const size_t tok0 = (size_t)blk * TLEN;

    cplx w1s[4];
    make_w1<-1>(w1s, tid);

    float r0r = 0.f, r0i = 0.f, r1r = 0.f, r1i = 0.f, r2r = 0.f, r2i = 0.f;

    float kvC[4], vvC[4];
    {
        const float* krow = KIO + tok0 * D_SZ;
        const float* vrow = V   + tok0 * D_SZ;
        #pragma unroll
        for (int k = 0; k < 4; k++) {
            kvC[k] = krow[tid + (k << 8)];
            vvC[k] = vrow[tid + (k << 8)];
        }
    }

    for (int tk = 0; tk < TLEN; ++tk) {
        const size_t token = tok0 + tk;
        float* krow = KIO + token * D_SZ;

        float ss = 0.f;
        #pragma unroll
        for (int k = 0; k < 4; k++) ss += kvC[k] * kvC[k];
        #pragma unroll
        for (int m = 1; m < 64; m <<= 1) ss += __shfl_xor(ss, m, 64);
        if (ln == 0) red[wv] = ss;
        __syncthreads();     // red ready; also orders bA reuse across tokens
        const float scale = 1.0f /
            fmaxf(sqrtf(red[0] + red[1] + red[2] + red[3]), 1e-12f);

        cplx z[4];
        #pragma unroll
        for (int k = 0; k < 4; k++) z[k] = {kvC[k] * scale, vvC[k]};

        // prefetch next token's rows (latency hidden under the FFT)
        if (tk + 1 < TLEN) {
            const float* krowN = KIO + (token + 1) * D_SZ;
            const float* vrowN = V   + (token + 1) * D_SZ;
            #pragma unroll
            for (int k = 0; k < 4; k++) {
                kvC[k] = krowN[tid + (k << 8)];
                vvC[k] = vrowN[tid + (k << 8)];
            }
        }

        fft1024_tw<-1>(bA, bB, z, tid, w1s);

        #pragma unroll
        for (int e = 0; e < 4; e++)
            bA[SWZ(tid + (e << 8))] = make_float2(z[e].r, z[e].i);
        __syncthreads();

        float2* Po = (float2*)(P + token * CCH);
        auto procbin = [&](int bin, float& rr, float& ri) {
            float2 Zb = bA[SWZ(bin)];
            float2 Zm = bA[SWZ((1024 - bin) & 1023)];
            float ar = 0.5f * (Zb.x + Zm.x);
            float ai = 0.5f * (Zb.y - Zm.y);
            float br = 0.5f * (Zb.y + Zm.y);
            float bi = 0.5f * (Zm.x - Zb.x);
            rr += ar * br - ai * bi;
            ri += ar * bi + ai * br;
            Po[bin] = make_float2(rr, ri);
            if (bin == 0)        krow[0] = ar;
            else if (bin == 512) krow[1] = ar;
            else { krow[2 * bin] = ar; krow[2 * bin + 1] = ai; }
        };
        procbin(tid,       r0r, r0i);
        procbin(tid + 256, r1r, r1i);
        if (tid == 0) procbin(512, r2r, r2i);
        // no trailing barrier: next iteration's red-barrier orders bA reuse
    }

    float* trow = totals + (size_t)blk * CCH;
    trow[2 * tid]             = r0r;  trow[2 * tid + 1]         = r0i;
    trow[2 * (tid + 256)]     = r1r;  trow[2 * (tid + 256) + 1] = r1i;
    if (tid == 0) { trow[1024] = r2r; trow[1025] = r2i; }
}

// ---------------------------------------------------------------------------
// 2-level scan of chunk totals -> exclusive offsets.
// S1: within each group of 16 chunks: exclusive scan in place + group total.
// S2: exclusive scan of the NG group totals per batch.
// unbind adds totals[chunk] + gt[chunk>>4].
// ---------------------------------------------------------------------------
__global__ __launch_bounds__(256) void scan_s1(
        float* __restrict__ totals, float* __restrict__ gt) {
    const int c = blockIdx.x * 256 + threadIdx.x;
    if (c >= CCH) return;
    const int g = blockIdx.y;
    const int b = blockIdx.z;
    float run = 0.f;
    #pragma unroll
    for (int i = 0; i < 16; i++) {
        size_t idx = ((size_t)(b * NCH + g * 16 + i)) * CCH + c;
        float v = totals[idx];
        totals[idx] = run;
        run += v;
    }
    gt[((size_t)(b * NG + g)) * CCH + c] = run;
}

__global__ __launch_bounds__(256) void scan_s2(float* __restrict__ gt) {
    const int c = blockIdx.x * 256 + threadIdx.x;
    if (c >= CCH) return;
    const int b = blockIdx.y;
    float run = 0.f;
    #pragma unroll
    for (int g = 0; g < NG; g++) {
        size_t idx = ((size_t)(b * NG + g)) * CCH + c;
        float v = gt[idx];
        gt[idx] = run;
        run += v;
    }
}

// ---------------------------------------------------------------------------
// Unbind: 4 pairs (8 tokens = exactly one chunk) per block. Combined chunk
// offsets (totals+gt) loaded ONCE into LDS and reused by all 4 pairs;
// ln_g/ln_b and twiddles hoisted. Per pair: packed real iFFT
// Y = Ra_ext + i*Rb_ext -> ra = Re(z), rb = Im(z); /sqrt(t+1); LayerNorm
// (shuffle reduce) -> bf16 RLN rows.
// ---------------------------------------------------------------------------
__global__ __launch_bounds__(256) void unbind4_ln_kernel(
        const float* __restrict__ P, const float* __restrict__ totals,
        const float* __restrict__ gt, const float* __restrict__ KF,
        const float* __restrict__ ln_g, const float* __restrict__ ln_b,
        unsigned short* __restrict__ RLNb) {
    __shared__ float2 bA[1024], bB[1024];
    __shared__ float2 offsh[NBINS];
    __shared__ float red[16];
    const int blk = blockIdx.x;
    const int tid = threadIdx.x;
    const int wv  = tid >> 6;
    const int ln  = tid & 63;
    const size_t tok0 = (size_t)blk * TLEN;     // 8 tokens, one chunk
    const int bidx  = (int)(tok0 >> 12);
    const int t0    = (int)(tok0 & (L_SZ - 1));
    const int chunk = t0 >> 3;                  // TLEN=8

    // combined chunk offset row -> LDS (once per block)
    {
        const float2* off2 = (const float2*)(totals + (size_t)(bidx * NCH + chunk) * CCH);
        const float2* gof2 = (const float2*)(gt + (size_t)(bidx * NG + (chunk >> 4)) * CCH);
        auto ldo = [&](int bin) {
            float2 o = off2[bin], g = gof2[bin];
            offsh[bin] = make_float2(o.x + g.x, o.y + g.y);
        };
        ldo(tid); ldo(tid + 256);
        if (tid == 0) ldo(512);
    }

    cplx w1s[4];
    make_w1<1>(w1s, tid);

    float gv[4], bev[4];
    #pragma unroll
    for (int e = 0; e < 4; e++) {
        gv[e]  = ln_g[tid + (e << 8)];
        bev[e] = ln_b[tid + (e << 8)];
    }
    __syncthreads();   // offsh ready

    for (int p = 0; p < 4; ++p) {
        const size_t ta = tok0 + 2 * p, tb = ta + 1;
        const float2* Sa2 = (const float2*)(P + ta * CCH);
        const float2* Sb2 = (const float2*)(P + tb * CCH);
        const float*  Ka  = KF + ta * D_SZ;
        const float*  Kb  = KF + tb * D_SZ;

        auto zc = [&](int bin, const float2* S2, const float* kf, float2 og) {
            float kr, ki;
            if (bin == 0)        { kr = kf[0]; ki = 0.f; }
            else if (bin == 512) { kr = kf[1]; ki = 0.f; }
            else { float2 k2 = *(const float2*)(kf + 2 * bin); kr = k2.x; ki = k2.y; }
            float2 s2 = S2[bin];
            float sr = s2.x + og.x, si = s2.y + og.y;
            return make_float2(sr * kr + si * ki, si * kr - sr * ki);
        };
        auto fill = [&](int bin) {
            float2 og = offsh[bin];
            float2 Za = zc(bin, Sa2, Ka, og);
            float2 Zb = zc(bin, Sb2, Kb, og);
            bA[SWZ(bin)] = make_float2(Za.x - Zb.y, Za.y + Zb.x);
            if (bin != 0 && bin != 512)
                bA[SWZ(1024 - bin)] = make_float2(Za.x + Zb.y, Zb.x - Za.y);
        };
        fill(tid);
        fill(tid + 256);
        if (tid == 0) fill(512);
        __syncthreads();

        cplx z[4];
        #pragma unroll
        for (int k = 0; k < 4; k++) {
            float2 c = bA[SWZ(tid + (k << 8))];
            z[k] = {c.x, c.y};
        }
        __syncthreads();
        fft1024_tw<1>(bA, bB, z, tid, w1s);   // z = 1024 * (ra + i*rb)

        const int t_a = t0 + 2 * p;
        const float sa = (1.0f / 1024.0f) * rsqrtf((float)(t_a + 1));
        const float sb = (1.0f / 1024.0f) * rsqrtf((float)(t_a + 2));
        float ra[4], rb[4];
        float s1a = 0.f, s2a = 0.f, s1b = 0.f, s2b = 0.f;
        #pragma unroll
        for (int e = 0; e < 4; e++) {
            ra[e] = z[e].r * sa;
            rb[e] = z[e].i * sb;
            s1a += ra[e]; s2a += ra[e] * ra[e];
            s1b += rb[e]; s2b += rb[e] * rb[e];
        }
        #pragma unroll
        for (int m = 1; m < 64; m <<= 1) {
            s1a += __shfl_xor(s1a, m, 64);
            s2a += __shfl_xor(s2a, m, 64);
            s1b += __shfl_xor(s1b, m, 64);
            s2b += __shfl_xor(s2b, m, 64);
        }
        if (ln == 0) {
            red[wv] = s1a; red[4 + wv] = s2a; red[8 + wv] = s1b; red[12 + wv] = s2b;
        }
        __syncthreads();
        const float S1a = red[0] + red[1] + red[2] + red[3];
        const float S2a = red[4] + red[5] + red[6] + red[7];
        const float S1b = red[8] + red[9] + red[10] + red[11];
        const float S2b = red[12] + red[13] + red[14] + red[15];
        const float mua = S1a * (1.0f / 1024.0f);
        const float vara = S2a * (1.0f / 1024.0f) - mua * mua;
        const float rsa = rsqrtf(vara + 1e-5f);
        const float mub = S1b * (1.0f / 1024.0f);
        const float varb = S2b * (1.0f / 1024.0f) - mub * mub;
        const float rsb = rsqrtf(varb + 1e-5f);

        unsigned short* outA = RLNb + ta * D_SZ;
        unsigned short* outB = RLNb + tb * D_SZ;
        #pragma unroll
        for (int e = 0; e < 4; e++) {
            const int d = tid + (e << 8);
            outA[d] = f2bf((ra[e] - mua) * rsa * gv[e] + bev[e]);
            outB[d] = f2bf((rb[e] - mub) * rsb * gv[e] + bev[e]);
        }
        __syncthreads();   // red/bA safe for next pair
    }
}

// ---------------------------------------------------------------------------
// Workspace (bytes)  [total 230.2 MiB — BELOW the R5-proven 234.4 MiB]:
//   Kraw   fp32 M*D        = 64.0 MB  (keys; bind overwrites with packed Kf)
//   V      fp32 M*D        = 64.0 MB  (dead after bind; reused as bf16 RLN)
//   P      fp32 M*CCH      = 64.1 MB  (bind writes inclusive-in-chunk cumsum)
//   xb     bf16 M*D        = 32.0 MB  (dead after gemm16; totals+gt OVERLAY it:
//            totals fp32 B*NCH*CCH = 8.4 MB, gt fp32 B*NG*CCH = 0.5 MB.
//            Stream-serialized: gemm16 finishes reading xb before bind_cum
//            writes totals. gemm8 does not touch xb.)
//   WB     bf16 2048*D     =  4.0 MB  (Wk ++ Wv)
//   Wob    bf16 D*D        =  2.0 MB
// ---------------------------------------------------------------------------
extern "C" void kernel_launch(void* const* d_in, const int* in_sizes, int n_in,
                              void* d_out, int out_size, void* d_ws, size_t ws_size,
                              hipStream_t stream) {
    (void)in_sizes; (void)n_in; (void)out_size; (void)ws_size;
    const float* x    = (const float*)d_in[0];
    const float* Wk   = (const float*)d_in[1];
    const float* bk   = (const float*)d_in[2];
    const float* Wv   = (const float*)d_in[3];
    const float* bv   = (const float*)d_in[4];
    const float* ln_g = (const float*)d_in[5];
    const float* ln_b = (const float*)d_in[6];
    const float* Wo   = (const float*)d_in[7];
    const float* bo   = (const float*)d_in[8];
    float* out = (float*)d_out;

    char* w = (char*)d_ws;
    float* Kraw   = (float*)w;  w += (size_t)M_SZ * D_SZ * 4;
    float* V      = (float*)w;  w += (size_t)M_SZ * D_SZ * 4;
    float* P      = (float*)w;  w += (size_t)M_SZ * CCH * 4;
    unsigned short* xb  = (unsigned short*)w;  w += (size_t)M_SZ * D_SZ * 2;
    unsigned short* WB  = (unsigned short*)w;  w += (size_t)2 * D_SZ * D_SZ * 2;
    unsigned short* Wob = (unsigned short*)w;  w += (size_t)D_SZ * D_SZ * 2;
    unsigned short* RLNb = (unsigned short*)V;  // overlays dead V
    // totals + gt overlay the dead xb region (xb only read by gemm16)
    float* totals = (float*)xb;                                   // 8.4 MB
    float* gt     = (float*)xb + (size_t)B_SZ * NCH * CCH;        // 0.5 MB

    const int n8x = M_SZ * D_SZ / 8;
    const int n8w = D_SZ * D_SZ / 8;
    cast_f32_bf16<<<n8x / 256, 256, 0, stream>>>(x, xb, n8x);
    dim3 wgrid(n8w / 256, 3);
    cast_w3<<<wgrid, 256, 0, stream>>>(Wk, Wv, Wo, WB, Wob, n8w);

    // fused K/V projection: N=2048 (first half -> Kraw, second -> V)
    gemm_mfma<16><<<(M_SZ / 256) * 16, 512, 0, stream>>>(
        xb, WB, bk, bv, nullptr, Kraw, V, M_SZ, D_SZ);

    // bind + in-chunk cumsum (one block per 8-token chunk)
    bind_cum_kernel<<<M_SZ / TLEN, 256, 0, stream>>>(Kraw, V, P, totals);

    // 2-level exclusive scan of chunk totals
    dim3 g1((CCH + 255) / 256, NG, B_SZ);
    scan_s1<<<g1, 256, 0, stream>>>(totals, gt);
    dim3 g2((CCH + 255) / 256, B_SZ);
    scan_s2<<<g2, 256, 0, stream>>>(gt);

    // unbind: 4 pairs (one chunk) per block, packed real iFFT
    unbind4_ln_kernel<<<M_SZ / TLEN, 256, 0, stream>>>(
        P, totals, gt, Kraw, ln_g, ln_b, RLNb);

    // output GEMM with fp32 residual
    gemm_mfma<8><<<(M_SZ / 256) * 8, 512, 0, stream>>>(
        RLNb, Wob, bo, bo, x, out, out, M_SZ, D_SZ);
}

// Round 9
// 389.733 us; speedup vs baseline: 1.2993x; 1.0038x over previous
//
#include <hip/hip_runtime.h>
#include <math.h>

// Problem constants (from reference): B=4, L=4096, D=1024
#define B_SZ 4
#define L_SZ 4096
#define D_SZ 1024
#define M_SZ (B_SZ * L_SZ)      // 16384 tokens
#define NBINS 513               // rfft bins for D=1024
#define CCH   (2 * NBINS)       // 1026 bf16 channels per token (interleaved re,im)
#define TLEN 8                  // tokens per cumsum chunk (= per bind block)
#define NCH  (L_SZ / TLEN)      // 512 chunks per batch
#define NG   32                 // chunk groups (16 chunks each) for 2-level scan

typedef short bf16x8 __attribute__((ext_vector_type(8)));
typedef float f32x4  __attribute__((ext_vector_type(4)));
typedef unsigned short us8 __attribute__((ext_vector_type(8)));

#define AS1 __attribute__((address_space(1)))
#define AS3 __attribute__((address_space(3)))

// round-to-nearest-even f32 -> bf16
__device__ inline unsigned short f2bf(float f) {
    unsigned int u = __float_as_uint(f);
    u += 0x7fffu + ((u >> 16) & 1u);
    return (unsigned short)(u >> 16);
}
__device__ inline float bf2f(unsigned short u) {
    return __uint_as_float(((unsigned int)u) << 16);
}

// ---------------------------------------------------------------------------
// f32 -> bf16 cast, 8 elements/thread
// ---------------------------------------------------------------------------
__global__ __launch_bounds__(256) void cast_f32_bf16(
        const float* __restrict__ in, unsigned short* __restrict__ out, int n8) {
    int i = blockIdx.x * 256 + threadIdx.x;
    if (i >= n8) return;
    const float4* p = (const float4*)in + 2 * (size_t)i;
    float4 a = p[0], b = p[1];
    us8 o;
    o[0] = f2bf(a.x); o[1] = f2bf(a.y); o[2] = f2bf(a.z); o[3] = f2bf(a.w);
    o[4] = f2bf(b.x); o[5] = f2bf(b.y); o[6] = f2bf(b.z); o[7] = f2bf(b.w);
    *(us8*)(out + (size_t)i * 8) = o;
}

// merged weight casts: blockIdx.y selects {Wk->WB, Wv->WB+1M, Wo->Wob}
__global__ __launch_bounds__(256) void cast_w3(
        const float* __restrict__ Wk, const float* __restrict__ Wv,
        const float* __restrict__ Wo,
        unsigned short* __restrict__ WB, unsigned short* __restrict__ Wob, int n8) {
    int i = blockIdx.x * 256 + threadIdx.x;
    if (i >= n8) return;
    const int which = blockIdx.y;
    const float* src = (which == 0) ? Wk : (which == 1) ? Wv : Wo;
    unsigned short* dst = (which == 0) ? WB : (which == 1) ? (WB + D_SZ * D_SZ) : Wob;
    const float4* p = (const float4*)src + 2 * (size_t)i;
    float4 a = p[0], b = p[1];
    us8 o;
    o[0] = f2bf(a.x); o[1] = f2bf(a.y); o[2] = f2bf(a.z); o[3] = f2bf(a.w);
    o[4] = f2bf(b.x); o[5] = f2bf(b.y); o[6] = f2bf(b.z); o[7] = f2bf(b.w);
    *(us8*)(dst + (size_t)i * 8) = o;
}

// ---------------------------------------------------------------------------
// bf16 MFMA GEMM, 256x128 tile, BK=32, 3 LDS slots (72 KiB -> 2 blocks/CU),
// 512 threads = 8 waves (2M x 4N), per-wave 128x32 output. (R4, known-good.)
// OBF16: store C as bf16 (no residual path); else fp32 store (+optional resid).
// ---------------------------------------------------------------------------
template<int CNT, bool OBF16>   // N = CNT*128
__global__ __launch_bounds__(512, 4) void gemm_mfma(
        const unsigned short* __restrict__ A, const unsigned short* __restrict__ W,
        const float* __restrict__ bias0, const float* __restrict__ bias1,
        const float* __restrict__ resid,
        void* __restrict__ C0v, void* __restrict__ C1v, int M, int K) {
    __shared__ unsigned short Abuf[3][256 * 32];   // 3 x 16 KiB
    __shared__ unsigned short Bbuf[3][128 * 32];   // 3 x  8 KiB
    const int id   = blockIdx.x;
    const int bx   = (id >> 3) % CNT;
    const int by   = (id & 7) + 8 * (id / (8 * CNT));
    const int tid  = threadIdx.x;
    const int lane = tid & 63;
    const int wid  = tid >> 6;        // 0..7
    const int wr   = wid >> 2;        // 0..1 (M, 128 rows)
    const int wc   = wid & 3;         // 0..3 (N, 32 cols)
    const int bm   = by * 256;
    const int bn   = bx * 128;

    const int sl = tid >> 3;              // line 0..63 (2 rows each)
    const int sq = (tid & 7) ^ (sl & 7);  // logical slot at this dest position
    const int srow = 2 * sl + (sq >> 2);  // row within chunk
    const int skof = (sq & 3) * 8;        // k offset (shorts)
    const unsigned short* Abase = A + (size_t)(bm + srow) * K + skof;
    const unsigned short* Wbase = W + (size_t)(bn + srow) * K + skof;
    const int dstoff = tid * 16;          // linear dest bytes within chunk

    auto stage3 = [&](int slot, int kk) {
        __builtin_amdgcn_global_load_lds((const AS1 unsigned int*)(Abase + kk),
            (AS3 unsigned int*)((char*)&Abuf[slot][0] + dstoff), 16, 0, 0);
        __builtin_amdgcn_global_load_lds((const AS1 unsigned int*)(Abase + (size_t)128 * K + kk),
            (AS3 unsigned int*)((char*)&Abuf[slot][128 * 32] + dstoff), 16, 0, 0);
        __builtin_amdgcn_global_load_lds((const AS1 unsigned int*)(Wbase + kk),
            (AS3 unsigned int*)((char*)&Bbuf[slot][0] + dstoff), 16, 0, 0);
    };

    const int fr = lane & 15;
    const int kq = lane >> 4;
    const int rslot = (((((fr & 1) << 2) + kq) ^ ((fr >> 1) & 7)) << 4); // bytes
    const int aoff0 = wr * 8192 + (fr >> 1) * 128 + rslot;
    const int boff0 = wc * 2048 + (fr >> 1) * 128 + rslot;

    f32x4 acc[8][2] = {};

    const int nt = K >> 5;    // 32 K-tiles
    stage3(0, 0);
    stage3(1, 32);
    asm volatile("s_waitcnt vmcnt(3)" ::: "memory");
    __builtin_amdgcn_s_barrier();
    asm volatile("" ::: "memory");

    int slot = 0, slot2 = 2;
    for (int cur = 0; cur < nt; ++cur) {
        bf16x8 a[8], b[2];
        const char* Ab = (const char*)&Abuf[slot][0];
        const char* Bb = (const char*)&Bbuf[slot][0];
        #pragma unroll
        for (int nf = 0; nf < 2; nf++)
            b[nf] = *(const bf16x8*)(Bb + boff0 + nf * 1024);
        #pragma unroll
        for (int mf = 0; mf < 8; mf++)
            a[mf] = *(const bf16x8*)(Ab + aoff0 + mf * 1024);
        if (cur + 2 < nt) stage3(slot2, (cur + 2) << 5);
        __builtin_amdgcn_s_setprio(1);
        #pragma unroll
        for (int mf = 0; mf < 8; mf++)
            #pragma unroll
            for (int nf = 0; nf < 2; nf++)
                acc[mf][nf] = __builtin_amdgcn_mfma_f32_16x16x32_bf16(
                                  a[mf], b[nf], acc[mf][nf], 0, 0, 0);
        __builtin_amdgcn_s_setprio(0);
        if (cur + 2 < nt) { asm volatile("s_waitcnt vmcnt(3)" ::: "memory"); }
        else              { asm volatile("s_waitcnt vmcnt(0)" ::: "memory"); }
        __builtin_amdgcn_s_barrier();
        asm volatile("" ::: "memory");
        slot  = (slot  == 2) ? 0 : slot  + 1;
        slot2 = (slot2 == 2) ? 0 : slot2 + 1;
    }

    const int col0 = lane & 15;
    const int quad = lane >> 4;
    #pragma unroll
    for (int nf = 0; nf < 2; nf++) {
        const int ng = bn + wc * 32 + nf * 16 + col0;   // global col in [0, CNT*128)
        const int half = ng >> 10;                      // wave-uniform per nf
        const int n = ng & 1023;
        const float bv = half ? bias1[n] : bias0[n];
        void* Cv = half ? C1v : C0v;
        #pragma unroll
        for (int mf = 0; mf < 8; mf++) {
            #pragma unroll
            for (int r = 0; r < 4; r++) {
                const int m = bm + wr * 128 + mf * 16 + quad * 4 + r;
                float v = acc[mf][nf][r] + bv;
                size_t off = (size_t)m * 1024 + n;
                if constexpr (OBF16) {
                    ((unsigned short*)Cv)[off] = f2bf(v);
                } else {
                    if (resid) v += resid[off];
                    ((float*)Cv)[off] = v;
                }
            }
        }
    }
}

// ---------------------------------------------------------------------------
// Stockham radix-4 1024-pt FFT, twiddles precomputed per thread (w1 per
// stage, 8 VGPRs, reused across many FFTs in a block). 256 threads, 4
// complex/thread, exchanges via two swizzled float2 LDS buffers.
// ---------------------------------------------------------------------------
#define SWZ(a) ((a) ^ (((a) >> 4) & 15))

struct cplx { float r, i; };
__device__ inline cplx cmul(cplx a, cplx b) {
    return {a.r * b.r - a.i * b.i, a.r * b.i + a.i * b.r};
}

__device__ inline void r4bfly(cplx v[4], float s) {
    cplx t0 {v[0].r + v[2].r, v[0].i + v[2].i};
    cplx t1 {v[0].r - v[2].r, v[0].i - v[2].i};
    cplx t2 {v[1].r + v[3].r, v[1].i + v[3].i};
    cplx t3 {v[1].r - v[3].r, v[1].i - v[3].i};
    cplx j3 {-s * t3.i, s * t3.r};     // s*i * t3
    v[0] = {t0.r + t2.r, t0.i + t2.i};
    v[2] = {t0.r - t2.r, t0.i - t2.i};
    v[1] = {t1.r + j3.r, t1.i + j3.i};
    v[3] = {t1.r - j3.r, t1.i - j3.i};
}

template<int SIGN>
__device__ inline void make_w1(cplx w1s[4], int tid) {
    const float s = (float)SIGN;
    #pragma unroll
    for (int q = 1; q <= 3; q++) {
        const int Ls = 1 << (2 * q);
        const float ang = s * 1.57079632679489662f * (float)(tid & (Ls - 1)) / (float)Ls;
        float sn, cs; __sincosf(ang, &sn, &cs);
        w1s[q - 1] = {cs, sn};
    }
    float sn, cs;
    __sincosf(s * 1.57079632679489662f * (float)tid / 256.0f, &sn, &cs);
    w1s[3] = {cs, sn};
}

template<int SIGN>
__device__ inline void fft1024_tw(float2* bA, float2* bB, cplx v[4], int tid,
                                  const cplx w1s[4]) {
    const float s = (float)SIGN;
    r4bfly(v, s);
    {
        const int base = tid << 2;
        #pragma unroll
        for (int e = 0; e < 4; e++)
            bA[SWZ(base + e)] = make_float2(v[e].r, v[e].i);
    }
    __syncthreads();
    float2* cur = bA;
    float2* nxt = bB;
    #pragma unroll
    for (int q = 1; q <= 3; q++) {
        const int Ls = 1 << (2 * q);
        #pragma unroll
        for (int k = 0; k < 4; k++) {
            float2 t = cur[SWZ(tid + (k << 8))];
            v[k] = {t.x, t.y};
        }
        const int d = tid & (Ls - 1);
        cplx w1 = w1s[q - 1];
        cplx w2 = cmul(w1, w1);
        cplx w3 = cmul(w2, w1);
        v[1] = cmul(v[1], w1);
        v[2] = cmul(v[2], w2);
        v[3] = cmul(v[3], w3);
        r4bfly(v, s);
        const int base = ((tid >> (2 * q)) << (2 * q + 2)) + d;
        #pragma unroll
        for (int e = 0; e < 4; e++)
            nxt[SWZ(base + (e << (2 * q)))] = make_float2(v[e].r, v[e].i);
        float2* tmp = cur; cur = nxt; nxt = tmp;
        __syncthreads();
    }
    #pragma unroll
    for (int k = 0; k < 4; k++) {
        float2 t = cur[SWZ(tid + (k << 8))];
        v[k] = {t.x, t.y};
    }
    {
        cplx w1 = w1s[3];
        cplx w2 = cmul(w1, w1);
        cplx w3 = cmul(w2, w1);
        v[1] = cmul(v[1], w1);
        v[2] = cmul(v[2], w2);
        v[3] = cmul(v[3], w3);
        r4bfly(v, s);
    }
}

// ---------------------------------------------------------------------------
// Bind + fused in-chunk cumsum. One block = one 8-token chunk (2048 blocks).
// K,V inputs are bf16 (from gemm16). Running P-cumsum kept in FP32 registers;
// P stored bf16 (re,im pairs). Kf packed bf16 in place over the dead K row:
// ushort[0]=Kf[0].re, [1]=Kf[512].re, [2b],[2b+1]=Kf[b] b=1..511 -> 1024
// ushorts = exactly one row. Chunk totals stay fp32 (large magnitudes).
// ---------------------------------------------------------------------------
__global__ __launch_bounds__(256) void bind_cum_kernel(
        unsigned short* __restrict__ KIO, const unsigned short* __restrict__ Vb,
        unsigned short* __restrict__ P, float* __restrict__ totals) {
    __shared__ float2 bA[1024], bB[1024];
    __shared__ float red[4];
    const int blk = blockIdx.x;           // = b*NCH + chunk
    const int tid = threadIdx.x;
    const int wv  = tid >> 6;
    const int ln  = tid & 63;
    const size_t tok0 = (size_t)blk * TLEN;

    cplx w1s[4];
    make_w1<-1>(w1s, tid);

    float r0r = 0.f, r0i = 0.f, r1r = 0.f, r1i = 0.f, r2r = 0.f, r2i = 0.f;

    float kvC[4], vvC[4];
    {
        const unsigned short* krow = KIO + tok0 * D_SZ;
        const unsigned short* vrow = Vb  + tok0 * D_SZ;
        #pragma unroll
        for (int k = 0; k < 4; k++) {
            kvC[k] = bf2f(krow[tid + (k << 8)]);
            vvC[k] = bf2f(vrow[tid + (k << 8)]);
        }
    }

    for (int tk = 0; tk < TLEN; ++tk) {
        const size_t token = tok0 + tk;
        unsigned short* krow = KIO + token * D_SZ;

        float ss = 0.f;
        #pragma unroll
        for (int k = 0; k < 4; k++) ss += kvC[k] * kvC[k];
        #pragma unroll
        for (int m = 1; m < 64; m <<= 1) ss += __shfl_xor(ss, m, 64);
        if (ln == 0) red[wv] = ss;
        __syncthreads();     // red ready; also orders bA reuse across tokens
        const float scale = 1.0f /
            fmaxf(sqrtf(red[0] + red[1] + red[2] + red[3]), 1e-12f);

        cplx z[4];
        #pragma unroll
        for (int k = 0; k < 4; k++) z[k] = {kvC[k] * scale, vvC[k]};

        // prefetch next token's rows (latency hidden under the FFT)
        if (tk + 1 < TLEN) {
            const unsigned short* krowN = KIO + (token + 1) * D_SZ;
            const unsigned short* vrowN = Vb  + (token + 1) * D_SZ;
            #pragma unroll
            for (int k = 0; k < 4; k++) {
                kvC[k] = bf2f(krowN[tid + (k << 8)]);
                vvC[k] = bf2f(vrowN[tid + (k << 8)]);
            }
        }

        fft1024_tw<-1>(bA, bB, z, tid, w1s);

        #pragma unroll
        for (int e = 0; e < 4; e++)
            bA[SWZ(tid + (e << 8))] = make_float2(z[e].r, z[e].i);
        __syncthreads();

        ushort2* Po = (ushort2*)(P + token * CCH);
        auto procbin = [&](int bin, float& rr, float& ri) {
            float2 Zb = bA[SWZ(bin)];
            float2 Zm = bA[SWZ((1024 - bin) & 1023)];
            float ar = 0.5f * (Zb.x + Zm.x);
            float ai = 0.5f * (Zb.y - Zm.y);
            float br = 0.5f * (Zb.y + Zm.y);
            float bi = 0.5f * (Zm.x - Zb.x);
            rr += ar * br - ai * bi;
            ri += ar * bi + ai * br;
            ushort2 pv; pv.x = f2bf(rr); pv.y = f2bf(ri);
            Po[bin] = pv;
            if (bin == 0)        krow[0] = f2bf(ar);
            else if (bin == 512) krow[1] = f2bf(ar);
            else {
                ushort2 kv2; kv2.x = f2bf(ar); kv2.y = f2bf(ai);
                *(ushort2*)(krow + 2 * bin) = kv2;
            }
        };
        procbin(tid,       r0r, r0i);
        procbin(tid + 256, r1r, r1i);
        if (tid == 0) procbin(512, r2r, r2i);
        // no trailing barrier: next iteration's red-barrier orders bA reuse
    }

    float* trow = totals + (size_t)blk * CCH;
    trow[2 * tid]             = r0r;  trow[2 * tid + 1]         = r0i;
    trow[2 * (tid + 256)]     = r1r;  trow[2 * (tid + 256) + 1] = r1i;
    if (tid == 0) { trow[1024] = r2r; trow[1025] = r2i; }
}

// ---------------------------------------------------------------------------
// 2-level scan of chunk totals -> exclusive offsets (fp32 throughout).
// ---------------------------------------------------------------------------
__global__ __launch_bounds__(256) void scan_s1(
        float* __restrict__ totals, float* __restrict__ gt) {
    const int c = blockIdx.x * 256 + threadIdx.x;
    if (c >= CCH) return;
    const int g = blockIdx.y;
    const int b = blockIdx.z;
    float run = 0.f;
    #pragma unroll
    for (int i = 0; i < 16; i++) {
        size_t idx = ((size_t)(b * NCH + g * 16 + i)) * CCH + c;
        float v = totals[idx];
        totals[idx] = run;
        run += v;
    }
    gt[((size_t)(b * NG + g)) * CCH + c] = run;
}

__global__ __launch_bounds__(256) void scan_s2(float* __restrict__ gt) {
    const int c = blockIdx.x * 256 + threadIdx.x;
    if (c >= CCH) return;
    const int b = blockIdx.y;
    float run = 0.f;
    #pragma unroll
    for (int g = 0; g < NG; g++) {
        size_t idx = ((size_t)(b * NG + g)) * CCH + c;
        float v = gt[idx];
        gt[idx] = run;
        run += v;
    }
}

// ---------------------------------------------------------------------------
// Unbind: 4 pairs (8 tokens = one chunk) per block. S = bf16(P) + fp32
// offsets (totals+gt cached in LDS, once per block). Kf read bf16-packed.
// Per pair: packed real iFFT Y = Ra_ext + i*Rb_ext -> ra,rb; /sqrt(t+1);
// LayerNorm (shuffle reduce) -> bf16 RLN rows.
// ---------------------------------------------------------------------------
__global__ __launch_bounds__(256) void unbind4_ln_kernel(
        const unsigned short* __restrict__ P, const float* __restrict__ totals,
        const float* __restrict__ gt, const unsigned short* __restrict__ KF,
        const float* __restrict__ ln_g, const float* __restrict__ ln_b,
        unsigned short* __restrict__ RLNb) {
    __shared__ float2 bA[1024], bB[1024];
    __shared__ float2 offsh[NBINS];
    __shared__ float red[16];
    const int blk = blockIdx.x;
    const int tid = threadIdx.x;
    const int wv  = tid >> 6;
    const int ln  = tid & 63;
    const size_t tok0 = (size_t)blk * TLEN;     // 8 tokens, one chunk
    const int bidx  = (int)(tok0 >> 12);
    const int t0    = (int)(tok0 & (L_SZ - 1));
    const int chunk = t0 >> 3;                  // TLEN=8

    // combined chunk offset row -> LDS (once per block)
    {
        const float2* off2 = (const float2*)(totals + (size_t)(bidx * NCH + chunk) * CCH);
        const float2* gof2 = (const float2*)(gt + (size_t)(bidx * NG + (chunk >> 4)) * CCH);
        auto ldo = [&](int bin) {
            float2 o = off2[bin], g = gof2[bin];
            offsh[bin] = make_float2(o.x + g.x, o.y + g.y);
        };
        ldo(tid); ldo(tid + 256);
        if (tid == 0) ldo(512);
    }

    cplx w1s[4];
    make_w1<1>(w1s, tid);

    float gv[4], bev[4];
    #pragma unroll
    for (int e = 0; e < 4; e++) {
        gv[e]  = ln_g[tid + (e << 8)];
        bev[e] = ln_b[tid + (e << 8)];
    }
    __syncthreads();   // offsh ready

    for (int p = 0; p < 4; ++p) {
        const size_t ta = tok0 + 2 * p, tb = ta + 1;
        const ushort2* Sa2 = (const ushort2*)(P + ta * CCH);
        const ushort2* Sb2 = (const ushort2*)(P + tb * CCH);
        const unsigned short* Ka = KF + ta * D_SZ;
        const unsigned short* Kb = KF + tb * D_SZ;

        auto zc = [&](int bin, const ushort2* S2, const unsigned short* kf, float2 og) {
            float kr, ki;
            if (bin == 0)        { kr = bf2f(kf[0]); ki = 0.f; }
            else if (bin == 512) { kr = bf2f(kf[1]); ki = 0.f; }
            else {
                ushort2 k2 = *(const ushort2*)(kf + 2 * bin);
                kr = bf2f(k2.x); ki = bf2f(k2.y);
            }
            ushort2 s2 = S2[bin];
            float sr = bf2f(s2.x) + og.x, si = bf2f(s2.y) + og.y;
            return make_float2(sr * kr + si * ki, si * kr - sr * ki);
        };
        auto fill = [&](int bin) {
            float2 og = offsh[bin];
            float2 Za = zc(bin, Sa2, Ka, og);
            float2 Zb = zc(bin, Sb2, Kb, og);
            bA[SWZ(bin)] = make_float2(Za.x - Zb.y, Za.y + Zb.x);
            if (bin != 0 && bin != 512)
                bA[SWZ(1024 - bin)] = make_float2(Za.x + Zb.y, Zb.x - Za.y);
        };
        fill(tid);
        fill(tid + 256);
        if (tid == 0) fill(512);
        __syncthreads();

        cplx z[4];
        #pragma unroll
        for (int k = 0; k < 4; k++) {
            float2 c = bA[SWZ(tid + (k << 8))];
            z[k] = {c.x, c.y};
        }
        __syncthreads();
        fft1024_tw<1>(bA, bB, z, tid, w1s);   // z = 1024 * (ra + i*rb)

        const int t_a = t0 + 2 * p;
        const float sa = (1.0f / 1024.0f) * rsqrtf((float)(t_a + 1));
        const float sb = (1.0f / 1024.0f) * rsqrtf((float)(t_a + 2));
        float ra[4], rb[4];
        float s1a = 0.f, s2a = 0.f, s1b = 0.f, s2b = 0.f;
        #pragma unroll
        for (int e = 0; e < 4; e++) {
            ra[e] = z[e].r * sa;
            rb[e] = z[e].i * sb;
            s1a += ra[e]; s2a += ra[e] * ra[e];
            s1b += rb[e]; s2b += rb[e] * rb[e];
        }
        #pragma unroll
        for (int m = 1; m < 64; m <<= 1) {
            s1a += __shfl_xor(s1a, m, 64);
            s2a += __shfl_xor(s2a, m, 64);
            s1b += __shfl_xor(s1b, m, 64);
            s2b += __shfl_xor(s2b, m, 64);
        }
        if (ln == 0) {
            red[wv] = s1a; red[4 + wv] = s2a; red[8 + wv] = s1b; red[12 + wv] = s2b;
        }
        __syncthreads();
        const float S1a = red[0] + red[1] + red[2] + red[3];
        const float S2a = red[4] + red[5] + red[6] + red[7];
        const float S1b = red[8] + red[9] + red[10] + red[11];
        const float S2b = red[12] + red[13] + red[14] + red[15];
        const float mua = S1a * (1.0f / 1024.0f);
        const float vara = S2a * (1.0f / 1024.0f) - mua * mua;
        const float rsa = rsqrtf(vara + 1e-5f);
        const float mub = S1b * (1.0f / 1024.0f);
        const float varb = S2b * (1.0f / 1024.0f) - mub * mub;
        const float rsb = rsqrtf(varb + 1e-5f);

        unsigned short* outA = RLNb + ta * D_SZ;
        unsigned short* outB = RLNb + tb * D_SZ;
        #pragma unroll
        for (int e = 0; e < 4; e++) {
            const int d = tid + (e << 8);
            outA[d] = f2bf((ra[e] - mua) * rsa * gv[e] + bev[e]);
            outB[d] = f2bf((rb[e] - mub) * rsb * gv[e] + bev[e]);
        }
        __syncthreads();   // red/bA safe for next pair
    }
}

// ---------------------------------------------------------------------------
// Workspace (bytes)  [total ~136 MiB — far below the proven 234 MiB]:
//   Kb     bf16 M*D        = 32.0 MB  (keys; bind overwrites with packed Kf)
//   Vb     bf16 M*D        = 32.0 MB  (dead after bind; reused as bf16 RLN)
//   Pb     bf16 M*CCH      = 33.6 MB  (bind writes inclusive-in-chunk cumsum)
//   xb     bf16 M*D        = 32.0 MB  (dead after gemm16; totals fp32 8.4 MB
//                                      + gt fp32 0.5 MB OVERLAY it)
//   WB     bf16 2048*D     =  4.0 MB  (Wk ++ Wv)
//   Wob    bf16 D*D        =  2.0 MB
// ---------------------------------------------------------------------------
extern "C" void kernel_launch(void* const* d_in, const int* in_sizes, int n_in,
                              void* d_out, int out_size, void* d_ws, size_t ws_size,
                              hipStream_t stream) {
    (void)in_sizes; (void)n_in; (void)out_size; (void)ws_size;
    const float* x    = (const float*)d_in[0];
    const float* Wk   = (const float*)d_in[1];
    const float* bk   = (const float*)d_in[2];
    const float* Wv   = (const float*)d_in[3];
    const float* bv   = (const float*)d_in[4];
    const float* ln_g = (const float*)d_in[5];
    const float* ln_b = (const float*)d_in[6];
    const float* Wo   = (const float*)d_in[7];
    const float* bo   = (const float*)d_in[8];
    float* out = (float*)d_out;

    char* w = (char*)d_ws;
    unsigned short* Kb  = (unsigned short*)w;  w += (size_t)M_SZ * D_SZ * 2;
    unsigned short* Vb  = (unsigned short*)w;  w += (size_t)M_SZ * D_SZ * 2;
    unsigned short* Pb  = (unsigned short*)w;  w += (size_t)M_SZ * CCH * 2;
    unsigned short* xb  = (unsigned short*)w;  w += (size_t)M_SZ * D_SZ * 2;
    unsigned short* WB  = (unsigned short*)w;  w += (size_t)2 * D_SZ * D_SZ * 2;
    unsigned short* Wob = (unsigned short*)w;  w += (size_t)D_SZ * D_SZ * 2;
    unsigned short* RLNb = Vb;  // overlays dead Vb
    // totals + gt overlay the dead xb region (xb only read by gemm16)
    float* totals = (float*)xb;                                   // 8.4 MB
    float* gt     = (float*)xb + (size_t)B_SZ * NCH * CCH;        // 0.5 MB

    const int n8x = M_SZ * D_SZ / 8;
    const int n8w = D_SZ * D_SZ / 8;
    cast_f32_bf16<<<n8x / 256, 256, 0, stream>>>(x, xb, n8x);
    dim3 wgrid(n8w / 256, 3);
    cast_w3<<<wgrid, 256, 0, stream>>>(Wk, Wv, Wo, WB, Wob, n8w);

    // fused K/V projection: N=2048, bf16 outputs (first half -> Kb, second -> Vb)
    gemm_mfma<16, true><<<(M_SZ / 256) * 16, 512, 0, stream>>>(
        xb, WB, bk, bv, nullptr, Kb, Vb, M_SZ, D_SZ);

    // bind + in-chunk cumsum (one block per 8-token chunk)
    bind_cum_kernel<<<M_SZ / TLEN, 256, 0, stream>>>(Kb, Vb, Pb, totals);

    // 2-level exclusive scan of chunk totals
    dim3 g1((CCH + 255) / 256, NG, B_SZ);
    scan_s1<<<g1, 256, 0, stream>>>(totals, gt);
    dim3 g2((CCH + 255) / 256, B_SZ);
    scan_s2<<<g2, 256, 0, stream>>>(gt);

    // unbind: 4 pairs (one chunk) per block, packed real iFFT
    unbind4_ln_kernel<<<M_SZ / TLEN, 256, 0, stream>>>(
        Pb, totals, gt, Kb, ln_g, ln_b, RLNb);

    // output GEMM with fp32 residual (fp32 store)
    gemm_mfma<8, false><<<(M_SZ / 256) * 8, 512, 0, stream>>>(
        RLNb, Wob, bo, bo, x, out, out, M_SZ, D_SZ);
}

// Round 10
// 379.016 us; speedup vs baseline: 1.3360x; 1.0283x over previous
//
#include <hip/hip_runtime.h>
#include <math.h>

// Problem constants (from reference): B=4, L=4096, D=1024
#define B_SZ 4
#define L_SZ 4096
#define D_SZ 1024
#define M_SZ (B_SZ * L_SZ)      // 16384 tokens
#define NBINS 513               // rfft bins for D=1024
#define CCH   1026              // live channels per token (re,im interleaved)
#define PSTR  1028              // padded row stride (shorts for P, floats for totals)
#define TLEN 8                  // tokens per cumsum chunk (= per bind block)
#define NCH  (L_SZ / TLEN)      // 512 chunks per batch
#define NG   32                 // chunk groups (16 chunks each) for 2-level scan

typedef short bf16x8 __attribute__((ext_vector_type(8)));
typedef float f32x4  __attribute__((ext_vector_type(4)));
typedef unsigned short us8 __attribute__((ext_vector_type(8)));

#define AS1 __attribute__((address_space(1)))
#define AS3 __attribute__((address_space(3)))

// round-to-nearest-even f32 -> bf16
__device__ inline unsigned short f2bf(float f) {
    unsigned int u = __float_as_uint(f);
    u += 0x7fffu + ((u >> 16) & 1u);
    return (unsigned short)(u >> 16);
}
__device__ inline float bf2f(unsigned short u) {
    return __uint_as_float(((unsigned int)u) << 16);
}

// ---------------------------------------------------------------------------
// f32 -> bf16 cast, 8 elements/thread
// ---------------------------------------------------------------------------
__global__ __launch_bounds__(256) void cast_f32_bf16(
        const float* __restrict__ in, unsigned short* __restrict__ out, int n8) {
    int i = blockIdx.x * 256 + threadIdx.x;
    if (i >= n8) return;
    const float4* p = (const float4*)in + 2 * (size_t)i;
    float4 a = p[0], b = p[1];
    us8 o;
    o[0] = f2bf(a.x); o[1] = f2bf(a.y); o[2] = f2bf(a.z); o[3] = f2bf(a.w);
    o[4] = f2bf(b.x); o[5] = f2bf(b.y); o[6] = f2bf(b.z); o[7] = f2bf(b.w);
    *(us8*)(out + (size_t)i * 8) = o;
}

// merged weight casts: blockIdx.y selects {Wk->WB, Wv->WB+1M, Wo->Wob}
__global__ __launch_bounds__(256) void cast_w3(
        const float* __restrict__ Wk, const float* __restrict__ Wv,
        const float* __restrict__ Wo,
        unsigned short* __restrict__ WB, unsigned short* __restrict__ Wob, int n8) {
    int i = blockIdx.x * 256 + threadIdx.x;
    if (i >= n8) return;
    const int which = blockIdx.y;
    const float* src = (which == 0) ? Wk : (which == 1) ? Wv : Wo;
    unsigned short* dst = (which == 0) ? WB : (which == 1) ? (WB + D_SZ * D_SZ) : Wob;
    const float4* p = (const float4*)src + 2 * (size_t)i;
    float4 a = p[0], b = p[1];
    us8 o;
    o[0] = f2bf(a.x); o[1] = f2bf(a.y); o[2] = f2bf(a.z); o[3] = f2bf(a.w);
    o[4] = f2bf(b.x); o[5] = f2bf(b.y); o[6] = f2bf(b.z); o[7] = f2bf(b.w);
    *(us8*)(dst + (size_t)i * 8) = o;
}

// ---------------------------------------------------------------------------
// bf16 MFMA GEMM, 256x128 tile, BK=32, 3 LDS slots (72 KiB -> 2 blocks/CU),
// 512 threads = 8 waves (2M x 4N), per-wave 128x32 output. (R4, known-good.)
// OBF16: store C as bf16 (no residual path); else fp32 store (+optional resid).
// ---------------------------------------------------------------------------
template<int CNT, bool OBF16>   // N = CNT*128
__global__ __launch_bounds__(512, 4) void gemm_mfma(
        const unsigned short* __restrict__ A, const unsigned short* __restrict__ W,
        const float* __restrict__ bias0, const float* __restrict__ bias1,
        const float* __restrict__ resid,
        void* __restrict__ C0v, void* __restrict__ C1v, int M, int K) {
    __shared__ unsigned short Abuf[3][256 * 32];   // 3 x 16 KiB
    __shared__ unsigned short Bbuf[3][128 * 32];   // 3 x  8 KiB
    const int id   = blockIdx.x;
    const int bx   = (id >> 3) % CNT;
    const int by   = (id & 7) + 8 * (id / (8 * CNT));
    const int tid  = threadIdx.x;
    const int lane = tid & 63;
    const int wid  = tid >> 6;        // 0..7
    const int wr   = wid >> 2;        // 0..1 (M, 128 rows)
    const int wc   = wid & 3;         // 0..3 (N, 32 cols)
    const int bm   = by * 256;
    const int bn   = bx * 128;

    const int sl = tid >> 3;              // line 0..63 (2 rows each)
    const int sq = (tid & 7) ^ (sl & 7);  // logical slot at this dest position
    const int srow = 2 * sl + (sq >> 2);  // row within chunk
    const int skof = (sq & 3) * 8;        // k offset (shorts)
    const unsigned short* Abase = A + (size_t)(bm + srow) * K + skof;
    const unsigned short* Wbase = W + (size_t)(bn + srow) * K + skof;
    const int dstoff = tid * 16;          // linear dest bytes within chunk

    auto stage3 = [&](int slot, int kk) {
        __builtin_amdgcn_global_load_lds((const AS1 unsigned int*)(Abase + kk),
            (AS3 unsigned int*)((char*)&Abuf[slot][0] + dstoff), 16, 0, 0);
        __builtin_amdgcn_global_load_lds((const AS1 unsigned int*)(Abase + (size_t)128 * K + kk),
            (AS3 unsigned int*)((char*)&Abuf[slot][128 * 32] + dstoff), 16, 0, 0);
        __builtin_amdgcn_global_load_lds((const AS1 unsigned int*)(Wbase + kk),
            (AS3 unsigned int*)((char*)&Bbuf[slot][0] + dstoff), 16, 0, 0);
    };

    const int fr = lane & 15;
    const int kq = lane >> 4;
    const int rslot = (((((fr & 1) << 2) + kq) ^ ((fr >> 1) & 7)) << 4); // bytes
    const int aoff0 = wr * 8192 + (fr >> 1) * 128 + rslot;
    const int boff0 = wc * 2048 + (fr >> 1) * 128 + rslot;

    f32x4 acc[8][2] = {};

    const int nt = K >> 5;    // 32 K-tiles
    stage3(0, 0);
    stage3(1, 32);
    asm volatile("s_waitcnt vmcnt(3)" ::: "memory");
    __builtin_amdgcn_s_barrier();
    asm volatile("" ::: "memory");

    int slot = 0, slot2 = 2;
    for (int cur = 0; cur < nt; ++cur) {
        bf16x8 a[8], b[2];
        const char* Ab = (const char*)&Abuf[slot][0];
        const char* Bb = (const char*)&Bbuf[slot][0];
        #pragma unroll
        for (int nf = 0; nf < 2; nf++)
            b[nf] = *(const bf16x8*)(Bb + boff0 + nf * 1024);
        #pragma unroll
        for (int mf = 0; mf < 8; mf++)
            a[mf] = *(const bf16x8*)(Ab + aoff0 + mf * 1024);
        if (cur + 2 < nt) stage3(slot2, (cur + 2) << 5);
        __builtin_amdgcn_s_setprio(1);
        #pragma unroll
        for (int mf = 0; mf < 8; mf++)
            #pragma unroll
            for (int nf = 0; nf < 2; nf++)
                acc[mf][nf] = __builtin_amdgcn_mfma_f32_16x16x32_bf16(
                                  a[mf], b[nf], acc[mf][nf], 0, 0, 0);
        __builtin_amdgcn_s_setprio(0);
        if (cur + 2 < nt) { asm volatile("s_waitcnt vmcnt(3)" ::: "memory"); }
        else              { asm volatile("s_waitcnt vmcnt(0)" ::: "memory"); }
        __builtin_amdgcn_s_barrier();
        asm volatile("" ::: "memory");
        slot  = (slot  == 2) ? 0 : slot  + 1;
        slot2 = (slot2 == 2) ? 0 : slot2 + 1;
    }

    const int col0 = lane & 15;
    const int quad = lane >> 4;
    #pragma unroll
    for (int nf = 0; nf < 2; nf++) {
        const int ng = bn + wc * 32 + nf * 16 + col0;   // global col in [0, CNT*128)
        const int half = ng >> 10;                      // wave-uniform per nf
        const int n = ng & 1023;
        const float bv = half ? bias1[n] : bias0[n];
        void* Cv = half ? C1v : C0v;
        #pragma unroll
        for (int mf = 0; mf < 8; mf++) {
            #pragma unroll
            for (int r = 0; r < 4; r++) {
                const int m = bm + wr * 128 + mf * 16 + quad * 4 + r;
                float v = acc[mf][nf][r] + bv;
                size_t off = (size_t)m * 1024 + n;
                if constexpr (OBF16) {
                    ((unsigned short*)Cv)[off] = f2bf(v);
                } else {
                    if (resid) v += resid[off];
                    ((float*)Cv)[off] = v;
                }
            }
        }
    }
}

// ---------------------------------------------------------------------------
// Stockham radix-4 1024-pt FFT, twiddles precomputed per thread (w1 per
// stage, 8 VGPRs, reused across many FFTs in a block). 256 threads, 4
// complex/thread, exchanges via two swizzled float2 LDS buffers.
// ---------------------------------------------------------------------------
#define SWZ(a) ((a) ^ (((a) >> 4) & 15))

struct cplx { float r, i; };
__device__ inline cplx cmul(cplx a, cplx b) {
    return {a.r * b.r - a.i * b.i, a.r * b.i + a.i * b.r};
}

__device__ inline void r4bfly(cplx v[4], float s) {
    cplx t0 {v[0].r + v[2].r, v[0].i + v[2].i};
    cplx t1 {v[0].r - v[2].r, v[0].i - v[2].i};
    cplx t2 {v[1].r + v[3].r, v[1].i + v[3].i};
    cplx t3 {v[1].r - v[3].r, v[1].i - v[3].i};
    cplx j3 {-s * t3.i, s * t3.r};     // s*i * t3
    v[0] = {t0.r + t2.r, t0.i + t2.i};
    v[2] = {t0.r - t2.r, t0.i - t2.i};
    v[1] = {t1.r + j3.r, t1.i + j3.i};
    v[3] = {t1.r - j3.r, t1.i - j3.i};
}

template<int SIGN>
__device__ inline void make_w1(cplx w1s[4], int tid) {
    const float s = (float)SIGN;
    #pragma unroll
    for (int q = 1; q <= 3; q++) {
        const int Ls = 1 << (2 * q);
        const float ang = s * 1.57079632679489662f * (float)(tid & (Ls - 1)) / (float)Ls;
        float sn, cs; __sincosf(ang, &sn, &cs);
        w1s[q - 1] = {cs, sn};
    }
    float sn, cs;
    __sincosf(s * 1.57079632679489662f * (float)tid / 256.0f, &sn, &cs);
    w1s[3] = {cs, sn};
}

template<int SIGN>
__device__ inline void fft1024_tw(float2* bA, float2* bB, cplx v[4], int tid,
                                  const cplx w1s[4]) {
    const float s = (float)SIGN;
    r4bfly(v, s);
    {
        const int base = tid << 2;
        #pragma unroll
        for (int e = 0; e < 4; e++)
            bA[SWZ(base + e)] = make_float2(v[e].r, v[e].i);
    }
    __syncthreads();
    float2* cur = bA;
    float2* nxt = bB;
    #pragma unroll
    for (int q = 1; q <= 3; q++) {
        const int Ls = 1 << (2 * q);
        #pragma unroll
        for (int k = 0; k < 4; k++) {
            float2 t = cur[SWZ(tid + (k << 8))];
            v[k] = {t.x, t.y};
        }
        const int d = tid & (Ls - 1);
        cplx w1 = w1s[q - 1];
        cplx w2 = cmul(w1, w1);
        cplx w3 = cmul(w2, w1);
        v[1] = cmul(v[1], w1);
        v[2] = cmul(v[2], w2);
        v[3] = cmul(v[3], w3);
        r4bfly(v, s);
        const int base = ((tid >> (2 * q)) << (2 * q + 2)) + d;
        #pragma unroll
        for (int e = 0; e < 4; e++)
            nxt[SWZ(base + (e << (2 * q)))] = make_float2(v[e].r, v[e].i);
        float2* tmp = cur; cur = nxt; nxt = tmp;
        __syncthreads();
    }
    #pragma unroll
    for (int k = 0; k < 4; k++) {
        float2 t = cur[SWZ(tid + (k << 8))];
        v[k] = {t.x, t.y};
    }
    {
        cplx w1 = w1s[3];
        cplx w2 = cmul(w1, w1);
        cplx w3 = cmul(w2, w1);
        v[1] = cmul(v[1], w1);
        v[2] = cmul(v[2], w2);
        v[3] = cmul(v[3], w3);
        r4bfly(v, s);
    }
}

// ---------------------------------------------------------------------------
// Bind + fused in-chunk cumsum. One block = one 8-token chunk (2048 blocks).
// K/V rows loaded COALESCED (ushort4, 8B/lane) and staged packed (K|V<<16)
// in a 4KB LDS buffer; FFT-ordered access = 4 conflict-free ds_read_b32.
// Each thread owns bins b0=2*tid, b1=2*tid+1 (tid 0 also bin 512): all P /
// Kf / totals stores are ushort4/float4. Running cumsum stays fp32 in regs.
// Kf packed bf16 over the dead K row: [0]=Kf0.re, [1]=Kf512.re,
// [2b],[2b+1]=Kf[b] b=1..511. P rows padded to PSTR=1028 for 8B alignment.
// ---------------------------------------------------------------------------
__global__ __launch_bounds__(256) void bind_cum_kernel(
        unsigned short* __restrict__ KIO, const unsigned short* __restrict__ Vb,
        unsigned short* __restrict__ P, float* __restrict__ totals) {
    __shared__ float2 bA[1024], bB[1024];
    __shared__ unsigned int kvs[1024];   // packed K | V<<16 per element
    __shared__ float red[4];
    const int blk = blockIdx.x;           // = b*NCH + chunk
    const int tid = threadIdx.x;
    const int wv  = tid >> 6;
    const int ln  = tid & 63;
    const size_t tok0 = (size_t)blk * TLEN;

    cplx w1s[4];
    make_w1<-1>(w1s, tid);

    float r0r = 0.f, r0i = 0.f, r1r = 0.f, r1i = 0.f, r2r = 0.f, r2i = 0.f;

    // preload token 0 coalesced and stage into kvs
    ushort4 k4 = *(const ushort4*)(KIO + tok0 * D_SZ + 4 * tid);
    ushort4 v4 = *(const ushort4*)(Vb  + tok0 * D_SZ + 4 * tid);
    {
        uint4 pk;
        pk.x = (unsigned int)k4.x | ((unsigned int)v4.x << 16);
        pk.y = (unsigned int)k4.y | ((unsigned int)v4.y << 16);
        pk.z = (unsigned int)k4.z | ((unsigned int)v4.z << 16);
        pk.w = (unsigned int)k4.w | ((unsigned int)v4.w << 16);
        *(uint4*)&kvs[4 * tid] = pk;
    }
    __syncthreads();

    for (int tk = 0; tk < TLEN; ++tk) {
        const size_t token = tok0 + tk;
        unsigned short* krow = KIO + token * D_SZ;

        // FFT-ordered K/V from LDS staging (conflict-free: bank = tid%32)
        float kvC[4], vvC[4];
        float ss = 0.f;
        #pragma unroll
        for (int k = 0; k < 4; k++) {
            unsigned int pk = kvs[tid + (k << 8)];
            kvC[k] = bf2f((unsigned short)(pk & 0xffffu));
            vvC[k] = bf2f((unsigned short)(pk >> 16));
            ss += kvC[k] * kvC[k];
        }
        #pragma unroll
        for (int m = 1; m < 64; m <<= 1) ss += __shfl_xor(ss, m, 64);
        if (ln == 0) red[wv] = ss;
        __syncthreads();     // B1: red ready; also orders kvs reads < writes
        const float scale = 1.0f /
            fmaxf(sqrtf(red[0] + red[1] + red[2] + red[3]), 1e-12f);

        cplx z[4];
        #pragma unroll
        for (int k = 0; k < 4; k++) z[k] = {kvC[k] * scale, vvC[k]};

        // prefetch next token coalesced (latency hidden under the FFT)
        if (tk + 1 < TLEN) {
            k4 = *(const ushort4*)(KIO + (token + 1) * D_SZ + 4 * tid);
            v4 = *(const ushort4*)(Vb  + (token + 1) * D_SZ + 4 * tid);
        }

        fft1024_tw<-1>(bA, bB, z, tid, w1s);

        #pragma unroll
        for (int e = 0; e < 4; e++)
            bA[SWZ(tid + (e << 8))] = make_float2(z[e].r, z[e].i);
        // stage next token's kvs (after B1, before B2 -> race-free)
        if (tk + 1 < TLEN) {
            uint4 pk;
            pk.x = (unsigned int)k4.x | ((unsigned int)v4.x << 16);
            pk.y = (unsigned int)k4.y | ((unsigned int)v4.y << 16);
            pk.z = (unsigned int)k4.z | ((unsigned int)v4.z << 16);
            pk.w = (unsigned int)k4.w | ((unsigned int)v4.w << 16);
            *(uint4*)&kvs[4 * tid] = pk;
        }
        __syncthreads();     // B2: spectrum + kvs ready

        // bin 512 (tid 0) first: its Kf value rides in thread 0's ushort4
        float ar512 = 0.f;
        if (tid == 0) {
            float2 Zc = bA[SWZ(512)];
            r2r += Zc.x * Zc.y;              // ai=bi=0 at Nyquist
            ar512 = Zc.x;
            ushort2 pv; pv.x = f2bf(r2r); pv.y = f2bf(r2i);
            *(ushort2*)(P + token * PSTR + 1024) = pv;
        }

        // paired bins b0=2*tid, b1=2*tid+1
        const int b0 = 2 * tid, b1 = 2 * tid + 1;
        float ar0, ai0, ar1, ai1;
        {
            float2 Zb = bA[SWZ(b0)];
            float2 Zm = bA[SWZ((1024 - b0) & 1023)];
            ar0 = 0.5f * (Zb.x + Zm.x);
            ai0 = 0.5f * (Zb.y - Zm.y);
            float br = 0.5f * (Zb.y + Zm.y);
            float bi = 0.5f * (Zm.x - Zb.x);
            r0r += ar0 * br - ai0 * bi;
            r0i += ar0 * bi + ai0 * br;
        }
        {
            float2 Zb = bA[SWZ(b1)];
            float2 Zm = bA[SWZ(1024 - b1)];
            ar1 = 0.5f * (Zb.x + Zm.x);
            ai1 = 0.5f * (Zb.y - Zm.y);
            float br = 0.5f * (Zb.y + Zm.y);
            float bi = 0.5f * (Zm.x - Zb.x);
            r1r += ar1 * br - ai1 * bi;
            r1i += ar1 * bi + ai1 * br;
        }
        ushort4 pw;
        pw.x = f2bf(r0r); pw.y = f2bf(r0i);
        pw.z = f2bf(r1r); pw.w = f2bf(r1i);
        *(ushort4*)(P + token * PSTR + 4 * tid) = pw;
        ushort4 kfw;
        kfw.x = f2bf(ar0);
        kfw.y = (tid == 0) ? f2bf(ar512) : f2bf(ai0);   // slot1 = Kf512.re for tid0
        kfw.z = f2bf(ar1); kfw.w = f2bf(ai1);
        *(ushort4*)(krow + 4 * tid) = kfw;
        // no trailing barrier: next iteration's B1 orders bA reuse
    }

    float* trow = totals + (size_t)blk * PSTR;
    float4 tw; tw.x = r0r; tw.y = r0i; tw.z = r1r; tw.w = r1i;
    *(float4*)(trow + 4 * tid) = tw;
    if (tid == 0) { trow[1024] = r2r; trow[1025] = r2i; }
}

// ---------------------------------------------------------------------------
// 2-level scan of chunk totals -> exclusive offsets (fp32, stride PSTR).
// ---------------------------------------------------------------------------
__global__ __launch_bounds__(256) void scan_s1(
        float* __restrict__ totals, float* __restrict__ gt) {
    const int c = blockIdx.x * 256 + threadIdx.x;
    if (c >= CCH) return;
    const int g = blockIdx.y;
    const int b = blockIdx.z;
    float run = 0.f;
    #pragma unroll
    for (int i = 0; i < 16; i++) {
        size_t idx = ((size_t)(b * NCH + g * 16 + i)) * PSTR + c;
        float v = totals[idx];
        totals[idx] = run;
        run += v;
    }
    gt[((size_t)(b * NG + g)) * PSTR + c] = run;
}

__global__ __launch_bounds__(256) void scan_s2(float* __restrict__ gt) {
    const int c = blockIdx.x * 256 + threadIdx.x;
    if (c >= CCH) return;
    const int b = blockIdx.y;
    float run = 0.f;
    #pragma unroll
    for (int g = 0; g < NG; g++) {
        size_t idx = ((size_t)(b * NG + g)) * PSTR + c;
        float v = gt[idx];
        gt[idx] = run;
        run += v;
    }
}

// ---------------------------------------------------------------------------
// Unbind: 4 pairs (8 tokens = one chunk) per block. Offsets (totals+gt)
// combined into LDS once per block (float4 loads). Per pair each thread
// fills bins b0=2*tid, b1=2*tid+1 via ushort4 S/Kf loads (8B coalesced);
// tid0 also bin 512. Packed real iFFT -> ra,rb; /sqrt(t+1); LayerNorm.
// ---------------------------------------------------------------------------
__global__ __launch_bounds__(256) void unbind4_ln_kernel(
        const unsigned short* __restrict__ P, const float* __restrict__ totals,
        const float* __restrict__ gt, const unsigned short* __restrict__ KF,
        const float* __restrict__ ln_g, const float* __restrict__ ln_b,
        unsigned short* __restrict__ RLNb) {
    __shared__ float2 bA[1024], bB[1024];
    __shared__ __align__(16) float2 offsh[514];
    __shared__ float red[16];
    const int blk = blockIdx.x;
    const int tid = threadIdx.x;
    const int wv  = tid >> 6;
    const int ln  = tid & 63;
    const size_t tok0 = (size_t)blk * TLEN;     // 8 tokens, one chunk
    const int bidx  = (int)(tok0 >> 12);
    const int t0    = (int)(tok0 & (L_SZ - 1));
    const int chunk = t0 >> 3;                  // TLEN=8

    // combined chunk offset row -> LDS (once per block, float4 loads)
    {
        const float* off2 = totals + (size_t)(bidx * NCH + chunk) * PSTR;
        const float* gof2 = gt + (size_t)(bidx * NG + (chunk >> 4)) * PSTR;
        float4 o = *(const float4*)(off2 + 4 * tid);
        float4 g = *(const float4*)(gof2 + 4 * tid);
        float4 og; og.x = o.x + g.x; og.y = o.y + g.y;
        og.z = o.z + g.z; og.w = o.w + g.w;
        *(float4*)&offsh[2 * tid] = og;
        if (tid == 0)
            offsh[512] = make_float2(off2[1024] + gof2[1024],
                                     off2[1025] + gof2[1025]);
    }

    cplx w1s[4];
    make_w1<1>(w1s, tid);

    float gv[4], bev[4];
    #pragma unroll
    for (int e = 0; e < 4; e++) {
        gv[e]  = ln_g[tid + (e << 8)];
        bev[e] = ln_b[tid + (e << 8)];
    }
    __syncthreads();   // offsh ready

    const int b0 = 2 * tid, b1 = 2 * tid + 1;

    for (int p = 0; p < 4; ++p) {
        const size_t ta = tok0 + 2 * p, tb = ta + 1;
        const unsigned short* Pa = P + ta * PSTR;
        const unsigned short* Pc = P + tb * PSTR;
        const unsigned short* Ka = KF + ta * D_SZ;
        const unsigned short* Kc = KF + tb * D_SZ;

        // vector loads: S and Kf quads covering bins b0,b1 for both tokens
        ushort4 sa = *(const ushort4*)(Pa + 4 * tid);
        ushort4 sb = *(const ushort4*)(Pc + 4 * tid);
        ushort4 ka = *(const ushort4*)(Ka + 4 * tid);
        ushort4 kb = *(const ushort4*)(Kc + 4 * tid);
        float2 og0 = offsh[b0], og1 = offsh[b1];

        // --- bin b0 (tid0: b0=0 -> ki=0, slot1 is Kf512.re, don't use)
        {
            float ka_r = bf2f(ka.x), ka_i = (tid == 0) ? 0.f : bf2f(ka.y);
            float kb_r = bf2f(kb.x), kb_i = (tid == 0) ? 0.f : bf2f(kb.y);
            float sra = bf2f(sa.x) + og0.x, sia = bf2f(sa.y) + og0.y;
            float srb = bf2f(sb.x) + og0.x, sib = bf2f(sb.y) + og0.y;
            float Zar = sra * ka_r + sia * ka_i, Zai = sia * ka_r - sra * ka_i;
            float Zbr = srb * kb_r + sib * kb_i, Zbi = sib * kb_r - srb * kb_i;
            bA[SWZ(b0)] = make_float2(Zar - Zbi, Zai + Zbr);
            if (b0 != 0)
                bA[SWZ(1024 - b0)] = make_float2(Zar + Zbi, Zbr - Zai);
        }
        // --- bin b1 (always 1..511)
        {
            float ka_r = bf2f(ka.z), ka_i = bf2f(ka.w);
            float kb_r = bf2f(kb.z), kb_i = bf2f(kb.w);
            float sra = bf2f(sa.z) + og1.x, sia = bf2f(sa.w) + og1.y;
            float srb = bf2f(sb.z) + og1.x, sib = bf2f(sb.w) + og1.y;
            float Zar = sra * ka_r + sia * ka_i, Zai = sia * ka_r - sra * ka_i;
            float Zbr = srb * kb_r + sib * kb_i, Zbi = sib * kb_r - srb * kb_i;
            bA[SWZ(b1)] = make_float2(Zar - Zbi, Zai + Zbr);
            bA[SWZ(1024 - b1)] = make_float2(Zar + Zbi, Zbr - Zai);
        }
        // --- bin 512 (tid 0)
        if (tid == 0) {
            ushort2 s5a = *(const ushort2*)(Pa + 1024);
            ushort2 s5b = *(const ushort2*)(Pc + 1024);
            float2 og = offsh[512];
            float kra = bf2f(Ka[1]), krb = bf2f(Kc[1]);
            float sra = bf2f(s5a.x) + og.x, sia = bf2f(s5a.y) + og.y;
            float srb = bf2f(s5b.x) + og.x, sib = bf2f(s5b.y) + og.y;
            float Zar = sra * kra, Zai = sia * kra;
            float Zbr = srb * krb, Zbi = sib * krb;
            bA[SWZ(512)] = make_float2(Zar - Zbi, Zai + Zbr);
        }
        __syncthreads();

        cplx z[4];
        #pragma unroll
        for (int k = 0; k < 4; k++) {
            float2 c = bA[SWZ(tid + (k << 8))];
            z[k] = {c.x, c.y};
        }
        __syncthreads();
        fft1024_tw<1>(bA, bB, z, tid, w1s);   // z = 1024 * (ra + i*rb)

        const int t_a = t0 + 2 * p;
        const float sc_a = (1.0f / 1024.0f) * rsqrtf((float)(t_a + 1));
        const float sc_b = (1.0f / 1024.0f) * rsqrtf((float)(t_a + 2));
        float ra[4], rb[4];
        float s1a = 0.f, s2a = 0.f, s1b = 0.f, s2b = 0.f;
        #pragma unroll
        for (int e = 0; e < 4; e++) {
            ra[e] = z[e].r * sc_a;
            rb[e] = z[e].i * sc_b;
            s1a += ra[e]; s2a += ra[e] * ra[e];
            s1b += rb[e]; s2b += rb[e] * rb[e];
        }
        #pragma unroll
        for (int m = 1; m < 64; m <<= 1) {
            s1a += __shfl_xor(s1a, m, 64);
            s2a += __shfl_xor(s2a, m, 64);
            s1b += __shfl_xor(s1b, m, 64);
            s2b += __shfl_xor(s2b, m, 64);
        }
        if (ln == 0) {
            red[wv] = s1a; red[4 + wv] = s2a; red[8 + wv] = s1b; red[12 + wv] = s2b;
        }
        __syncthreads();
        const float S1a = red[0] + red[1] + red[2] + red[3];
        const float S2a = red[4] + red[5] + red[6] + red[7];
        const float S1b = red[8] + red[9] + red[10] + red[11];
        const float S2b = red[12] + red[13] + red[14] + red[15];
        const float mua = S1a * (1.0f / 1024.0f);
        const float vara = S2a * (1.0f / 1024.0f) - mua * mua;
        const float rsa = rsqrtf(vara + 1e-5f);
        const float mub = S1b * (1.0f / 1024.0f);
        const float varb = S2b * (1.0f / 1024.0f) - mub * mub;
        const float rsb = rsqrtf(varb + 1e-5f);

        unsigned short* outA = RLNb + ta * D_SZ;
        unsigned short* outB = RLNb + tb * D_SZ;
        #pragma unroll
        for (int e = 0; e < 4; e++) {
            const int d = tid + (e << 8);
            outA[d] = f2bf((ra[e] - mua) * rsa * gv[e] + bev[e]);
            outB[d] = f2bf((rb[e] - mub) * rsb * gv[e] + bev[e]);
        }
        __syncthreads();   // red/bA safe for next pair
    }
}

// ---------------------------------------------------------------------------
// Workspace (bytes)  [total ~136 MiB — far below the proven 234 MiB]:
//   Kb     bf16 M*D        = 32.0 MB  (keys; bind overwrites with packed Kf)
//   Vb     bf16 M*D        = 32.0 MB  (dead after bind; reused as bf16 RLN)
//   Pb     bf16 M*PSTR     = 33.7 MB  (bind writes inclusive-in-chunk cumsum)
//   xb     bf16 M*D        = 32.0 MB  (dead after gemm16; totals fp32 8.4 MB
//                                      + gt fp32 0.5 MB OVERLAY it)
//   WB     bf16 2048*D     =  4.0 MB  (Wk ++ Wv)
//   Wob    bf16 D*D        =  2.0 MB
// ---------------------------------------------------------------------------
extern "C" void kernel_launch(void* const* d_in, const int* in_sizes, int n_in,
                              void* d_out, int out_size, void* d_ws, size_t ws_size,
                              hipStream_t stream) {
    (void)in_sizes; (void)n_in; (void)out_size; (void)ws_size;
    const float* x    = (const float*)d_in[0];
    const float* Wk   = (const float*)d_in[1];
    const float* bk   = (const float*)d_in[2];
    const float* Wv   = (const float*)d_in[3];
    const float* bv   = (const float*)d_in[4];
    const float* ln_g = (const float*)d_in[5];
    const float* ln_b = (const float*)d_in[6];
    const float* Wo   = (const float*)d_in[7];
    const float* bo   = (const float*)d_in[8];
    float* out = (float*)d_out;

    char* w = (char*)d_ws;
    unsigned short* Kb  = (unsigned short*)w;  w += (size_t)M_SZ * D_SZ * 2;
    unsigned short* Vb  = (unsigned short*)w;  w += (size_t)M_SZ * D_SZ * 2;
    unsigned short* Pb  = (unsigned short*)w;  w += (size_t)M_SZ * PSTR * 2;
    unsigned short* xb  = (unsigned short*)w;  w += (size_t)M_SZ * D_SZ * 2;
    unsigned short* WB  = (unsigned short*)w;  w += (size_t)2 * D_SZ * D_SZ * 2;
    unsigned short* Wob = (unsigned short*)w;  w += (size_t)D_SZ * D_SZ * 2;
    unsigned short* RLNb = Vb;  // overlays dead Vb
    // totals + gt overlay the dead xb region (xb only read by gemm16)
    float* totals = (float*)xb;                                    // 8.4 MB
    float* gt     = (float*)xb + (size_t)B_SZ * NCH * PSTR;        // 0.5 MB

    const int n8x = M_SZ * D_SZ / 8;
    const int n8w = D_SZ * D_SZ / 8;
    cast_f32_bf16<<<n8x / 256, 256, 0, stream>>>(x, xb, n8x);
    dim3 wgrid(n8w / 256, 3);
    cast_w3<<<wgrid, 256, 0, stream>>>(Wk, Wv, Wo, WB, Wob, n8w);

    // fused K/V projection: N=2048, bf16 outputs (first half -> Kb, second -> Vb)
    gemm_mfma<16, true><<<(M_SZ / 256) * 16, 512, 0, stream>>>(
        xb, WB, bk, bv, nullptr, Kb, Vb, M_SZ, D_SZ);

    // bind + in-chunk cumsum (one block per 8-token chunk)
    bind_cum_kernel<<<M_SZ / TLEN, 256, 0, stream>>>(Kb, Vb, Pb, totals);

    // 2-level exclusive scan of chunk totals
    dim3 g1((CCH + 255) / 256, NG, B_SZ);
    scan_s1<<<g1, 256, 0, stream>>>(totals, gt);
    dim3 g2((CCH + 255) / 256, B_SZ);
    scan_s2<<<g2, 256, 0, stream>>>(gt);

    // unbind: 4 pairs (one chunk) per block, packed real iFFT
    unbind4_ln_kernel<<<M_SZ / TLEN, 256, 0, stream>>>(
        Pb, totals, gt, Kb, ln_g, ln_b, RLNb);

    // output GEMM with fp32 residual (fp32 store)
    gemm_mfma<8, false><<<(M_SZ / 256) * 8, 512, 0, stream>>>(
        RLNb, Wob, bo, bo, x, out, out, M_SZ, D_SZ);
}

// Round 11
// 361.965 us; speedup vs baseline: 1.3990x; 1.0471x over previous
//
#include <hip/hip_runtime.h>
#include <math.h>

// Problem constants (from reference): B=4, L=4096, D=1024
#define B_SZ 4
#define L_SZ 4096
#define D_SZ 1024
#define M_SZ (B_SZ * L_SZ)      // 16384 tokens
#define NBINS 513               // rfft bins for D=1024
#define CCH   1026              // live channels per token (re,im interleaved)
#define PSTR  1028              // padded row stride (shorts for P, floats for totals)
#define TLEN 8                  // tokens per cumsum chunk (= per bind block)
#define NCH  (L_SZ / TLEN)      // 512 chunks per batch
#define NG   32                 // chunk groups (16 chunks each) for 2-level scan

typedef short bf16x8 __attribute__((ext_vector_type(8)));
typedef float f32x4  __attribute__((ext_vector_type(4)));
typedef unsigned short us8 __attribute__((ext_vector_type(8)));

#define AS1 __attribute__((address_space(1)))
#define AS3 __attribute__((address_space(3)))

// round-to-nearest-even f32 -> bf16
__device__ inline unsigned short f2bf(float f) {
    unsigned int u = __float_as_uint(f);
    u += 0x7fffu + ((u >> 16) & 1u);
    return (unsigned short)(u >> 16);
}
__device__ inline float bf2f(unsigned short u) {
    return __uint_as_float(((unsigned int)u) << 16);
}

// ---------------------------------------------------------------------------
// Single cast kernel: x (8192 blocks) + Wk/Wv/Wo (512 blocks each) in one
// launch. 8 f32->bf16 elements per thread, float4 loads / us8 stores.
// ---------------------------------------------------------------------------
#define XBLK 8192
#define WBLK 512
__global__ __launch_bounds__(256) void cast_all(
        const float* __restrict__ x, const float* __restrict__ Wk,
        const float* __restrict__ Wv, const float* __restrict__ Wo,
        unsigned short* __restrict__ xb, unsigned short* __restrict__ WB,
        unsigned short* __restrict__ Wob) {
    const int b = blockIdx.x;
    const float* src;
    unsigned short* dst;
    size_t i;
    if (b < XBLK) {
        src = x;  dst = xb;  i = (size_t)b * 256 + threadIdx.x;
    } else if (b < XBLK + WBLK) {
        src = Wk; dst = WB;  i = (size_t)(b - XBLK) * 256 + threadIdx.x;
    } else if (b < XBLK + 2 * WBLK) {
        src = Wv; dst = WB + D_SZ * D_SZ;
        i = (size_t)(b - XBLK - WBLK) * 256 + threadIdx.x;
    } else {
        src = Wo; dst = Wob;
        i = (size_t)(b - XBLK - 2 * WBLK) * 256 + threadIdx.x;
    }
    const float4* p = (const float4*)src + 2 * i;
    float4 a = p[0], bb = p[1];
    us8 o;
    o[0] = f2bf(a.x);  o[1] = f2bf(a.y);  o[2] = f2bf(a.z);  o[3] = f2bf(a.w);
    o[4] = f2bf(bb.x); o[5] = f2bf(bb.y); o[6] = f2bf(bb.z); o[7] = f2bf(bb.w);
    *(us8*)(dst + i * 8) = o;
}

// ---------------------------------------------------------------------------
// bf16 MFMA GEMM, 256x128 tile, BK=32, 3 LDS slots (72 KiB -> 2 blocks/CU),
// 512 threads = 8 waves. Round 11: waves partitioned 4M x 2N (64x64 per
// wave): 8 ds_read_b128 + 16 MFMA per K-tile (was 10+16) -> LDS bytes/CU
// per tile-round 128KB (was 160KB), MFMA:LDS instr ratio 2:1.
// OBF16: store C as bf16 (no residual path); else fp32 store (+opt resid).
// ---------------------------------------------------------------------------
template<int CNT, bool OBF16>   // N = CNT*128
__global__ __launch_bounds__(512, 4) void gemm_mfma(
        const unsigned short* __restrict__ A, const unsigned short* __restrict__ W,
        const float* __restrict__ bias0, const float* __restrict__ bias1,
        const float* __restrict__ resid,
        void* __restrict__ C0v, void* __restrict__ C1v, int M, int K) {
    __shared__ unsigned short Abuf[3][256 * 32];   // 3 x 16 KiB
    __shared__ unsigned short Bbuf[3][128 * 32];   // 3 x  8 KiB
    const int id   = blockIdx.x;
    const int bx   = (id >> 3) % CNT;
    const int by   = (id & 7) + 8 * (id / (8 * CNT));
    const int tid  = threadIdx.x;
    const int lane = tid & 63;
    const int wid  = tid >> 6;        // 0..7
    const int wr   = wid >> 1;        // 0..3 (M, 64 rows each)
    const int wc   = wid & 1;         // 0..1 (N, 64 cols each)
    const int bm   = by * 256;
    const int bn   = bx * 128;

    const int sl = tid >> 3;              // line 0..63 (2 rows each)
    const int sq = (tid & 7) ^ (sl & 7);  // logical slot at this dest position
    const int srow = 2 * sl + (sq >> 2);  // row within chunk
    const int skof = (sq & 3) * 8;        // k offset (shorts)
    const unsigned short* Abase = A + (size_t)(bm + srow) * K + skof;
    const unsigned short* Wbase = W + (size_t)(bn + srow) * K + skof;
    const int dstoff = tid * 16;          // linear dest bytes within chunk

    auto stage3 = [&](int slot, int kk) {
        __builtin_amdgcn_global_load_lds((const AS1 unsigned int*)(Abase + kk),
            (AS3 unsigned int*)((char*)&Abuf[slot][0] + dstoff), 16, 0, 0);
        __builtin_amdgcn_global_load_lds((const AS1 unsigned int*)(Abase + (size_t)128 * K + kk),
            (AS3 unsigned int*)((char*)&Abuf[slot][128 * 32] + dstoff), 16, 0, 0);
        __builtin_amdgcn_global_load_lds((const AS1 unsigned int*)(Wbase + kk),
            (AS3 unsigned int*)((char*)&Bbuf[slot][0] + dstoff), 16, 0, 0);
    };

    const int fr = lane & 15;
    const int kq = lane >> 4;
    const int rslot = (((((fr & 1) << 2) + kq) ^ ((fr >> 1) & 7)) << 4); // bytes
    const int aoff0 = wr * 4096 + (fr >> 1) * 128 + rslot;   // + mf*1024
    const int boff0 = wc * 4096 + (fr >> 1) * 128 + rslot;   // + nf*1024

    f32x4 acc[4][4] = {};

    const int nt = K >> 5;    // 32 K-tiles
    stage3(0, 0);
    stage3(1, 32);
    asm volatile("s_waitcnt vmcnt(3)" ::: "memory");
    __builtin_amdgcn_s_barrier();
    asm volatile("" ::: "memory");

    int slot = 0, slot2 = 2;
    for (int cur = 0; cur < nt; ++cur) {
        bf16x8 a[4], b[4];
        const char* Ab = (const char*)&Abuf[slot][0];
        const char* Bb = (const char*)&Bbuf[slot][0];
        #pragma unroll
        for (int nf = 0; nf < 4; nf++)
            b[nf] = *(const bf16x8*)(Bb + boff0 + nf * 1024);
        #pragma unroll
        for (int mf = 0; mf < 4; mf++)
            a[mf] = *(const bf16x8*)(Ab + aoff0 + mf * 1024);
        if (cur + 2 < nt) stage3(slot2, (cur + 2) << 5);
        __builtin_amdgcn_s_setprio(1);
        #pragma unroll
        for (int mf = 0; mf < 4; mf++)
            #pragma unroll
            for (int nf = 0; nf < 4; nf++)
                acc[mf][nf] = __builtin_amdgcn_mfma_f32_16x16x32_bf16(
                                  a[mf], b[nf], acc[mf][nf], 0, 0, 0);
        __builtin_amdgcn_s_setprio(0);
        if (cur + 2 < nt) { asm volatile("s_waitcnt vmcnt(3)" ::: "memory"); }
        else              { asm volatile("s_waitcnt vmcnt(0)" ::: "memory"); }
        __builtin_amdgcn_s_barrier();
        asm volatile("" ::: "memory");
        slot  = (slot  == 2) ? 0 : slot  + 1;
        slot2 = (slot2 == 2) ? 0 : slot2 + 1;
    }

    const int col0 = lane & 15;
    const int quad = lane >> 4;
    #pragma unroll
    for (int nf = 0; nf < 4; nf++) {
        const int ng = bn + wc * 64 + nf * 16 + col0;   // global col in [0, CNT*128)
        const int half = ng >> 10;                      // wave-uniform per nf
        const int n = ng & 1023;
        const float bv = half ? bias1[n] : bias0[n];
        void* Cv = half ? C1v : C0v;
        #pragma unroll
        for (int mf = 0; mf < 4; mf++) {
            #pragma unroll
            for (int r = 0; r < 4; r++) {
                const int m = bm + wr * 64 + mf * 16 + quad * 4 + r;
                float v = acc[mf][nf][r] + bv;
                size_t off = (size_t)m * 1024 + n;
                if constexpr (OBF16) {
                    ((unsigned short*)Cv)[off] = f2bf(v);
                } else {
                    if (resid) v += resid[off];
                    ((float*)Cv)[off] = v;
                }
            }
        }
    }
}

// ---------------------------------------------------------------------------
// Stockham radix-4 1024-pt FFT, twiddles precomputed per thread (w1 per
// stage, reused across FFTs). 256 threads, 4 complex/thread, exchanges via
// two swizzled float2 LDS buffers. 4 internal barriers. Buffer trace:
// store bA, sync | q1: rd bA wr bB, sync | q2: rd bB wr bA, sync |
// q3: rd bA wr bB, sync | final: rd bB (per-thread slots tid+k*256).
// ---------------------------------------------------------------------------
#define SWZ(a) ((a) ^ (((a) >> 4) & 15))

struct cplx { float r, i; };
__device__ inline cplx cmul(cplx a, cplx b) {
    return {a.r * b.r - a.i * b.i, a.r * b.i + a.i * b.r};
}

__device__ inline void r4bfly(cplx v[4], float s) {
    cplx t0 {v[0].r + v[2].r, v[0].i + v[2].i};
    cplx t1 {v[0].r - v[2].r, v[0].i - v[2].i};
    cplx t2 {v[1].r + v[3].r, v[1].i + v[3].i};
    cplx t3 {v[1].r - v[3].r, v[1].i - v[3].i};
    cplx j3 {-s * t3.i, s * t3.r};     // s*i * t3
    v[0] = {t0.r + t2.r, t0.i + t2.i};
    v[2] = {t0.r - t2.r, t0.i - t2.i};
    v[1] = {t1.r + j3.r, t1.i + j3.i};
    v[3] = {t1.r - j3.r, t1.i - j3.i};
}

template<int SIGN>
__device__ inline void make_w1(cplx w1s[4], int tid) {
    const float s = (float)SIGN;
    #pragma unroll
    for (int q = 1; q <= 3; q++) {
        const int Ls = 1 << (2 * q);
        const float ang = s * 1.57079632679489662f * (float)(tid & (Ls - 1)) / (float)Ls;
        float sn, cs; __sincosf(ang, &sn, &cs);
        w1s[q - 1] = {cs, sn};
    }
    float sn, cs;
    __sincosf(s * 1.57079632679489662f * (float)tid / 256.0f, &sn, &cs);
    w1s[3] = {cs, sn};
}

template<int SIGN>
__device__ inline void fft1024_tw(float2* bA, float2* bB, cplx v[4], int tid,
                                  const cplx w1s[4]) {
    const float s = (float)SIGN;
    r4bfly(v, s);
    {
        const int base = tid << 2;
        #pragma unroll
        for (int e = 0; e < 4; e++)
            bA[SWZ(base + e)] = make_float2(v[e].r, v[e].i);
    }
    __syncthreads();
    float2* cur = bA;
    float2* nxt = bB;
    #pragma unroll
    for (int q = 1; q <= 3; q++) {
        const int Ls = 1 << (2 * q);
        #pragma unroll
        for (int k = 0; k < 4; k++) {
            float2 t = cur[SWZ(tid + (k << 8))];
            v[k] = {t.x, t.y};
        }
        const int d = tid & (Ls - 1);
        cplx w1 = w1s[q - 1];
        cplx w2 = cmul(w1, w1);
        cplx w3 = cmul(w2, w1);
        v[1] = cmul(v[1], w1);
        v[2] = cmul(v[2], w2);
        v[3] = cmul(v[3], w3);
        r4bfly(v, s);
        const int base = ((tid >> (2 * q)) << (2 * q + 2)) + d;
        #pragma unroll
        for (int e = 0; e < 4; e++)
            nxt[SWZ(base + (e << (2 * q)))] = make_float2(v[e].r, v[e].i);
        float2* tmp = cur; cur = nxt; nxt = tmp;
        __syncthreads();
    }
    #pragma unroll
    for (int k = 0; k < 4; k++) {
        float2 t = cur[SWZ(tid + (k << 8))];
        v[k] = {t.x, t.y};
    }
    {
        cplx w1 = w1s[3];
        cplx w2 = cmul(w1, w1);
        cplx w3 = cmul(w2, w1);
        v[1] = cmul(v[1], w1);
        v[2] = cmul(v[2], w2);
        v[3] = cmul(v[3], w3);
        r4bfly(v, s);
    }
}

// ---------------------------------------------------------------------------
// Bind + fused in-chunk cumsum. One block = one 8-token chunk (2048 blocks).
// Round 11 barrier thinning: FFT runs on the UNNORMALIZED z = k + i*v (FFT
// is linear; the key-norm scale is applied to the even/Kf part at unpack),
// so the pre-FFT norm barrier (B1) is gone. Spectrum is staged in bB (each
// thread overwrites exactly the slots it alone just read in the FFT final
// stage), so the next token's FFT (which first writes bA) cannot race the
// current unpack's bB reads: the FFT-initial sync orders them. Norm
// reduction buffer is parity-double-buffered (red[tk&1]). 5 barriers/token
// (was 7).
// ---------------------------------------------------------------------------
__global__ __launch_bounds__(256) void bind_cum_kernel(
        unsigned short* __restrict__ KIO, const unsigned short* __restrict__ Vb,
        unsigned short* __restrict__ P, float* __restrict__ totals) {
    __shared__ float2 bA[1024], bB[1024];
    __shared__ unsigned int kvs[1024];   // packed K | V<<16 per element
    __shared__ float red[2][4];
    const int blk = blockIdx.x;           // = b*NCH + chunk
    const int tid = threadIdx.x;
    const int wv  = tid >> 6;
    const int ln  = tid & 63;
    const size_t tok0 = (size_t)blk * TLEN;

    cplx w1s[4];
    make_w1<-1>(w1s, tid);

    float r0r = 0.f, r0i = 0.f, r1r = 0.f, r1i = 0.f, r2r = 0.f, r2i = 0.f;

    // preload token 0 coalesced and stage into kvs
    ushort4 k4 = *(const ushort4*)(KIO + tok0 * D_SZ + 4 * tid);
    ushort4 v4 = *(const ushort4*)(Vb  + tok0 * D_SZ + 4 * tid);
    {
        uint4 pk;
        pk.x = (unsigned int)k4.x | ((unsigned int)v4.x << 16);
        pk.y = (unsigned int)k4.y | ((unsigned int)v4.y << 16);
        pk.z = (unsigned int)k4.z | ((unsigned int)v4.z << 16);
        pk.w = (unsigned int)k4.w | ((unsigned int)v4.w << 16);
        *(uint4*)&kvs[4 * tid] = pk;
    }
    __syncthreads();

    for (int tk = 0; tk < TLEN; ++tk) {
        const size_t token = tok0 + tk;
        unsigned short* krow = KIO + token * D_SZ;

        // FFT-ordered K/V from LDS staging (conflict-free: bank = tid%32)
        float kvC[4], vvC[4];
        float ss = 0.f;
        #pragma unroll
        for (int k = 0; k < 4; k++) {
            unsigned int pk = kvs[tid + (k << 8)];
            kvC[k] = bf2f((unsigned short)(pk & 0xffffu));
            vvC[k] = bf2f((unsigned short)(pk >> 16));
            ss += kvC[k] * kvC[k];
        }
        #pragma unroll
        for (int m = 1; m < 64; m <<= 1) ss += __shfl_xor(ss, m, 64);
        if (ln == 0) red[tk & 1][wv] = ss;   // published by FFT-initial sync

        cplx z[4];
        #pragma unroll
        for (int k = 0; k < 4; k++) z[k] = {kvC[k], vvC[k]};   // UNNORMALIZED

        // prefetch next token coalesced (latency hidden under the FFT)
        if (tk + 1 < TLEN) {
            k4 = *(const ushort4*)(KIO + (token + 1) * D_SZ + 4 * tid);
            v4 = *(const ushort4*)(Vb  + (token + 1) * D_SZ + 4 * tid);
        }

        fft1024_tw<-1>(bA, bB, z, tid, w1s);

        // spectrum -> bB: per-thread slots identical to the FFT's final
        // reads, so no cross-thread hazard before B2.
        #pragma unroll
        for (int e = 0; e < 4; e++)
            bB[SWZ(tid + (e << 8))] = make_float2(z[e].r, z[e].i);
        // stage next token's kvs (after FFT-initial sync, before B2)
        if (tk + 1 < TLEN) {
            uint4 pk;
            pk.x = (unsigned int)k4.x | ((unsigned int)v4.x << 16);
            pk.y = (unsigned int)k4.y | ((unsigned int)v4.y << 16);
            pk.z = (unsigned int)k4.z | ((unsigned int)v4.z << 16);
            pk.w = (unsigned int)k4.w | ((unsigned int)v4.w << 16);
            *(uint4*)&kvs[4 * tid] = pk;
        }
        __syncthreads();     // B2: spectrum + kvs ready

        const float* rd = red[tk & 1];
        const float scale = 1.0f /
            fmaxf(sqrtf(rd[0] + rd[1] + rd[2] + rd[3]), 1e-12f);

        // bin 512 (tid 0): Kf part gets the scale
        float ar512 = 0.f;
        if (tid == 0) {
            float2 Zc = bB[SWZ(512)];
            float ark = scale * Zc.x;
            r2r += ark * Zc.y;               // ai=bi=0 at Nyquist
            ar512 = ark;
            ushort2 pv; pv.x = f2bf(r2r); pv.y = f2bf(r2i);
            *(ushort2*)(P + token * PSTR + 1024) = pv;
        }

        // paired bins b0=2*tid, b1=2*tid+1 (even part scaled by key norm)
        const int b0 = 2 * tid, b1 = 2 * tid + 1;
        float ar0, ai0, ar1, ai1;
        {
            float2 Zb = bB[SWZ(b0)];
            float2 Zm = bB[SWZ((1024 - b0) & 1023)];
            ar0 = scale * 0.5f * (Zb.x + Zm.x);
            ai0 = scale * 0.5f * (Zb.y - Zm.y);
            float br = 0.5f * (Zb.y + Zm.y);
            float bi = 0.5f * (Zm.x - Zb.x);
            r0r += ar0 * br - ai0 * bi;
            r0i += ar0 * bi + ai0 * br;
        }
        {
            float2 Zb = bB[SWZ(b1)];
            float2 Zm = bB[SWZ(1024 - b1)];
            ar1 = scale * 0.5f * (Zb.x + Zm.x);
            ai1 = scale * 0.5f * (Zb.y - Zm.y);
            float br = 0.5f * (Zb.y + Zm.y);
            float bi = 0.5f * (Zm.x - Zb.x);
            r1r += ar1 * br - ai1 * bi;
            r1i += ar1 * bi + ai1 * br;
        }
        ushort4 pw;
        pw.x = f2bf(r0r); pw.y = f2bf(r0i);
        pw.z = f2bf(r1r); pw.w = f2bf(r1i);
        *(ushort4*)(P + token * PSTR + 4 * tid) = pw;
        ushort4 kfw;
        kfw.x = f2bf(ar0);
        kfw.y = (tid == 0) ? f2bf(ar512) : f2bf(ai0);   // slot1 = Kf512.re for tid0
        kfw.z = f2bf(ar1); kfw.w = f2bf(ai1);
        *(ushort4*)(krow + 4 * tid) = kfw;
        // no trailing barrier: next FFT's initial sync orders bB reuse
        // (next token first writes bA; its q1 bB writes are behind that sync)
    }

    float* trow = totals + (size_t)blk * PSTR;
    float4 tw; tw.x = r0r; tw.y = r0i; tw.z = r1r; tw.w = r1i;
    *(float4*)(trow + 4 * tid) = tw;
    if (tid == 0) { trow[1024] = r2r; trow[1025] = r2i; }
}

// ---------------------------------------------------------------------------
// 2-level scan of chunk totals -> exclusive offsets (fp32, stride PSTR).
// ---------------------------------------------------------------------------
__global__ __launch_bounds__(256) void scan_s1(
        float* __restrict__ totals, float* __restrict__ gt) {
    const int c = blockIdx.x * 256 + threadIdx.x;
    if (c >= CCH) return;
    const int g = blockIdx.y;
    const int b = blockIdx.z;
    float run = 0.f;
    #pragma unroll
    for (int i = 0; i < 16; i++) {
        size_t idx = ((size_t)(b * NCH + g * 16 + i)) * PSTR + c;
        float v = totals[idx];
        totals[idx] = run;
        run += v;
    }
    gt[((size_t)(b * NG + g)) * PSTR + c] = run;
}

__global__ __launch_bounds__(256) void scan_s2(float* __restrict__ gt) {
    const int c = blockIdx.x * 256 + threadIdx.x;
    if (c >= CCH) return;
    const int b = blockIdx.y;
    float run = 0.f;
    #pragma unroll
    for (int g = 0; g < NG; g++) {
        size_t idx = ((size_t)(b * NG + g)) * PSTR + c;
        float v = gt[idx];
        gt[idx] = run;
        run += v;
    }
}

// ---------------------------------------------------------------------------
// Unbind: 4 pairs (8 tokens = one chunk) per block. Round 11 barrier
// thinning: fill writes bB (FFT's initial sync then guards its q1 bB
// writes against the z-reads), LN reduction parity-buffered -> z-read sync
// and tail sync deleted: 6 barriers/pair (was 8).
// ---------------------------------------------------------------------------
__global__ __launch_bounds__(256) void unbind4_ln_kernel(
        const unsigned short* __restrict__ P, const float* __restrict__ totals,
        const float* __restrict__ gt, const unsigned short* __restrict__ KF,
        const float* __restrict__ ln_g, const float* __restrict__ ln_b,
        unsigned short* __restrict__ RLNb) {
    __shared__ float2 bA[1024], bB[1024];
    __shared__ __align__(16) float2 offsh[514];
    __shared__ float red[2][16];
    const int blk = blockIdx.x;
    const int tid = threadIdx.x;
    const int wv  = tid >> 6;
    const int ln  = tid & 63;
    const size_t tok0 = (size_t)blk * TLEN;     // 8 tokens, one chunk
    const int bidx  = (int)(tok0 >> 12);
    const int t0    = (int)(tok0 & (L_SZ - 1));
    const int chunk = t0 >> 3;                  // TLEN=8

    // combined chunk offset row -> LDS (once per block, float4 loads)
    {
        const float* off2 = totals + (size_t)(bidx * NCH + chunk) * PSTR;
        const float* gof2 = gt + (size_t)(bidx * NG + (chunk >> 4)) * PSTR;
        float4 o = *(const float4*)(off2 + 4 * tid);
        float4 g = *(const float4*)(gof2 + 4 * tid);
        float4 og; og.x = o.x + g.x; og.y = o.y + g.y;
        og.z = o.z + g.z; og.w = o.w + g.w;
        *(float4*)&offsh[2 * tid] = og;
        if (tid == 0)
            offsh[512] = make_float2(off2[1024] + gof2[1024],
                                     off2[1025] + gof2[1025]);
    }

    cplx w1s[4];
    make_w1<1>(w1s, tid);

    float gv[4], bev[4];
    #pragma unroll
    for (int e = 0; e < 4; e++) {
        gv[e]  = ln_g[tid + (e << 8)];
        bev[e] = ln_b[tid + (e << 8)];
    }
    __syncthreads();   // offsh ready

    const int b0 = 2 * tid, b1 = 2 * tid + 1;

    for (int p = 0; p < 4; ++p) {
        const size_t ta = tok0 + 2 * p, tb = ta + 1;
        const unsigned short* Pa = P + ta * PSTR;
        const unsigned short* Pc = P + tb * PSTR;
        const unsigned short* Ka = KF + ta * D_SZ;
        const unsigned short* Kc = KF + tb * D_SZ;

        // vector loads: S and Kf quads covering bins b0,b1 for both tokens
        ushort4 sa = *(const ushort4*)(Pa + 4 * tid);
        ushort4 sb = *(const ushort4*)(Pc + 4 * tid);
        ushort4 ka = *(const ushort4*)(Ka + 4 * tid);
        ushort4 kb = *(const ushort4*)(Kc + 4 * tid);
        float2 og0 = offsh[b0], og1 = offsh[b1];

        // --- bin b0 (tid0: b0=0 -> ki=0, slot1 is Kf512.re, don't use)
        {
            float ka_r = bf2f(ka.x), ka_i = (tid == 0) ? 0.f : bf2f(ka.y);
            float kb_r = bf2f(kb.x), kb_i = (tid == 0) ? 0.f : bf2f(kb.y);
            float sra = bf2f(sa.x) + og0.x, sia = bf2f(sa.y) + og0.y;
            float srb = bf2f(sb.x) + og0.x, sib = bf2f(sb.y) + og0.y;
            float Zar = sra * ka_r + sia * ka_i, Zai = sia * ka_r - sra * ka_i;
            float Zbr = srb * kb_r + sib * kb_i, Zbi = sib * kb_r - srb * kb_i;
            bB[SWZ(b0)] = make_float2(Zar - Zbi, Zai + Zbr);
            if (b0 != 0)
                bB[SWZ(1024 - b0)] = make_float2(Zar + Zbi, Zbr - Zai);
        }
        // --- bin b1 (always 1..511)
        {
            float ka_r = bf2f(ka.z), ka_i = bf2f(ka.w);
            float kb_r = bf2f(kb.z), kb_i = bf2f(kb.w);
            float sra = bf2f(sa.z) + og1.x, sia = bf2f(sa.w) + og1.y;
            float srb = bf2f(sb.z) + og1.x, sib = bf2f(sb.w) + og1.y;
            float Zar = sra * ka_r + sia * ka_i, Zai = sia * ka_r - sra * ka_i;
            float Zbr = srb * kb_r + sib * kb_i, Zbi = sib * kb_r - srb * kb_i;
            bB[SWZ(b1)] = make_float2(Zar - Zbi, Zai + Zbr);
            bB[SWZ(1024 - b1)] = make_float2(Zar + Zbi, Zbr - Zai);
        }
        // --- bin 512 (tid 0)
        if (tid == 0) {
            ushort2 s5a = *(const ushort2*)(Pa + 1024);
            ushort2 s5b = *(const ushort2*)(Pc + 1024);
            float2 og = offsh[512];
            float kra = bf2f(Ka[1]), krb = bf2f(Kc[1]);
            float sra = bf2f(s5a.x) + og.x, sia = bf2f(s5a.y) + og.y;
            float srb = bf2f(s5b.x) + og.x, sib = bf2f(s5b.y) + og.y;
            float Zar = sra * kra, Zai = sia * kra;
            float Zbr = srb * krb, Zbi = sib * krb;
            bB[SWZ(512)] = make_float2(Zar - Zbi, Zai + Zbr);
        }
        __syncthreads();   // bB (Hermitian-packed Y) ready

        cplx z[4];
        #pragma unroll
        for (int k = 0; k < 4; k++) {
            float2 c = bB[SWZ(tid + (k << 8))];
            z[k] = {c.x, c.y};
        }
        // no sync: FFT's initial store targets bA; its q1 bB writes are
        // behind the FFT-initial barrier, which all z-reads precede.
        fft1024_tw<1>(bA, bB, z, tid, w1s);   // z = 1024 * (ra + i*rb)

        const int t_a = t0 + 2 * p;
        const float sc_a = (1.0f / 1024.0f) * rsqrtf((float)(t_a + 1));
        const float sc_b = (1.0f / 1024.0f) * rsqrtf((float)(t_a + 2));
        float ra[4], rb[4];
        float s1a = 0.f, s2a = 0.f, s1b = 0.f, s2b = 0.f;
        #pragma unroll
        for (int e = 0; e < 4; e++) {
            ra[e] = z[e].r * sc_a;
            rb[e] = z[e].i * sc_b;
            s1a += ra[e]; s2a += ra[e] * ra[e];
            s1b += rb[e]; s2b += rb[e] * rb[e];
        }
        #pragma unroll
        for (int m = 1; m < 64; m <<= 1) {
            s1a += __shfl_xor(s1a, m, 64);
            s2a += __shfl_xor(s2a, m, 64);
            s1b += __shfl_xor(s1b, m, 64);
            s2b += __shfl_xor(s2b, m, 64);
        }
        float* rw = red[p & 1];
        if (ln == 0) {
            rw[wv] = s1a; rw[4 + wv] = s2a; rw[8 + wv] = s1b; rw[12 + wv] = s2b;
        }
        __syncthreads();   // red ready; also orders prior bB reads < next fill
        const float S1a = rw[0] + rw[1] + rw[2] + rw[3];
        const float S2a = rw[4] + rw[5] + rw[6] + rw[7];
        const float S1b = rw[8] + rw[9] + rw[10] + rw[11];
        const float S2b = rw[12] + rw[13] + rw[14] + rw[15];
        const float mua = S1a * (1.0f / 1024.0f);
        const float vara = S2a * (1.0f / 1024.0f) - mua * mua;
        const float rsa = rsqrtf(vara + 1e-5f);
        const float mub = S1b * (1.0f / 1024.0f);
        const float varb = S2b * (1.0f / 1024.0f) - mub * mub;
        const float rsb = rsqrtf(varb + 1e-5f);

        unsigned short* outA = RLNb + ta * D_SZ;
        unsigned short* outB = RLNb + tb * D_SZ;
        #pragma unroll
        for (int e = 0; e < 4; e++) {
            const int d = tid + (e << 8);
            outA[d] = f2bf((ra[e] - mua) * rsa * gv[e] + bev[e]);
            outB[d] = f2bf((rb[e] - mub) * rsb * gv[e] + bev[e]);
        }
        // no tail sync: red is parity-buffered; bA/bB reuse ordered by the
        // red-sync above + next pair's fill-sync + FFT-initial sync.
    }
}

// ---------------------------------------------------------------------------
// Workspace (bytes)  [total ~136 MiB — far below the proven 234 MiB]:
//   Kb     bf16 M*D        = 32.0 MB  (keys; bind overwrites with packed Kf)
//   Vb     bf16 M*D        = 32.0 MB  (dead after bind; reused as bf16 RLN)
//   Pb     bf16 M*PSTR     = 33.7 MB  (bind writes inclusive-in-chunk cumsum)
//   xb     bf16 M*D        = 32.0 MB  (dead after gemm16; totals fp32 8.4 MB
//                                      + gt fp32 0.5 MB OVERLAY it)
//   WB     bf16 2048*D     =  4.0 MB  (Wk ++ Wv)
//   Wob    bf16 D*D        =  2.0 MB
// ---------------------------------------------------------------------------
extern "C" void kernel_launch(void* const* d_in, const int* in_sizes, int n_in,
                              void* d_out, int out_size, void* d_ws, size_t ws_size,
                              hipStream_t stream) {
    (void)in_sizes; (void)n_in; (void)out_size; (void)ws_size;
    const float* x    = (const float*)d_in[0];
    const float* Wk   = (const float*)d_in[1];
    const float* bk   = (const float*)d_in[2];
    const float* Wv   = (const float*)d_in[3];
    const float* bv   = (const float*)d_in[4];
    const float* ln_g = (const float*)d_in[5];
    const float* ln_b = (const float*)d_in[6];
    const float* Wo   = (const float*)d_in[7];
    const float* bo   = (const float*)d_in[8];
    float* out = (float*)d_out;

    char* w = (char*)d_ws;
    unsigned short* Kb  = (unsigned short*)w;  w += (size_t)M_SZ * D_SZ * 2;
    unsigned short* Vb  = (unsigned short*)w;  w += (size_t)M_SZ * D_SZ * 2;
    unsigned short* Pb  = (unsigned short*)w;  w += (size_t)M_SZ * PSTR * 2;
    unsigned short* xb  = (unsigned short*)w;  w += (size_t)M_SZ * D_SZ * 2;
    unsigned short* WB  = (unsigned short*)w;  w += (size_t)2 * D_SZ * D_SZ * 2;
    unsigned short* Wob = (unsigned short*)w;  w += (size_t)D_SZ * D_SZ * 2;
    unsigned short* RLNb = Vb;  // overlays dead Vb
    // totals + gt overlay the dead xb region (xb only read by gemm16)
    float* totals = (float*)xb;                                    // 8.4 MB
    float* gt     = (float*)xb + (size_t)B_SZ * NCH * PSTR;        // 0.5 MB

    // single cast launch: x + Wk + Wv + Wo
    cast_all<<<XBLK + 3 * WBLK, 256, 0, stream>>>(x, Wk, Wv, Wo, xb, WB, Wob);

    // fused K/V projection: N=2048, bf16 outputs (first half -> Kb, second -> Vb)
    gemm_mfma<16, true><<<(M_SZ / 256) * 16, 512, 0, stream>>>(
        xb, WB, bk, bv, nullptr, Kb, Vb, M_SZ, D_SZ);

    // bind + in-chunk cumsum (one block per 8-token chunk)
    bind_cum_kernel<<<M_SZ / TLEN, 256, 0, stream>>>(Kb, Vb, Pb, totals);

    // 2-level exclusive scan of chunk totals
    dim3 g1((CCH + 255) / 256, NG, B_SZ);
    scan_s1<<<g1, 256, 0, stream>>>(totals, gt);
    dim3 g2((CCH + 255) / 256, B_SZ);
    scan_s2<<<g2, 256, 0, stream>>>(gt);

    // unbind: 4 pairs (one chunk) per block, packed real iFFT
    unbind4_ln_kernel<<<M_SZ / TLEN, 256, 0, stream>>>(
        Pb, totals, gt, Kb, ln_g, ln_b, RLNb);

    // output GEMM with fp32 residual (fp32 store)
    gemm_mfma<8, false><<<(M_SZ / 256) * 8, 512, 0, stream>>>(
        RLNb, Wob, bo, bo, x, out, out, M_SZ, D_SZ);
}